// Round 1
// baseline (1132.239 us; speedup 1.0000x reference)
//
#include <hip/hip_runtime.h>
#include <hip/hip_bf16.h>

#define HD 128          // hidden dim
#define BN_EPS 1e-5f

// ---------------- degree count ----------------
__global__ void k_count(const int* __restrict__ dst, int* __restrict__ counts, int E) {
    int i = blockIdx.x * blockDim.x + threadIdx.x;
    for (; i < E; i += gridDim.x * blockDim.x)
        atomicAdd(&counts[dst[i]], 1);
}

// ---------------- exclusive scan (3-kernel) ----------------
__global__ void k_scan1(const int* __restrict__ counts, int* __restrict__ offs,
                        int* __restrict__ bsums, int n) {
    __shared__ int s[256];
    int t = threadIdx.x, i = blockIdx.x * 256 + t;
    int v = (i < n) ? counts[i] : 0;
    s[t] = v; __syncthreads();
    for (int d = 1; d < 256; d <<= 1) {
        int x = (t >= d) ? s[t - d] : 0;
        __syncthreads(); s[t] += x; __syncthreads();
    }
    if (i < n) offs[i] = s[t] - v;
    if (t == 255) bsums[blockIdx.x] = s[255];
}

__global__ void k_scan2(int* __restrict__ bsums, int nb) {
    __shared__ int s[256];
    int t = threadIdx.x;
    int v = (t < nb) ? bsums[t] : 0;
    s[t] = v; __syncthreads();
    for (int d = 1; d < 256; d <<= 1) {
        int x = (t >= d) ? s[t - d] : 0;
        __syncthreads(); s[t] += x; __syncthreads();
    }
    if (t < nb) bsums[t] = s[t] - v;
}

__global__ void k_scan3(int* __restrict__ offs, const int* __restrict__ bsums,
                        int* __restrict__ cursor, int n) {
    int i = blockIdx.x * 256 + threadIdx.x;
    if (i < n) {
        int v = offs[i] + bsums[blockIdx.x];
        offs[i] = v;
        cursor[i] = v;
    }
}

// ---------------- dis = rsqrt(deg) ----------------
__global__ void k_dis(const int* __restrict__ counts, float* __restrict__ dis, int n) {
    int i = blockIdx.x * blockDim.x + threadIdx.x;
    if (i < n) dis[i] = rsqrtf((float)(counts[i] + 1));   // +1 self loop
}

// ---------------- CSR fill ----------------
__global__ void k_fill(const int* __restrict__ src, const int* __restrict__ dst,
                       const float* __restrict__ dis, int* __restrict__ cursor,
                       int* __restrict__ csr_src, float* __restrict__ csr_cf, int E) {
    int i = blockIdx.x * blockDim.x + threadIdx.x;
    for (; i < E; i += gridDim.x * blockDim.x) {
        int s = src[i], d = dst[i];
        int pos = atomicAdd(&cursor[d], 1);
        csr_src[pos] = s;
        csr_cf[pos] = dis[s] * dis[d];
    }
}

// ---------------- row GEMM: out[n,128] = A[n,K] @ W[K,128] ----------------
__global__ void k_gemm(const float* __restrict__ A, const float* __restrict__ W,
                       float* __restrict__ out, int n, int K) {
    __shared__ float row[HD];
    int t = threadIdx.x;
    const int ROWS = 8;
    int base = blockIdx.x * ROWS;
    for (int r = 0; r < ROWS; ++r) {
        int node = base + r;
        if (node >= n) return;           // uniform across block
        if (t < K) row[t] = A[(size_t)node * K + t];
        __syncthreads();
        float acc = 0.f;
        for (int k = 0; k < K; ++k)
            acc += row[k] * W[k * HD + t];
        out[(size_t)node * HD + t] = acc;
        __syncthreads();
    }
}

// ---------------- aggregate + bias + BN + ReLU ----------------
__global__ void k_agg(const float* __restrict__ hw, const int* __restrict__ offs,
                      const int* __restrict__ counts, const int* __restrict__ csr_src,
                      const float* __restrict__ csr_cf, const float* __restrict__ dis,
                      const float* __restrict__ bias, const float* __restrict__ gamma,
                      const float* __restrict__ beta, const float* __restrict__ mean,
                      const float* __restrict__ var, float* __restrict__ hout, int n) {
    int node = blockIdx.x;
    int t = threadIdx.x;
    float dn = dis[node];
    float acc = dn * dn * hw[(size_t)node * HD + t];
    int beg = offs[node], cnt = counts[node];
    for (int i = 0; i < cnt; ++i) {
        int e = beg + i;
        acc += csr_cf[e] * hw[(size_t)csr_src[e] * HD + t];
    }
    acc += bias[t];
    acc = (acc - mean[t]) * rsqrtf(var[t] + BN_EPS) * gamma[t] + beta[t];
    hout[(size_t)node * HD + t] = fmaxf(acc, 0.f);
}

// ---------------- pooling (mean-sum / max / count) ----------------
__global__ void k_pool(const float* __restrict__ h, const int* __restrict__ batch,
                       float* __restrict__ gsum, unsigned int* __restrict__ gmax,
                       int* __restrict__ gcnt, int n) {
    int total = n * HD;
    int i = blockIdx.x * blockDim.x + threadIdx.x;
    for (; i < total; i += gridDim.x * blockDim.x) {
        int node = i >> 7, f = i & (HD - 1);
        float v = h[i];
        int g = batch[node];
        atomicAdd(&gsum[g * HD + f], v);
        atomicMax(&gmax[g * HD + f], __float_as_uint(v));   // v >= 0 after ReLU
        if (f == 0) atomicAdd(&gcnt[g], 1);
    }
}

// ---------------- pooled MLP layer 1: relu([mean||max] @ pool_W + pool_b) ----------------
__global__ void k_mlp1(const float* __restrict__ gsum, const unsigned int* __restrict__ gmax,
                       const int* __restrict__ gcnt, const float* __restrict__ pool_W,
                       const float* __restrict__ pool_b, float* __restrict__ hid) {
    int g = blockIdx.x, t = threadIdx.x;   // t in [0,128)
    __shared__ float pooled[2 * HD];
    float cntf = fmaxf((float)gcnt[g], 1.f);
    pooled[t] = gsum[g * HD + t] / cntf;
    pooled[HD + t] = __uint_as_float(gmax[g * HD + t]);
    __syncthreads();
    float acc = pool_b[t];
    for (int k = 0; k < 2 * HD; ++k)
        acc += pooled[k] * pool_W[k * HD + t];
    hid[g * HD + t] = fmaxf(acc, 0.f);
}

// ---------------- final head: hid @ out_W + out_b ----------------
__global__ void k_mlp2(const float* __restrict__ hid, const float* __restrict__ out_W,
                       const float* __restrict__ out_b, float* __restrict__ out) {
    int g = blockIdx.x, o = threadIdx.x;   // o in [0,64)
    __shared__ float hv[HD];
    hv[o] = hid[g * HD + o];
    hv[o + 64] = hid[g * HD + o + 64];
    __syncthreads();
    float acc = out_b[o];
    for (int j = 0; j < HD; ++j)
        acc += hv[j] * out_W[j * 64 + o];
    out[g * 64 + o] = acc;
}

extern "C" void kernel_launch(void* const* d_in, const int* in_sizes, int n_in,
                              void* d_out, int out_size, void* d_ws, size_t ws_size,
                              hipStream_t stream) {
    const float* x        = (const float*)d_in[0];
    const int*   eidx     = (const int*)d_in[1];
    const int*   batch    = (const int*)d_in[2];
    const float* W0       = (const float*)d_in[3];
    const float* Wh       = (const float*)d_in[4];
    const float* b        = (const float*)d_in[5];
    const float* bn_gamma = (const float*)d_in[6];
    const float* bn_beta  = (const float*)d_in[7];
    const float* bn_mean  = (const float*)d_in[8];
    const float* bn_var   = (const float*)d_in[9];
    const float* pool_W   = (const float*)d_in[10];
    const float* pool_b   = (const float*)d_in[11];
    const float* out_W    = (const float*)d_in[12];
    const float* out_b    = (const float*)d_in[13];
    float* out = (float*)d_out;

    const int N = in_sizes[2];
    const int E = in_sizes[1] / 2;
    const int F_IN = in_sizes[0] / N;
    const int L = in_sizes[5] / HD;
    const int G = out_size / (HD / 2);

    const int* src = eidx;
    const int* dst = eidx + E;

    // workspace layout (all 4-byte types)
    char* p = (char*)d_ws;
    float* h       = (float*)p; p += (size_t)N * HD * 4;
    float* hw      = (float*)p; p += (size_t)N * HD * 4;
    int*   counts  = (int*)p;   p += (size_t)N * 4;
    float* dis     = (float*)p; p += (size_t)N * 4;
    int*   offs    = (int*)p;   p += (size_t)(N + 1) * 4;
    int*   cursor  = (int*)p;   p += (size_t)N * 4;
    int*   csr_src = (int*)p;   p += (size_t)E * 4;
    float* csr_cf  = (float*)p; p += (size_t)E * 4;
    int*   bsums   = (int*)p;   p += 256 * 4;
    float* gsum    = (float*)p; p += (size_t)G * HD * 4;
    unsigned int* gmax = (unsigned int*)p; p += (size_t)G * HD * 4;
    int*   gcnt    = (int*)p;   p += (size_t)G * 4;
    float* hid     = (float*)p; p += (size_t)G * HD * 4;
    (void)ws_size; (void)n_in;

    // zero accumulators
    hipMemsetAsync(counts, 0, (size_t)N * 4, stream);
    hipMemsetAsync(gsum, 0, (size_t)G * HD * 4, stream);
    hipMemsetAsync(gmax, 0, (size_t)G * HD * 4, stream);
    hipMemsetAsync(gcnt, 0, (size_t)G * 4, stream);

    const int NB = (N + 255) / 256;

    k_count<<<1024, 256, 0, stream>>>(dst, counts, E);
    k_scan1<<<NB, 256, 0, stream>>>(counts, offs, bsums, N);
    k_scan2<<<1, 256, 0, stream>>>(bsums, NB);
    k_scan3<<<NB, 256, 0, stream>>>(offs, bsums, cursor, N);
    k_dis<<<(N + 255) / 256, 256, 0, stream>>>(counts, dis, N);
    k_fill<<<1024, 256, 0, stream>>>(src, dst, dis, cursor, csr_src, csr_cf, E);

    // layers
    const float* cur_in = x;
    int K = F_IN;
    for (int l = 0; l < L; ++l) {
        const float* W = (l == 0) ? W0 : (Wh + (size_t)(l - 1) * HD * HD);
        k_gemm<<<(N + 7) / 8, HD, 0, stream>>>(cur_in, W, hw, N, K);
        k_agg<<<N, HD, 0, stream>>>(hw, offs, counts, csr_src, csr_cf, dis,
                                    b + l * HD, bn_gamma + l * HD, bn_beta + l * HD,
                                    bn_mean + l * HD, bn_var + l * HD, h, N);
        cur_in = h;
        K = HD;
    }

    // pooling + head
    k_pool<<<2048, 256, 0, stream>>>(h, batch, gsum, gmax, gcnt, N);
    k_mlp1<<<G, HD, 0, stream>>>(gsum, gmax, gcnt, pool_W, pool_b, hid);
    k_mlp2<<<G, 64, 0, stream>>>(hid, out_W, out_b, out);
}

// Round 2
// 796.765 us; speedup vs baseline: 1.4210x; 1.4210x over previous
//
#include <hip/hip_runtime.h>
#include <hip/hip_bf16.h>

#define HD 128          // hidden dim
#define BN_EPS 1e-5f
#define PSPLIT 16       // pooling slices per graph

// ---------------- degree count ----------------
__global__ void k_count(const int* __restrict__ dst, int* __restrict__ counts, int E) {
    int i = blockIdx.x * blockDim.x + threadIdx.x;
    for (; i < E; i += gridDim.x * blockDim.x)
        atomicAdd(&counts[dst[i]], 1);
}

// ---------------- exclusive scan (3-kernel) ----------------
__global__ void k_scan1(const int* __restrict__ counts, int* __restrict__ offs,
                        int* __restrict__ bsums, int n) {
    __shared__ int s[256];
    int t = threadIdx.x, i = blockIdx.x * 256 + t;
    int v = (i < n) ? counts[i] : 0;
    s[t] = v; __syncthreads();
    for (int d = 1; d < 256; d <<= 1) {
        int x = (t >= d) ? s[t - d] : 0;
        __syncthreads(); s[t] += x; __syncthreads();
    }
    if (i < n) offs[i] = s[t] - v;
    if (t == 255) bsums[blockIdx.x] = s[255];
}

__global__ void k_scan2(int* __restrict__ bsums, int nb) {
    __shared__ int s[256];
    int t = threadIdx.x;
    int v = (t < nb) ? bsums[t] : 0;
    s[t] = v; __syncthreads();
    for (int d = 1; d < 256; d <<= 1) {
        int x = (t >= d) ? s[t - d] : 0;
        __syncthreads(); s[t] += x; __syncthreads();
    }
    if (t < nb) bsums[t] = s[t] - v;
}

__global__ void k_scan3(int* __restrict__ offs, const int* __restrict__ bsums,
                        int* __restrict__ cursor, int n) {
    int i = blockIdx.x * 256 + threadIdx.x;
    if (i < n) {
        int v = offs[i] + bsums[blockIdx.x];
        offs[i] = v;
        cursor[i] = v;
    }
}

// ---------------- dis = rsqrt(deg) ----------------
__global__ void k_dis(const int* __restrict__ counts, float* __restrict__ dis, int n) {
    int i = blockIdx.x * blockDim.x + threadIdx.x;
    if (i < n) dis[i] = rsqrtf((float)(counts[i] + 1));   // +1 self loop
}

// ---------------- CSR fill ----------------
__global__ void k_fill(const int* __restrict__ src, const int* __restrict__ dst,
                       const float* __restrict__ dis, int* __restrict__ cursor,
                       int* __restrict__ csr_src, float* __restrict__ csr_cf, int E) {
    int i = blockIdx.x * blockDim.x + threadIdx.x;
    for (; i < E; i += gridDim.x * blockDim.x) {
        int s = src[i], d = dst[i];
        int pos = atomicAdd(&cursor[d], 1);
        csr_src[pos] = s;
        csr_cf[pos] = dis[s] * dis[d];
    }
}

// ---------------- row GEMM: out[n,128] = A[n,K] @ W[K,128] ----------------
__global__ void k_gemm(const float* __restrict__ A, const float* __restrict__ W,
                       float* __restrict__ out, int n, int K) {
    __shared__ float row[HD];
    int t = threadIdx.x;
    const int ROWS = 8;
    int base = blockIdx.x * ROWS;
    for (int r = 0; r < ROWS; ++r) {
        int node = base + r;
        if (node >= n) return;           // uniform across block
        if (t < K) row[t] = A[(size_t)node * K + t];
        __syncthreads();
        float acc = 0.f;
        for (int k = 0; k < K; ++k)
            acc += row[k] * W[k * HD + t];
        out[(size_t)node * HD + t] = acc;
        __syncthreads();
    }
}

// ---------------- aggregate + bias + BN + ReLU ----------------
__global__ void k_agg(const float* __restrict__ hw, const int* __restrict__ offs,
                      const int* __restrict__ counts, const int* __restrict__ csr_src,
                      const float* __restrict__ csr_cf, const float* __restrict__ dis,
                      const float* __restrict__ bias, const float* __restrict__ gamma,
                      const float* __restrict__ beta, const float* __restrict__ mean,
                      const float* __restrict__ var, float* __restrict__ hout, int n) {
    int node = blockIdx.x;
    int t = threadIdx.x;
    float dn = dis[node];
    float acc = dn * dn * hw[(size_t)node * HD + t];
    int beg = offs[node], cnt = counts[node];
    for (int i = 0; i < cnt; ++i) {
        int e = beg + i;
        acc += csr_cf[e] * hw[(size_t)csr_src[e] * HD + t];
    }
    acc += bias[t];
    acc = (acc - mean[t]) * rsqrtf(var[t] + BN_EPS) * gamma[t] + beta[t];
    hout[(size_t)node * HD + t] = fmaxf(acc, 0.f);
}

// ---------------- graph segment boundaries (batch is sorted) ----------------
__global__ void k_bounds(const int* __restrict__ batch, int* __restrict__ starts,
                         int n, int G) {
    int g = threadIdx.x;                 // 0..G inclusive
    if (g > G) return;
    int lo = 0, hi = n;
    while (lo < hi) {                    // lower_bound(batch, g)
        int mid = (lo + hi) >> 1;
        if (batch[mid] < g) lo = mid + 1; else hi = mid;
    }
    starts[g] = lo;
}

// ---------------- pooling: per-graph-slice register reduction ----------------
__global__ void k_pool(const float* __restrict__ h, const int* __restrict__ starts,
                       float* __restrict__ gsum, unsigned int* __restrict__ gmax) {
    int g = blockIdx.x;
    int slice = blockIdx.y;
    int t = threadIdx.x;                 // feature 0..127
    int s = starts[g], e = starts[g + 1];
    int cnt = e - s;
    int per = (cnt + PSPLIT - 1) / PSPLIT;
    int beg = s + slice * per;
    int end = min(beg + per, e);
    if (beg >= end) return;
    float sum = 0.f, mx = 0.f;           // post-ReLU values are >= 0
    for (int node = beg; node < end; ++node) {
        float v = h[(size_t)node * HD + t];
        sum += v;
        mx = fmaxf(mx, v);
    }
    atomicAdd(&gsum[g * HD + t], sum);
    atomicMax(&gmax[g * HD + t], __float_as_uint(mx));
}

// ---------------- pooled MLP layer 1: relu([mean||max] @ pool_W + pool_b) ----------------
__global__ void k_mlp1(const float* __restrict__ gsum, const unsigned int* __restrict__ gmax,
                       const int* __restrict__ starts, const float* __restrict__ pool_W,
                       const float* __restrict__ pool_b, float* __restrict__ hid) {
    int g = blockIdx.x, t = threadIdx.x;   // t in [0,128)
    __shared__ float pooled[2 * HD];
    float cntf = fmaxf((float)(starts[g + 1] - starts[g]), 1.f);
    pooled[t] = gsum[g * HD + t] / cntf;
    pooled[HD + t] = __uint_as_float(gmax[g * HD + t]);
    __syncthreads();
    float acc = pool_b[t];
    for (int k = 0; k < 2 * HD; ++k)
        acc += pooled[k] * pool_W[k * HD + t];
    hid[g * HD + t] = fmaxf(acc, 0.f);
}

// ---------------- final head: hid @ out_W + out_b ----------------
__global__ void k_mlp2(const float* __restrict__ hid, const float* __restrict__ out_W,
                       const float* __restrict__ out_b, float* __restrict__ out) {
    int g = blockIdx.x, o = threadIdx.x;   // o in [0,64)
    __shared__ float hv[HD];
    hv[o] = hid[g * HD + o];
    hv[o + 64] = hid[g * HD + o + 64];
    __syncthreads();
    float acc = out_b[o];
    for (int j = 0; j < HD; ++j)
        acc += hv[j] * out_W[j * 64 + o];
    out[g * 64 + o] = acc;
}

extern "C" void kernel_launch(void* const* d_in, const int* in_sizes, int n_in,
                              void* d_out, int out_size, void* d_ws, size_t ws_size,
                              hipStream_t stream) {
    const float* x        = (const float*)d_in[0];
    const int*   eidx     = (const int*)d_in[1];
    const int*   batch    = (const int*)d_in[2];
    const float* W0       = (const float*)d_in[3];
    const float* Wh       = (const float*)d_in[4];
    const float* b        = (const float*)d_in[5];
    const float* bn_gamma = (const float*)d_in[6];
    const float* bn_beta  = (const float*)d_in[7];
    const float* bn_mean  = (const float*)d_in[8];
    const float* bn_var   = (const float*)d_in[9];
    const float* pool_W   = (const float*)d_in[10];
    const float* pool_b   = (const float*)d_in[11];
    const float* out_W    = (const float*)d_in[12];
    const float* out_b    = (const float*)d_in[13];
    float* out = (float*)d_out;

    const int N = in_sizes[2];
    const int E = in_sizes[1] / 2;
    const int F_IN = in_sizes[0] / N;
    const int L = in_sizes[5] / HD;
    const int G = out_size / (HD / 2);

    const int* src = eidx;
    const int* dst = eidx + E;

    // workspace layout (all 4-byte types)
    char* p = (char*)d_ws;
    float* h       = (float*)p; p += (size_t)N * HD * 4;
    float* hw      = (float*)p; p += (size_t)N * HD * 4;
    int*   counts  = (int*)p;   p += (size_t)N * 4;
    float* dis     = (float*)p; p += (size_t)N * 4;
    int*   offs    = (int*)p;   p += (size_t)(N + 1) * 4;
    int*   cursor  = (int*)p;   p += (size_t)N * 4;
    int*   csr_src = (int*)p;   p += (size_t)E * 4;
    float* csr_cf  = (float*)p; p += (size_t)E * 4;
    int*   bsums   = (int*)p;   p += 256 * 4;
    float* gsum    = (float*)p; p += (size_t)G * HD * 4;
    unsigned int* gmax = (unsigned int*)p; p += (size_t)G * HD * 4;
    int*   starts  = (int*)p;   p += (size_t)(G + 1) * 4;
    float* hid     = (float*)p; p += (size_t)G * HD * 4;
    (void)ws_size; (void)n_in;

    // zero accumulators
    hipMemsetAsync(counts, 0, (size_t)N * 4, stream);
    hipMemsetAsync(gsum, 0, (size_t)G * HD * 4, stream);
    hipMemsetAsync(gmax, 0, (size_t)G * HD * 4, stream);

    const int NB = (N + 255) / 256;

    k_count<<<1024, 256, 0, stream>>>(dst, counts, E);
    k_scan1<<<NB, 256, 0, stream>>>(counts, offs, bsums, N);
    k_scan2<<<1, 256, 0, stream>>>(bsums, NB);
    k_scan3<<<NB, 256, 0, stream>>>(offs, bsums, cursor, N);
    k_dis<<<(N + 255) / 256, 256, 0, stream>>>(counts, dis, N);
    k_fill<<<1024, 256, 0, stream>>>(src, dst, dis, cursor, csr_src, csr_cf, E);
    k_bounds<<<1, 128, 0, stream>>>(batch, starts, N, G);

    // layers
    const float* cur_in = x;
    int K = F_IN;
    for (int l = 0; l < L; ++l) {
        const float* W = (l == 0) ? W0 : (Wh + (size_t)(l - 1) * HD * HD);
        k_gemm<<<(N + 7) / 8, HD, 0, stream>>>(cur_in, W, hw, N, K);
        k_agg<<<N, HD, 0, stream>>>(hw, offs, counts, csr_src, csr_cf, dis,
                                    b + l * HD, bn_gamma + l * HD, bn_beta + l * HD,
                                    bn_mean + l * HD, bn_var + l * HD, h, N);
        cur_in = h;
        K = HD;
    }

    // pooling + head
    dim3 pgrid(G, PSPLIT);
    k_pool<<<pgrid, HD, 0, stream>>>(h, starts, gsum, gmax);
    k_mlp1<<<G, HD, 0, stream>>>(gsum, gmax, starts, pool_W, pool_b, hid);
    k_mlp2<<<G, 64, 0, stream>>>(hid, out_W, out_b, out);
}

// Round 3
// 575.466 us; speedup vs baseline: 1.9675x; 1.3846x over previous
//
#include <hip/hip_runtime.h>
#include <hip/hip_bf16.h>

#define HD 128          // hidden dim
#define BN_EPS 1e-5f
#define PSPLIT 16       // pooling slices per graph

// ---------------- degree count ----------------
__global__ void k_count(const int* __restrict__ dst, int* __restrict__ counts, int E) {
    int i = blockIdx.x * blockDim.x + threadIdx.x;
    for (; i < E; i += gridDim.x * blockDim.x)
        atomicAdd(&counts[dst[i]], 1);
}

// ---------------- exclusive scan (3-kernel) ----------------
__global__ void k_scan1(const int* __restrict__ counts, int* __restrict__ offs,
                        int* __restrict__ bsums, int n) {
    __shared__ int s[256];
    int t = threadIdx.x, i = blockIdx.x * 256 + t;
    int v = (i < n) ? counts[i] : 0;
    s[t] = v; __syncthreads();
    for (int d = 1; d < 256; d <<= 1) {
        int x = (t >= d) ? s[t - d] : 0;
        __syncthreads(); s[t] += x; __syncthreads();
    }
    if (i < n) offs[i] = s[t] - v;
    if (t == 255) bsums[blockIdx.x] = s[255];
}

__global__ void k_scan2(int* __restrict__ bsums, int nb) {
    __shared__ int s[256];
    int t = threadIdx.x;
    int v = (t < nb) ? bsums[t] : 0;
    s[t] = v; __syncthreads();
    for (int d = 1; d < 256; d <<= 1) {
        int x = (t >= d) ? s[t - d] : 0;
        __syncthreads(); s[t] += x; __syncthreads();
    }
    if (t < nb) bsums[t] = s[t] - v;
}

__global__ void k_scan3(int* __restrict__ offs, const int* __restrict__ bsums,
                        int* __restrict__ cursor, int n) {
    int i = blockIdx.x * 256 + threadIdx.x;
    if (i < n) {
        int v = offs[i] + bsums[blockIdx.x];
        offs[i] = v;
        cursor[i] = v;
    }
}

// ---------------- dis = rsqrt(deg) ----------------
__global__ void k_dis(const int* __restrict__ counts, float* __restrict__ dis, int n) {
    int i = blockIdx.x * blockDim.x + threadIdx.x;
    if (i < n) dis[i] = rsqrtf((float)(counts[i] + 1));   // +1 self loop
}

// ---------------- CSR fill ----------------
__global__ void k_fill(const int* __restrict__ src, const int* __restrict__ dst,
                       const float* __restrict__ dis, int* __restrict__ cursor,
                       int* __restrict__ csr_src, float* __restrict__ csr_cf, int E) {
    int i = blockIdx.x * blockDim.x + threadIdx.x;
    for (; i < E; i += gridDim.x * blockDim.x) {
        int s = src[i], d = dst[i];
        int pos = atomicAdd(&cursor[d], 1);
        csr_src[pos] = s;
        csr_cf[pos] = dis[s] * dis[d];
    }
}

// ---------------- tiled GEMM: out[n,HD] = A[n,K] @ W[K,HD] ----------------
// 64x64 tile per 256-thread block, 4x4 micro-tile per thread, K tiled by BK.
template<int BK>
__global__ __launch_bounds__(256) void k_gemm_t(const float* __restrict__ A,
                                                const float* __restrict__ W,
                                                float* __restrict__ out, int n, int K) {
    __shared__ float as[64][BK + 4];   // A tile (row-major), +4 pad: reads 2-way max
    __shared__ float ws[BK][68];       // W tile, +4 pad
    constexpr int KV = BK / 4;

    int tid = threadIdx.x;
    int row0 = blockIdx.x * 64;
    int col0 = blockIdx.y * 64;
    int tx = tid & 15, ty = tid >> 4;  // 16x16 thread grid

    float acc[4][4] = {};

    for (int kt = 0; kt < K; kt += BK) {
        // stage A tile: rows row0..row0+63, cols kt..kt+BK-1
        for (int f = tid; f < 64 * KV; f += 256) {
            int r = f / KV, kq = f % KV;
            float4 v = make_float4(0.f, 0.f, 0.f, 0.f);
            int row = row0 + r;
            if (row < n)
                v = reinterpret_cast<const float4*>(A + (size_t)row * K + kt)[kq];
            *reinterpret_cast<float4*>(&as[r][kq * 4]) = v;
        }
        // stage W tile: rows kt..kt+BK-1, cols col0..col0+63
        for (int f = tid; f < BK * 16; f += 256) {
            int k = f / 16, cq = f % 16;
            float4 v = reinterpret_cast<const float4*>(W + (size_t)(kt + k) * HD + col0)[cq];
            *reinterpret_cast<float4*>(&ws[k][cq * 4]) = v;
        }
        __syncthreads();

        #pragma unroll
        for (int k4 = 0; k4 < KV; ++k4) {
            float4 w0 = *reinterpret_cast<float4*>(&ws[k4 * 4 + 0][tx * 4]);
            float4 w1 = *reinterpret_cast<float4*>(&ws[k4 * 4 + 1][tx * 4]);
            float4 w2 = *reinterpret_cast<float4*>(&ws[k4 * 4 + 2][tx * 4]);
            float4 w3 = *reinterpret_cast<float4*>(&ws[k4 * 4 + 3][tx * 4]);
            #pragma unroll
            for (int r = 0; r < 4; ++r) {
                float4 a = *reinterpret_cast<float4*>(&as[ty * 4 + r][k4 * 4]);
                acc[r][0] += a.x * w0.x + a.y * w1.x + a.z * w2.x + a.w * w3.x;
                acc[r][1] += a.x * w0.y + a.y * w1.y + a.z * w2.y + a.w * w3.y;
                acc[r][2] += a.x * w0.z + a.y * w1.z + a.z * w2.z + a.w * w3.z;
                acc[r][3] += a.x * w0.w + a.y * w1.w + a.z * w2.w + a.w * w3.w;
            }
        }
        __syncthreads();
    }

    #pragma unroll
    for (int r = 0; r < 4; ++r) {
        int row = row0 + ty * 4 + r;
        if (row < n) {
            float4 v = make_float4(acc[r][0], acc[r][1], acc[r][2], acc[r][3]);
            *reinterpret_cast<float4*>(out + (size_t)row * HD + col0 + tx * 4) = v;
        }
    }
}

// ---------------- aggregate + bias + BN + ReLU (float4, 32 lanes/node) ----------------
__global__ void k_agg(const float* __restrict__ hw, const int* __restrict__ offs,
                      const int* __restrict__ counts, const int* __restrict__ csr_src,
                      const float* __restrict__ csr_cf, const float* __restrict__ dis,
                      const float* __restrict__ bias, const float* __restrict__ gamma,
                      const float* __restrict__ beta, const float* __restrict__ mean,
                      const float* __restrict__ var, float* __restrict__ hout, int n) {
    int grp = threadIdx.x >> 5;          // 8 groups per 256-thread block
    int lane = threadIdx.x & 31;         // feature quad index
    int node = blockIdx.x * 8 + grp;
    if (node >= n) return;

    const float4* hw4 = reinterpret_cast<const float4*>(hw);
    float dn = dis[node];
    float sl = dn * dn;                  // self-loop coef
    float4 a = hw4[(size_t)node * 32 + lane];
    float4 acc = make_float4(sl * a.x, sl * a.y, sl * a.z, sl * a.w);

    int beg = offs[node], end = beg + counts[node];
    for (int e = beg; e < end; ++e) {
        int s = csr_src[e];              // broadcast within group
        float cf = csr_cf[e];
        float4 v = hw4[(size_t)s * 32 + lane];
        acc.x += cf * v.x; acc.y += cf * v.y;
        acc.z += cf * v.z; acc.w += cf * v.w;
    }

    float4 g = reinterpret_cast<const float4*>(gamma)[lane];
    float4 bb = reinterpret_cast<const float4*>(beta)[lane];
    float4 m = reinterpret_cast<const float4*>(mean)[lane];
    float4 vv = reinterpret_cast<const float4*>(var)[lane];
    float4 bi = reinterpret_cast<const float4*>(bias)[lane];
    float4 o;
    o.x = fmaxf(((acc.x + bi.x) - m.x) * rsqrtf(vv.x + BN_EPS) * g.x + bb.x, 0.f);
    o.y = fmaxf(((acc.y + bi.y) - m.y) * rsqrtf(vv.y + BN_EPS) * g.y + bb.y, 0.f);
    o.z = fmaxf(((acc.z + bi.z) - m.z) * rsqrtf(vv.z + BN_EPS) * g.z + bb.z, 0.f);
    o.w = fmaxf(((acc.w + bi.w) - m.w) * rsqrtf(vv.w + BN_EPS) * g.w + bb.w, 0.f);
    reinterpret_cast<float4*>(hout)[(size_t)node * 32 + lane] = o;
}

// ---------------- graph segment boundaries (batch is sorted) ----------------
__global__ void k_bounds(const int* __restrict__ batch, int* __restrict__ starts,
                         int n, int G) {
    int g = threadIdx.x;                 // 0..G inclusive
    if (g > G) return;
    int lo = 0, hi = n;
    while (lo < hi) {                    // lower_bound(batch, g)
        int mid = (lo + hi) >> 1;
        if (batch[mid] < g) lo = mid + 1; else hi = mid;
    }
    starts[g] = lo;
}

// ---------------- pooling: per-graph-slice register reduction ----------------
__global__ void k_pool(const float* __restrict__ h, const int* __restrict__ starts,
                       float* __restrict__ gsum, unsigned int* __restrict__ gmax) {
    int g = blockIdx.x;
    int slice = blockIdx.y;
    int t = threadIdx.x;                 // feature 0..127
    int s = starts[g], e = starts[g + 1];
    int cnt = e - s;
    int per = (cnt + PSPLIT - 1) / PSPLIT;
    int beg = s + slice * per;
    int end = min(beg + per, e);
    if (beg >= end) return;
    float sum = 0.f, mx = 0.f;           // post-ReLU values are >= 0
    for (int node = beg; node < end; ++node) {
        float v = h[(size_t)node * HD + t];
        sum += v;
        mx = fmaxf(mx, v);
    }
    atomicAdd(&gsum[g * HD + t], sum);
    atomicMax(&gmax[g * HD + t], __float_as_uint(mx));
}

// ---------------- pooled MLP layer 1: relu([mean||max] @ pool_W + pool_b) ----------------
__global__ void k_mlp1(const float* __restrict__ gsum, const unsigned int* __restrict__ gmax,
                       const int* __restrict__ starts, const float* __restrict__ pool_W,
                       const float* __restrict__ pool_b, float* __restrict__ hid) {
    int g = blockIdx.x, t = threadIdx.x;   // t in [0,128)
    __shared__ float pooled[2 * HD];
    float cntf = fmaxf((float)(starts[g + 1] - starts[g]), 1.f);
    pooled[t] = gsum[g * HD + t] / cntf;
    pooled[HD + t] = __uint_as_float(gmax[g * HD + t]);
    __syncthreads();
    float acc = pool_b[t];
    for (int k = 0; k < 2 * HD; ++k)
        acc += pooled[k] * pool_W[k * HD + t];
    hid[g * HD + t] = fmaxf(acc, 0.f);
}

// ---------------- final head: hid @ out_W + out_b ----------------
__global__ void k_mlp2(const float* __restrict__ hid, const float* __restrict__ out_W,
                       const float* __restrict__ out_b, float* __restrict__ out) {
    int g = blockIdx.x, o = threadIdx.x;   // o in [0,64)
    __shared__ float hv[HD];
    hv[o] = hid[g * HD + o];
    hv[o + 64] = hid[g * HD + o + 64];
    __syncthreads();
    float acc = out_b[o];
    for (int j = 0; j < HD; ++j)
        acc += hv[j] * out_W[j * 64 + o];
    out[g * 64 + o] = acc;
}

extern "C" void kernel_launch(void* const* d_in, const int* in_sizes, int n_in,
                              void* d_out, int out_size, void* d_ws, size_t ws_size,
                              hipStream_t stream) {
    const float* x        = (const float*)d_in[0];
    const int*   eidx     = (const int*)d_in[1];
    const int*   batch    = (const int*)d_in[2];
    const float* W0       = (const float*)d_in[3];
    const float* Wh       = (const float*)d_in[4];
    const float* b        = (const float*)d_in[5];
    const float* bn_gamma = (const float*)d_in[6];
    const float* bn_beta  = (const float*)d_in[7];
    const float* bn_mean  = (const float*)d_in[8];
    const float* bn_var   = (const float*)d_in[9];
    const float* pool_W   = (const float*)d_in[10];
    const float* pool_b   = (const float*)d_in[11];
    const float* out_W    = (const float*)d_in[12];
    const float* out_b    = (const float*)d_in[13];
    float* out = (float*)d_out;

    const int N = in_sizes[2];
    const int E = in_sizes[1] / 2;
    const int F_IN = in_sizes[0] / N;
    const int L = in_sizes[5] / HD;
    const int G = out_size / (HD / 2);

    const int* src = eidx;
    const int* dst = eidx + E;

    // workspace layout (all 4-byte types)
    char* p = (char*)d_ws;
    float* h       = (float*)p; p += (size_t)N * HD * 4;
    float* hw      = (float*)p; p += (size_t)N * HD * 4;
    int*   counts  = (int*)p;   p += (size_t)N * 4;
    float* dis     = (float*)p; p += (size_t)N * 4;
    int*   offs    = (int*)p;   p += (size_t)(N + 1) * 4;
    int*   cursor  = (int*)p;   p += (size_t)N * 4;
    int*   csr_src = (int*)p;   p += (size_t)E * 4;
    float* csr_cf  = (float*)p; p += (size_t)E * 4;
    int*   bsums   = (int*)p;   p += 256 * 4;
    float* gsum    = (float*)p; p += (size_t)G * HD * 4;
    unsigned int* gmax = (unsigned int*)p; p += (size_t)G * HD * 4;
    int*   starts  = (int*)p;   p += (size_t)(G + 1) * 4;
    float* hid     = (float*)p; p += (size_t)G * HD * 4;
    (void)ws_size; (void)n_in;

    // zero accumulators
    hipMemsetAsync(counts, 0, (size_t)N * 4, stream);
    hipMemsetAsync(gsum, 0, (size_t)G * HD * 4, stream);
    hipMemsetAsync(gmax, 0, (size_t)G * HD * 4, stream);

    const int NB = (N + 255) / 256;

    k_count<<<1024, 256, 0, stream>>>(dst, counts, E);
    k_scan1<<<NB, 256, 0, stream>>>(counts, offs, bsums, N);
    k_scan2<<<1, 256, 0, stream>>>(bsums, NB);
    k_scan3<<<NB, 256, 0, stream>>>(offs, bsums, cursor, N);
    k_dis<<<(N + 255) / 256, 256, 0, stream>>>(counts, dis, N);
    k_fill<<<1024, 256, 0, stream>>>(src, dst, dis, cursor, csr_src, csr_cf, E);
    k_bounds<<<1, 128, 0, stream>>>(batch, starts, N, G);

    // layers
    dim3 ggrid((N + 63) / 64, HD / 64);
    const float* cur_in = x;
    int K = F_IN;
    for (int l = 0; l < L; ++l) {
        const float* W = (l == 0) ? W0 : (Wh + (size_t)(l - 1) * HD * HD);
        if (K == HD)
            k_gemm_t<64><<<ggrid, 256, 0, stream>>>(cur_in, W, hw, N, K);
        else
            k_gemm_t<24><<<ggrid, 256, 0, stream>>>(cur_in, W, hw, N, K);
        k_agg<<<(N + 7) / 8, 256, 0, stream>>>(hw, offs, counts, csr_src, csr_cf, dis,
                                    b + l * HD, bn_gamma + l * HD, bn_beta + l * HD,
                                    bn_mean + l * HD, bn_var + l * HD, h, N);
        cur_in = h;
        K = HD;
    }

    // pooling + head
    dim3 pgrid(G, PSPLIT);
    k_pool<<<pgrid, HD, 0, stream>>>(h, starts, gsum, gmax);
    k_mlp1<<<G, HD, 0, stream>>>(gsum, gmax, starts, pool_W, pool_b, hid);
    k_mlp2<<<G, 64, 0, stream>>>(hid, out_W, out_b, out);
}

// Round 4
// 420.657 us; speedup vs baseline: 2.6916x; 1.3680x over previous
//
#include <hip/hip_runtime.h>
#include <hip/hip_bf16.h>

#define HD 128          // hidden dim
#define BN_EPS 1e-5f
#define PSPLIT 16       // pooling slices per graph

// ---------------- degree count ----------------
__global__ void k_count(const int* __restrict__ dst, int* __restrict__ counts, int E) {
    int i = blockIdx.x * blockDim.x + threadIdx.x;
    for (; i < E; i += gridDim.x * blockDim.x)
        atomicAdd(&counts[dst[i]], 1);
}

// ---------------- exclusive scan (3-kernel) ----------------
__global__ void k_scan1(const int* __restrict__ counts, int* __restrict__ offs,
                        int* __restrict__ bsums, int n) {
    __shared__ int s[256];
    int t = threadIdx.x, i = blockIdx.x * 256 + t;
    int v = (i < n) ? counts[i] : 0;
    s[t] = v; __syncthreads();
    for (int d = 1; d < 256; d <<= 1) {
        int x = (t >= d) ? s[t - d] : 0;
        __syncthreads(); s[t] += x; __syncthreads();
    }
    if (i < n) offs[i] = s[t] - v;
    if (t == 255) bsums[blockIdx.x] = s[255];
}

__global__ void k_scan2(int* __restrict__ bsums, int nb) {
    __shared__ int s[256];
    int t = threadIdx.x;
    int v = (t < nb) ? bsums[t] : 0;
    s[t] = v; __syncthreads();
    for (int d = 1; d < 256; d <<= 1) {
        int x = (t >= d) ? s[t - d] : 0;
        __syncthreads(); s[t] += x; __syncthreads();
    }
    if (t < nb) bsums[t] = s[t] - v;
}

__global__ void k_scan3(int* __restrict__ offs, const int* __restrict__ bsums,
                        int* __restrict__ cursor, int n) {
    int i = blockIdx.x * 256 + threadIdx.x;
    if (i < n) {
        int v = offs[i] + bsums[blockIdx.x];
        offs[i] = v;
        cursor[i] = v;
    }
}

// ---------------- dis = rsqrt(deg) ----------------
__global__ void k_dis(const int* __restrict__ counts, float* __restrict__ dis, int n) {
    int i = blockIdx.x * blockDim.x + threadIdx.x;
    if (i < n) dis[i] = rsqrtf((float)(counts[i] + 1));   // +1 self loop
}

// ---------------- CSR fill ----------------
__global__ void k_fill(const int* __restrict__ src, const int* __restrict__ dst,
                       const float* __restrict__ dis, int* __restrict__ cursor,
                       int* __restrict__ csr_src, float* __restrict__ csr_cf, int E) {
    int i = blockIdx.x * blockDim.x + threadIdx.x;
    for (; i < E; i += gridDim.x * blockDim.x) {
        int s = src[i], d = dst[i];
        int pos = atomicAdd(&cursor[d], 1);
        csr_src[pos] = s;
        csr_cf[pos] = dis[s] * dis[d];
    }
}

// ---------------- aggregation (agg-first): out = Â in, rows of FQ quads ----------------
// GRP lanes per node; lane = feature-quad index (lane >= FQ idle).
template<int FQ, int GRP>
__global__ void k_agg(const float* __restrict__ in, const int* __restrict__ offs,
                      const int* __restrict__ counts, const int* __restrict__ csr_src,
                      const float* __restrict__ csr_cf, const float* __restrict__ dis,
                      float* __restrict__ out, int n) {
    int grp = threadIdx.x / GRP;
    int lane = threadIdx.x % GRP;
    int node = blockIdx.x * (blockDim.x / GRP) + grp;
    if (node >= n || lane >= FQ) return;

    const float4* in4 = reinterpret_cast<const float4*>(in);
    float dn = dis[node];
    float sl = dn * dn;                  // self-loop coef
    float4 a = in4[(size_t)node * FQ + lane];
    float4 acc = make_float4(sl * a.x, sl * a.y, sl * a.z, sl * a.w);

    int e = offs[node], end = e + counts[node];
    for (; e + 1 < end; e += 2) {
        int s0 = csr_src[e], s1 = csr_src[e + 1];
        float c0 = csr_cf[e], c1 = csr_cf[e + 1];
        float4 v0 = in4[(size_t)s0 * FQ + lane];
        float4 v1 = in4[(size_t)s1 * FQ + lane];
        acc.x += c0 * v0.x + c1 * v1.x;
        acc.y += c0 * v0.y + c1 * v1.y;
        acc.z += c0 * v0.z + c1 * v1.z;
        acc.w += c0 * v0.w + c1 * v1.w;
    }
    if (e < end) {
        int s0 = csr_src[e];
        float c0 = csr_cf[e];
        float4 v0 = in4[(size_t)s0 * FQ + lane];
        acc.x += c0 * v0.x; acc.y += c0 * v0.y;
        acc.z += c0 * v0.z; acc.w += c0 * v0.w;
    }
    reinterpret_cast<float4*>(out)[(size_t)node * FQ + lane] = acc;
}

// ---------------- tiled GEMM + fused bias/BN/ReLU ----------------
// out[n,HD] = relu(bn(A[n,K] @ W[K,HD] + bias)); 64 rows x 128 cols per block,
// 256 threads, micro-tile 4 rows x 8 cols.
template<int BK>
__global__ __launch_bounds__(256, 3) void k_gemm_f(
        const float* __restrict__ A, const float* __restrict__ W,
        const float* __restrict__ bias, const float* __restrict__ gamma,
        const float* __restrict__ beta, const float* __restrict__ mean,
        const float* __restrict__ var, float* __restrict__ out, int n, int K) {
    __shared__ float as[64][BK + 4];
    __shared__ float ws[BK][HD + 4];
    constexpr int KQ = BK / 4;

    int tid = threadIdx.x;
    int row0 = blockIdx.x * 64;
    int tx = tid & 15, ty = tid >> 4;   // tx: col group (8 cols), ty: row group (4 rows)

    float acc[4][8] = {};

    for (int kt = 0; kt < K; kt += BK) {
        // stage A tile (row-major): 64 rows x KQ quads, coalesced
        for (int f = tid; f < 64 * KQ; f += 256) {
            int r = f / KQ, kq = f % KQ;
            float4 v = make_float4(0.f, 0.f, 0.f, 0.f);
            if (row0 + r < n)
                v = *reinterpret_cast<const float4*>(A + (size_t)(row0 + r) * K + kt + kq * 4);
            *reinterpret_cast<float4*>(&as[r][kq * 4]) = v;
        }
        // stage W tile: BK rows x 32 quads, coalesced
        for (int f = tid; f < BK * 32; f += 256) {
            int k = f >> 5, cq = f & 31;
            float4 v = *reinterpret_cast<const float4*>(W + (size_t)(kt + k) * HD + cq * 4);
            *reinterpret_cast<float4*>(&ws[k][cq * 4]) = v;
        }
        __syncthreads();

        #pragma unroll 8
        for (int k = 0; k < BK; ++k) {
            float4 w0 = *reinterpret_cast<float4*>(&ws[k][tx * 8]);
            float4 w1 = *reinterpret_cast<float4*>(&ws[k][tx * 8 + 4]);
            #pragma unroll
            for (int r = 0; r < 4; ++r) {
                float a = as[ty * 4 + r][k];
                acc[r][0] += a * w0.x; acc[r][1] += a * w0.y;
                acc[r][2] += a * w0.z; acc[r][3] += a * w0.w;
                acc[r][4] += a * w1.x; acc[r][5] += a * w1.y;
                acc[r][6] += a * w1.z; acc[r][7] += a * w1.w;
            }
        }
        __syncthreads();
    }

    // fused epilogue: out = relu((acc + bias - mean) * gamma/sqrt(var+eps) + beta)
    int c0 = tx * 8;
    float sc[8], sh[8];
    #pragma unroll
    for (int j = 0; j < 8; ++j) {
        float g = gamma[c0 + j], vv = var[c0 + j];
        float m = mean[c0 + j], bb = beta[c0 + j], bi = bias[c0 + j];
        float s = g * rsqrtf(vv + BN_EPS);
        sc[j] = s;
        sh[j] = bb + (bi - m) * s;
    }
    #pragma unroll
    for (int r = 0; r < 4; ++r) {
        int row = row0 + ty * 4 + r;
        if (row < n) {
            float4 o0, o1;
            o0.x = fmaxf(fmaf(acc[r][0], sc[0], sh[0]), 0.f);
            o0.y = fmaxf(fmaf(acc[r][1], sc[1], sh[1]), 0.f);
            o0.z = fmaxf(fmaf(acc[r][2], sc[2], sh[2]), 0.f);
            o0.w = fmaxf(fmaf(acc[r][3], sc[3], sh[3]), 0.f);
            o1.x = fmaxf(fmaf(acc[r][4], sc[4], sh[4]), 0.f);
            o1.y = fmaxf(fmaf(acc[r][5], sc[5], sh[5]), 0.f);
            o1.z = fmaxf(fmaf(acc[r][6], sc[6], sh[6]), 0.f);
            o1.w = fmaxf(fmaf(acc[r][7], sc[7], sh[7]), 0.f);
            *reinterpret_cast<float4*>(out + (size_t)row * HD + c0) = o0;
            *reinterpret_cast<float4*>(out + (size_t)row * HD + c0 + 4) = o1;
        }
    }
}

// ---------------- graph segment boundaries (batch is sorted) ----------------
__global__ void k_bounds(const int* __restrict__ batch, int* __restrict__ starts,
                         int n, int G) {
    int g = threadIdx.x;                 // 0..G inclusive
    if (g > G) return;
    int lo = 0, hi = n;
    while (lo < hi) {                    // lower_bound(batch, g)
        int mid = (lo + hi) >> 1;
        if (batch[mid] < g) lo = mid + 1; else hi = mid;
    }
    starts[g] = lo;
}

// ---------------- pooling: per-graph-slice register reduction ----------------
__global__ void k_pool(const float* __restrict__ h, const int* __restrict__ starts,
                       float* __restrict__ gsum, unsigned int* __restrict__ gmax) {
    int g = blockIdx.x;
    int slice = blockIdx.y;
    int t = threadIdx.x;                 // feature 0..127
    int s = starts[g], e = starts[g + 1];
    int cnt = e - s;
    int per = (cnt + PSPLIT - 1) / PSPLIT;
    int beg = s + slice * per;
    int end = min(beg + per, e);
    if (beg >= end) return;
    float sum = 0.f, mx = 0.f;           // post-ReLU values are >= 0
    for (int node = beg; node < end; ++node) {
        float v = h[(size_t)node * HD + t];
        sum += v;
        mx = fmaxf(mx, v);
    }
    atomicAdd(&gsum[g * HD + t], sum);
    atomicMax(&gmax[g * HD + t], __float_as_uint(mx));
}

// ---------------- pooled MLP layer 1: relu([mean||max] @ pool_W + pool_b) ----------------
__global__ void k_mlp1(const float* __restrict__ gsum, const unsigned int* __restrict__ gmax,
                       const int* __restrict__ starts, const float* __restrict__ pool_W,
                       const float* __restrict__ pool_b, float* __restrict__ hid) {
    int g = blockIdx.x, t = threadIdx.x;   // t in [0,128)
    __shared__ float pooled[2 * HD];
    float cntf = fmaxf((float)(starts[g + 1] - starts[g]), 1.f);
    pooled[t] = gsum[g * HD + t] / cntf;
    pooled[HD + t] = __uint_as_float(gmax[g * HD + t]);
    __syncthreads();
    float acc = pool_b[t];
    for (int k = 0; k < 2 * HD; ++k)
        acc += pooled[k] * pool_W[k * HD + t];
    hid[g * HD + t] = fmaxf(acc, 0.f);
}

// ---------------- final head: hid @ out_W + out_b ----------------
__global__ void k_mlp2(const float* __restrict__ hid, const float* __restrict__ out_W,
                       const float* __restrict__ out_b, float* __restrict__ out) {
    int g = blockIdx.x, o = threadIdx.x;   // o in [0,64)
    __shared__ float hv[HD];
    hv[o] = hid[g * HD + o];
    hv[o + 64] = hid[g * HD + o + 64];
    __syncthreads();
    float acc = out_b[o];
    for (int j = 0; j < HD; ++j)
        acc += hv[j] * out_W[j * 64 + o];
    out[g * 64 + o] = acc;
}

extern "C" void kernel_launch(void* const* d_in, const int* in_sizes, int n_in,
                              void* d_out, int out_size, void* d_ws, size_t ws_size,
                              hipStream_t stream) {
    const float* x        = (const float*)d_in[0];
    const int*   eidx     = (const int*)d_in[1];
    const int*   batch    = (const int*)d_in[2];
    const float* W0       = (const float*)d_in[3];
    const float* Wh       = (const float*)d_in[4];
    const float* b        = (const float*)d_in[5];
    const float* bn_gamma = (const float*)d_in[6];
    const float* bn_beta  = (const float*)d_in[7];
    const float* bn_mean  = (const float*)d_in[8];
    const float* bn_var   = (const float*)d_in[9];
    const float* pool_W   = (const float*)d_in[10];
    const float* pool_b   = (const float*)d_in[11];
    const float* out_W    = (const float*)d_in[12];
    const float* out_b    = (const float*)d_in[13];
    float* out = (float*)d_out;

    const int N = in_sizes[2];
    const int E = in_sizes[1] / 2;
    const int F_IN = in_sizes[0] / N;    // 24
    const int L = in_sizes[5] / HD;
    const int G = out_size / (HD / 2);

    const int* src = eidx;
    const int* dst = eidx + E;

    // workspace layout (all 4-byte types)
    char* p = (char*)d_ws;
    float* h       = (float*)p; p += (size_t)N * HD * 4;   // layer output
    float* ag      = (float*)p; p += (size_t)N * HD * 4;   // aggregated input (also N x F_IN)
    int*   counts  = (int*)p;   p += (size_t)N * 4;
    float* dis     = (float*)p; p += (size_t)N * 4;
    int*   offs    = (int*)p;   p += (size_t)(N + 1) * 4;
    int*   cursor  = (int*)p;   p += (size_t)N * 4;
    int*   csr_src = (int*)p;   p += (size_t)E * 4;
    float* csr_cf  = (float*)p; p += (size_t)E * 4;
    int*   bsums   = (int*)p;   p += 256 * 4;
    float* gsum    = (float*)p; p += (size_t)G * HD * 4;
    unsigned int* gmax = (unsigned int*)p; p += (size_t)G * HD * 4;
    int*   starts  = (int*)p;   p += (size_t)(G + 1) * 4;
    float* hid     = (float*)p; p += (size_t)G * HD * 4;
    (void)ws_size; (void)n_in; (void)F_IN;

    // zero accumulators
    hipMemsetAsync(counts, 0, (size_t)N * 4, stream);
    hipMemsetAsync(gsum, 0, (size_t)G * HD * 4, stream);
    hipMemsetAsync(gmax, 0, (size_t)G * HD * 4, stream);

    const int NB = (N + 255) / 256;

    k_count<<<1024, 256, 0, stream>>>(dst, counts, E);
    k_scan1<<<NB, 256, 0, stream>>>(counts, offs, bsums, N);
    k_scan2<<<1, 256, 0, stream>>>(bsums, NB);
    k_scan3<<<NB, 256, 0, stream>>>(offs, bsums, cursor, N);
    k_dis<<<(N + 255) / 256, 256, 0, stream>>>(counts, dis, N);
    k_fill<<<1024, 256, 0, stream>>>(src, dst, dis, cursor, csr_src, csr_cf, E);
    k_bounds<<<1, 128, 0, stream>>>(batch, starts, N, G);

    const int GEMM_GRID = (N + 63) / 64;

    // layer 0: aggregate x (24 features), then GEMM 24->128 with fused BN/ReLU
    k_agg<6, 8><<<(N + 31) / 32, 256, 0, stream>>>(x, offs, counts, csr_src, csr_cf,
                                                   dis, ag, N);
    k_gemm_f<24><<<GEMM_GRID, 256, 0, stream>>>(ag, W0, b, bn_gamma, bn_beta,
                                                bn_mean, bn_var, h, N, 24);

    // layers 1..L-1: aggregate h (128), GEMM 128->128 fused
    for (int l = 1; l < L; ++l) {
        const float* W = Wh + (size_t)(l - 1) * HD * HD;
        k_agg<32, 32><<<(N + 7) / 8, 256, 0, stream>>>(h, offs, counts, csr_src,
                                                       csr_cf, dis, ag, N);
        k_gemm_f<64><<<GEMM_GRID, 256, 0, stream>>>(ag, W, b + l * HD,
                                                    bn_gamma + l * HD, bn_beta + l * HD,
                                                    bn_mean + l * HD, bn_var + l * HD,
                                                    h, N, HD);
    }

    // pooling + head
    dim3 pgrid(G, PSPLIT);
    k_pool<<<pgrid, HD, 0, stream>>>(h, starts, gsum, gmax);
    k_mlp1<<<G, HD, 0, stream>>>(gsum, gmax, starts, pool_W, pool_b, hid);
    k_mlp2<<<G, 64, 0, stream>>>(hid, out_W, out_b, out);
}

// Round 5
// 404.997 us; speedup vs baseline: 2.7957x; 1.0387x over previous
//
#include <hip/hip_runtime.h>
#include <hip/hip_bf16.h>

#define HD 128          // hidden dim
#define BN_EPS 1e-5f
#define PSPLIT 16       // pooling slices per graph

// ---------------- degree count ----------------
__global__ void k_count(const int* __restrict__ dst, int* __restrict__ counts, int E) {
    int i = blockIdx.x * blockDim.x + threadIdx.x;
    for (; i < E; i += gridDim.x * blockDim.x)
        atomicAdd(&counts[dst[i]], 1);
}

// ---------------- exclusive scan (3-kernel) ----------------
__global__ void k_scan1(const int* __restrict__ counts, int* __restrict__ offs,
                        int* __restrict__ bsums, int n) {
    __shared__ int s[256];
    int t = threadIdx.x, i = blockIdx.x * 256 + t;
    int v = (i < n) ? counts[i] : 0;
    s[t] = v; __syncthreads();
    for (int d = 1; d < 256; d <<= 1) {
        int x = (t >= d) ? s[t - d] : 0;
        __syncthreads(); s[t] += x; __syncthreads();
    }
    if (i < n) offs[i] = s[t] - v;
    if (t == 255) bsums[blockIdx.x] = s[255];
}

__global__ void k_scan2(int* __restrict__ bsums, int nb) {
    __shared__ int s[256];
    int t = threadIdx.x;
    int v = (t < nb) ? bsums[t] : 0;
    s[t] = v; __syncthreads();
    for (int d = 1; d < 256; d <<= 1) {
        int x = (t >= d) ? s[t - d] : 0;
        __syncthreads(); s[t] += x; __syncthreads();
    }
    if (t < nb) bsums[t] = s[t] - v;
}

__global__ void k_scan3(int* __restrict__ offs, const int* __restrict__ bsums,
                        int* __restrict__ cursor, int n) {
    int i = blockIdx.x * 256 + threadIdx.x;
    if (i < n) {
        int v = offs[i] + bsums[blockIdx.x];
        offs[i] = v;
        cursor[i] = v;
    }
}

// ---------------- dis = rsqrt(deg) ----------------
__global__ void k_dis(const int* __restrict__ counts, float* __restrict__ dis, int n) {
    int i = blockIdx.x * blockDim.x + threadIdx.x;
    if (i < n) dis[i] = rsqrtf((float)(counts[i] + 1));   // +1 self loop
}

// ---------------- CSR fill: packed (src, coef) records ----------------
__global__ void k_fill(const int* __restrict__ src, const int* __restrict__ dst,
                       const float* __restrict__ dis, int* __restrict__ cursor,
                       int2* __restrict__ ecsr, int E) {
    int i = blockIdx.x * blockDim.x + threadIdx.x;
    for (; i < E; i += gridDim.x * blockDim.x) {
        int s = src[i], d = dst[i];
        int pos = atomicAdd(&cursor[d], 1);
        ecsr[pos] = make_int2(s, __float_as_int(dis[s] * dis[d]));
    }
}

// ---------------- aggregation (agg-first): out = Â in, rows of FQ quads ----------------
// GRP lanes per node; lane = feature-quad index (lane >= FQ idle).
template<int FQ, int GRP>
__global__ void k_agg(const float* __restrict__ in, const int* __restrict__ offs,
                      const int* __restrict__ counts, const int2* __restrict__ ecsr,
                      const float* __restrict__ dis, float* __restrict__ out, int n) {
    int grp = threadIdx.x / GRP;
    int lane = threadIdx.x % GRP;
    int node = blockIdx.x * (blockDim.x / GRP) + grp;
    if (node >= n || lane >= FQ) return;

    const float4* in4 = reinterpret_cast<const float4*>(in);
    float dn = dis[node];
    float sl = dn * dn;                  // self-loop coef
    float4 a = in4[(size_t)node * FQ + lane];
    float4 accA = make_float4(sl * a.x, sl * a.y, sl * a.z, sl * a.w);
    float4 accB = make_float4(0.f, 0.f, 0.f, 0.f);

    int e = offs[node], end = e + counts[node];
    for (; e + 3 < end; e += 4) {
        int2 r0 = ecsr[e], r1 = ecsr[e + 1], r2 = ecsr[e + 2], r3 = ecsr[e + 3];
        float4 v0 = in4[(size_t)r0.x * FQ + lane];
        float4 v1 = in4[(size_t)r1.x * FQ + lane];
        float4 v2 = in4[(size_t)r2.x * FQ + lane];
        float4 v3 = in4[(size_t)r3.x * FQ + lane];
        float c0 = __int_as_float(r0.y), c1 = __int_as_float(r1.y);
        float c2 = __int_as_float(r2.y), c3 = __int_as_float(r3.y);
        accA.x = fmaf(c0, v0.x, fmaf(c2, v2.x, accA.x));
        accA.y = fmaf(c0, v0.y, fmaf(c2, v2.y, accA.y));
        accA.z = fmaf(c0, v0.z, fmaf(c2, v2.z, accA.z));
        accA.w = fmaf(c0, v0.w, fmaf(c2, v2.w, accA.w));
        accB.x = fmaf(c1, v1.x, fmaf(c3, v3.x, accB.x));
        accB.y = fmaf(c1, v1.y, fmaf(c3, v3.y, accB.y));
        accB.z = fmaf(c1, v1.z, fmaf(c3, v3.z, accB.z));
        accB.w = fmaf(c1, v1.w, fmaf(c3, v3.w, accB.w));
    }
    for (; e < end; ++e) {
        int2 r0 = ecsr[e];
        float c0 = __int_as_float(r0.y);
        float4 v0 = in4[(size_t)r0.x * FQ + lane];
        accA.x = fmaf(c0, v0.x, accA.x);
        accA.y = fmaf(c0, v0.y, accA.y);
        accA.z = fmaf(c0, v0.z, accA.z);
        accA.w = fmaf(c0, v0.w, accA.w);
    }
    float4 acc = make_float4(accA.x + accB.x, accA.y + accB.y,
                             accA.z + accB.z, accA.w + accB.w);
    reinterpret_cast<float4*>(out)[(size_t)node * FQ + lane] = acc;
}

// ---------------- tiled GEMM + fused bias/BN/ReLU ----------------
// out[n,HD] = relu(bn(A[n,K] @ W[K,HD] + bias)); 64 rows x 128 cols per block,
// 256 threads, micro-tile 4 rows x 8 cols.
template<int BK>
__global__ __launch_bounds__(256, 3) void k_gemm_f(
        const float* __restrict__ A, const float* __restrict__ W,
        const float* __restrict__ bias, const float* __restrict__ gamma,
        const float* __restrict__ beta, const float* __restrict__ mean,
        const float* __restrict__ var, float* __restrict__ out, int n, int K) {
    __shared__ float as[64][BK + 4];
    __shared__ float ws[BK][HD + 4];
    constexpr int KQ = BK / 4;

    int tid = threadIdx.x;
    int row0 = blockIdx.x * 64;
    int tx = tid & 15, ty = tid >> 4;   // tx: col group (8 cols), ty: row group (4 rows)

    float acc[4][8] = {};

    for (int kt = 0; kt < K; kt += BK) {
        // stage A tile (row-major): 64 rows x KQ quads, coalesced
        for (int f = tid; f < 64 * KQ; f += 256) {
            int r = f / KQ, kq = f % KQ;
            float4 v = make_float4(0.f, 0.f, 0.f, 0.f);
            if (row0 + r < n)
                v = *reinterpret_cast<const float4*>(A + (size_t)(row0 + r) * K + kt + kq * 4);
            *reinterpret_cast<float4*>(&as[r][kq * 4]) = v;
        }
        // stage W tile: BK rows x 32 quads, coalesced
        for (int f = tid; f < BK * 32; f += 256) {
            int k = f >> 5, cq = f & 31;
            float4 v = *reinterpret_cast<const float4*>(W + (size_t)(kt + k) * HD + cq * 4);
            *reinterpret_cast<float4*>(&ws[k][cq * 4]) = v;
        }
        __syncthreads();

        #pragma unroll 8
        for (int k = 0; k < BK; ++k) {
            float4 w0 = *reinterpret_cast<float4*>(&ws[k][tx * 8]);
            float4 w1 = *reinterpret_cast<float4*>(&ws[k][tx * 8 + 4]);
            #pragma unroll
            for (int r = 0; r < 4; ++r) {
                float a = as[ty * 4 + r][k];
                acc[r][0] += a * w0.x; acc[r][1] += a * w0.y;
                acc[r][2] += a * w0.z; acc[r][3] += a * w0.w;
                acc[r][4] += a * w1.x; acc[r][5] += a * w1.y;
                acc[r][6] += a * w1.z; acc[r][7] += a * w1.w;
            }
        }
        __syncthreads();
    }

    // fused epilogue: out = relu((acc + bias - mean) * gamma/sqrt(var+eps) + beta)
    int c0 = tx * 8;
    float sc[8], sh[8];
    #pragma unroll
    for (int j = 0; j < 8; ++j) {
        float g = gamma[c0 + j], vv = var[c0 + j];
        float m = mean[c0 + j], bb = beta[c0 + j], bi = bias[c0 + j];
        float s = g * rsqrtf(vv + BN_EPS);
        sc[j] = s;
        sh[j] = bb + (bi - m) * s;
    }
    #pragma unroll
    for (int r = 0; r < 4; ++r) {
        int row = row0 + ty * 4 + r;
        if (row < n) {
            float4 o0, o1;
            o0.x = fmaxf(fmaf(acc[r][0], sc[0], sh[0]), 0.f);
            o0.y = fmaxf(fmaf(acc[r][1], sc[1], sh[1]), 0.f);
            o0.z = fmaxf(fmaf(acc[r][2], sc[2], sh[2]), 0.f);
            o0.w = fmaxf(fmaf(acc[r][3], sc[3], sh[3]), 0.f);
            o1.x = fmaxf(fmaf(acc[r][4], sc[4], sh[4]), 0.f);
            o1.y = fmaxf(fmaf(acc[r][5], sc[5], sh[5]), 0.f);
            o1.z = fmaxf(fmaf(acc[r][6], sc[6], sh[6]), 0.f);
            o1.w = fmaxf(fmaf(acc[r][7], sc[7], sh[7]), 0.f);
            *reinterpret_cast<float4*>(out + (size_t)row * HD + c0) = o0;
            *reinterpret_cast<float4*>(out + (size_t)row * HD + c0 + 4) = o1;
        }
    }
}

// ---------------- graph segment boundaries (batch is sorted) ----------------
__global__ void k_bounds(const int* __restrict__ batch, int* __restrict__ starts,
                         int n, int G) {
    int g = threadIdx.x;                 // 0..G inclusive
    if (g > G) return;
    int lo = 0, hi = n;
    while (lo < hi) {                    // lower_bound(batch, g)
        int mid = (lo + hi) >> 1;
        if (batch[mid] < g) lo = mid + 1; else hi = mid;
    }
    starts[g] = lo;
}

// ---------------- pooling: per-graph-slice register reduction ----------------
__global__ void k_pool(const float* __restrict__ h, const int* __restrict__ starts,
                       float* __restrict__ gsum, unsigned int* __restrict__ gmax) {
    int g = blockIdx.x;
    int slice = blockIdx.y;
    int t = threadIdx.x;                 // feature 0..127
    int s = starts[g], e = starts[g + 1];
    int cnt = e - s;
    int per = (cnt + PSPLIT - 1) / PSPLIT;
    int beg = s + slice * per;
    int end = min(beg + per, e);
    if (beg >= end) return;
    float sum = 0.f, mx = 0.f;           // post-ReLU values are >= 0
    for (int node = beg; node < end; ++node) {
        float v = h[(size_t)node * HD + t];
        sum += v;
        mx = fmaxf(mx, v);
    }
    atomicAdd(&gsum[g * HD + t], sum);
    atomicMax(&gmax[g * HD + t], __float_as_uint(mx));
}

// ---------------- pooled MLP layer 1: relu([mean||max] @ pool_W + pool_b) ----------------
__global__ void k_mlp1(const float* __restrict__ gsum, const unsigned int* __restrict__ gmax,
                       const int* __restrict__ starts, const float* __restrict__ pool_W,
                       const float* __restrict__ pool_b, float* __restrict__ hid) {
    int g = blockIdx.x, t = threadIdx.x;   // t in [0,128)
    __shared__ float pooled[2 * HD];
    float cntf = fmaxf((float)(starts[g + 1] - starts[g]), 1.f);
    pooled[t] = gsum[g * HD + t] / cntf;
    pooled[HD + t] = __uint_as_float(gmax[g * HD + t]);
    __syncthreads();
    float acc = pool_b[t];
    for (int k = 0; k < 2 * HD; ++k)
        acc += pooled[k] * pool_W[k * HD + t];
    hid[g * HD + t] = fmaxf(acc, 0.f);
}

// ---------------- final head: hid @ out_W + out_b ----------------
__global__ void k_mlp2(const float* __restrict__ hid, const float* __restrict__ out_W,
                       const float* __restrict__ out_b, float* __restrict__ out) {
    int g = blockIdx.x, o = threadIdx.x;   // o in [0,64)
    __shared__ float hv[HD];
    hv[o] = hid[g * HD + o];
    hv[o + 64] = hid[g * HD + o + 64];
    __syncthreads();
    float acc = out_b[o];
    for (int j = 0; j < HD; ++j)
        acc += hv[j] * out_W[j * 64 + o];
    out[g * 64 + o] = acc;
}

extern "C" void kernel_launch(void* const* d_in, const int* in_sizes, int n_in,
                              void* d_out, int out_size, void* d_ws, size_t ws_size,
                              hipStream_t stream) {
    const float* x        = (const float*)d_in[0];
    const int*   eidx     = (const int*)d_in[1];
    const int*   batch    = (const int*)d_in[2];
    const float* W0       = (const float*)d_in[3];
    const float* Wh       = (const float*)d_in[4];
    const float* b        = (const float*)d_in[5];
    const float* bn_gamma = (const float*)d_in[6];
    const float* bn_beta  = (const float*)d_in[7];
    const float* bn_mean  = (const float*)d_in[8];
    const float* bn_var   = (const float*)d_in[9];
    const float* pool_W   = (const float*)d_in[10];
    const float* pool_b   = (const float*)d_in[11];
    const float* out_W    = (const float*)d_in[12];
    const float* out_b    = (const float*)d_in[13];
    float* out = (float*)d_out;

    const int N = in_sizes[2];
    const int E = in_sizes[1] / 2;
    const int F_IN = in_sizes[0] / N;    // 24
    const int L = in_sizes[5] / HD;
    const int G = out_size / (HD / 2);

    const int* src = eidx;
    const int* dst = eidx + E;

    // workspace layout (8B-aligned arrays first)
    char* p = (char*)d_ws;
    float* h       = (float*)p; p += (size_t)N * HD * 4;   // layer output
    float* ag      = (float*)p; p += (size_t)N * HD * 4;   // aggregated input
    int2*  ecsr    = (int2*)p;  p += (size_t)E * 8;        // packed (src, coef)
    int*   counts  = (int*)p;   p += (size_t)N * 4;
    float* dis     = (float*)p; p += (size_t)N * 4;
    int*   offs    = (int*)p;   p += (size_t)(N + 1) * 4;
    int*   cursor  = (int*)p;   p += (size_t)N * 4;
    int*   bsums   = (int*)p;   p += 256 * 4;
    float* gsum    = (float*)p; p += (size_t)G * HD * 4;
    unsigned int* gmax = (unsigned int*)p; p += (size_t)G * HD * 4;
    int*   starts  = (int*)p;   p += (size_t)(G + 1) * 4;
    float* hid     = (float*)p; p += (size_t)G * HD * 4;
    (void)ws_size; (void)n_in; (void)F_IN;

    // zero accumulators
    hipMemsetAsync(counts, 0, (size_t)N * 4, stream);
    hipMemsetAsync(gsum, 0, (size_t)G * HD * 4, stream);
    hipMemsetAsync(gmax, 0, (size_t)G * HD * 4, stream);

    const int NB = (N + 255) / 256;

    k_count<<<1024, 256, 0, stream>>>(dst, counts, E);
    k_scan1<<<NB, 256, 0, stream>>>(counts, offs, bsums, N);
    k_scan2<<<1, 256, 0, stream>>>(bsums, NB);
    k_scan3<<<NB, 256, 0, stream>>>(offs, bsums, cursor, N);
    k_dis<<<(N + 255) / 256, 256, 0, stream>>>(counts, dis, N);
    k_fill<<<1024, 256, 0, stream>>>(src, dst, dis, cursor, ecsr, E);
    k_bounds<<<1, 128, 0, stream>>>(batch, starts, N, G);

    const int GEMM_GRID = (N + 63) / 64;

    // layer 0: aggregate x (24 features), then GEMM 24->128 with fused BN/ReLU
    k_agg<6, 8><<<(N + 31) / 32, 256, 0, stream>>>(x, offs, counts, ecsr, dis, ag, N);
    k_gemm_f<24><<<GEMM_GRID, 256, 0, stream>>>(ag, W0, b, bn_gamma, bn_beta,
                                                bn_mean, bn_var, h, N, 24);

    // layers 1..L-1: aggregate h (128), GEMM 128->128 fused
    for (int l = 1; l < L; ++l) {
        const float* W = Wh + (size_t)(l - 1) * HD * HD;
        k_agg<32, 32><<<(N + 7) / 8, 256, 0, stream>>>(h, offs, counts, ecsr, dis, ag, N);
        k_gemm_f<64><<<GEMM_GRID, 256, 0, stream>>>(ag, W, b + l * HD,
                                                    bn_gamma + l * HD, bn_beta + l * HD,
                                                    bn_mean + l * HD, bn_var + l * HD,
                                                    h, N, HD);
    }

    // pooling + head
    dim3 pgrid(G, PSPLIT);
    k_pool<<<pgrid, HD, 0, stream>>>(h, starts, gsum, gmax);
    k_mlp1<<<G, HD, 0, stream>>>(gsum, gmax, starts, pool_W, pool_b, hid);
    k_mlp2<<<G, 64, 0, stream>>>(hid, out_W, out_b, out);
}

// Round 6
// 347.416 us; speedup vs baseline: 3.2590x; 1.1657x over previous
//
#include <hip/hip_runtime.h>
#include <hip/hip_bf16.h>

#define HD 128          // hidden dim
#define BN_EPS 1e-5f
#define PSPLIT 16       // pooling slices per graph

typedef __attribute__((ext_vector_type(8))) short short8;
typedef __attribute__((ext_vector_type(4))) float f32x4;

// round-to-nearest-even f32 -> bf16 bits; rem = v - bf16(v)
__device__ inline unsigned short f2bf(float v, float& rem) {
    unsigned u = __float_as_uint(v);
    unsigned r = (u + 0x7FFFu + ((u >> 16) & 1u)) >> 16;
    rem = v - __uint_as_float(r << 16);
    return (unsigned short)r;
}

// ---------------- degree count ----------------
__global__ void k_count(const int* __restrict__ dst, int* __restrict__ counts, int E) {
    int i = blockIdx.x * blockDim.x + threadIdx.x;
    for (; i < E; i += gridDim.x * blockDim.x)
        atomicAdd(&counts[dst[i]], 1);
}

// ---------------- exclusive scan (3-kernel) ----------------
__global__ void k_scan1(const int* __restrict__ counts, int* __restrict__ offs,
                        int* __restrict__ bsums, int n) {
    __shared__ int s[256];
    int t = threadIdx.x, i = blockIdx.x * 256 + t;
    int v = (i < n) ? counts[i] : 0;
    s[t] = v; __syncthreads();
    for (int d = 1; d < 256; d <<= 1) {
        int x = (t >= d) ? s[t - d] : 0;
        __syncthreads(); s[t] += x; __syncthreads();
    }
    if (i < n) offs[i] = s[t] - v;
    if (t == 255) bsums[blockIdx.x] = s[255];
}

__global__ void k_scan2(int* __restrict__ bsums, int nb) {
    __shared__ int s[256];
    int t = threadIdx.x;
    int v = (t < nb) ? bsums[t] : 0;
    s[t] = v; __syncthreads();
    for (int d = 1; d < 256; d <<= 1) {
        int x = (t >= d) ? s[t - d] : 0;
        __syncthreads(); s[t] += x; __syncthreads();
    }
    if (t < nb) bsums[t] = s[t] - v;
}

__global__ void k_scan3(int* __restrict__ offs, const int* __restrict__ bsums,
                        int* __restrict__ cursor, int n) {
    int i = blockIdx.x * 256 + threadIdx.x;
    if (i < n) {
        int v = offs[i] + bsums[blockIdx.x];
        offs[i] = v;
        cursor[i] = v;
    }
}

// ---------------- dis = rsqrt(deg) ----------------
__global__ void k_dis(const int* __restrict__ counts, float* __restrict__ dis, int n) {
    int i = blockIdx.x * blockDim.x + threadIdx.x;
    if (i < n) dis[i] = rsqrtf((float)(counts[i] + 1));   // +1 self loop
}

// ---------------- CSR fill: u16 src records (coef recomputed later) ----------------
__global__ void k_fill(const int* __restrict__ src, const int* __restrict__ dst,
                       int* __restrict__ cursor, unsigned short* __restrict__ esrc, int E) {
    int i = blockIdx.x * blockDim.x + threadIdx.x;
    for (; i < E; i += gridDim.x * blockDim.x) {
        int s = src[i], d = dst[i];
        int pos = atomicAdd(&cursor[d], 1);
        esrc[pos] = (unsigned short)s;
    }
}

// ---------------- W split to bf16 hi/lo in MFMA B-fragment layout ----------------
// layer 0: K padded to 32, KC=1 layout; layers 1..3: K=128, KC=4 layout.
__global__ void k_wsplit(const float* __restrict__ W0, const float* __restrict__ Wh,
                         unsigned short* __restrict__ whi, unsigned short* __restrict__ wlo) {
    int idx = blockIdx.x * 256 + threadIdx.x;     // 4 * 128 * 128
    int l = idx >> 14, rest = idx & 16383;
    int k = rest >> 7, c = rest & 127;
    float val;
    if (l == 0) {
        if (k >= 32) return;
        val = (k < 24) ? W0[k * HD + c] : 0.f;
    } else {
        val = Wh[(size_t)(l - 1) * HD * HD + (size_t)k * HD + c];
    }
    float rem, rem2;
    unsigned short hi = f2bf(val, rem);
    unsigned short lo = f2bf(rem, rem2);
    int cb = c >> 4, kc = k >> 5;
    int lane = (c & 15) | (((k & 31) >> 3) << 4);
    int j = k & 7;
    size_t addr;
    if (l == 0) addr = (size_t)(cb * 64 + lane) * 8 + j;                  // KC=1
    else        addr = (size_t)l * 16384 + (size_t)((cb * 4 + kc) * 64 + lane) * 8 + j;
    whi[addr] = hi; wlo[addr] = lo;
}

// ---------------- aggregation: out = Â in, emitted as bf16 hi/lo A-fragments ----
// GRP lanes per node; lane = feature-quad index. KCA = k-chunks per rowblock.
template<int FQ, int GRP, int KCA, bool TAIL>
__global__ void k_agg(const float* __restrict__ in, const int* __restrict__ offs,
                      const int* __restrict__ counts, const unsigned short* __restrict__ esrc,
                      const float* __restrict__ dis, unsigned short* __restrict__ ohi,
                      unsigned short* __restrict__ olo, int n) {
    int grp = threadIdx.x / GRP;
    int lane = threadIdx.x % GRP;
    int node = blockIdx.x * (blockDim.x / GRP) + grp;
    if (node >= n) return;
    int rowblk = node >> 4, rr = node & 15;

    if (TAIL && lane == FQ) {          // zero-fill features 24..31 (layer-0 K pad)
        size_t base = ((size_t)rowblk * KCA) * 512 + (size_t)(rr + 48) * 8;
        ushort4 z = make_ushort4(0, 0, 0, 0);
        *(ushort4*)(ohi + base) = z; *(ushort4*)(ohi + base + 4) = z;
        *(ushort4*)(olo + base) = z; *(ushort4*)(olo + base + 4) = z;
    }
    if (lane >= FQ) return;

    const float4* in4 = reinterpret_cast<const float4*>(in);
    float dn = dis[node];
    float sl = dn * dn;                  // self-loop coef
    float4 a = in4[(size_t)node * FQ + lane];
    float4 accA = make_float4(sl * a.x, sl * a.y, sl * a.z, sl * a.w);
    float4 accB = make_float4(0.f, 0.f, 0.f, 0.f);

    int e = offs[node], end = e + counts[node];
    for (; e + 3 < end; e += 4) {
        int s0 = esrc[e],     s1 = esrc[e + 1];
        int s2 = esrc[e + 2], s3 = esrc[e + 3];
        float c0 = dis[s0] * dn, c1 = dis[s1] * dn;
        float c2 = dis[s2] * dn, c3 = dis[s3] * dn;
        float4 v0 = in4[(size_t)s0 * FQ + lane];
        float4 v1 = in4[(size_t)s1 * FQ + lane];
        float4 v2 = in4[(size_t)s2 * FQ + lane];
        float4 v3 = in4[(size_t)s3 * FQ + lane];
        accA.x = fmaf(c0, v0.x, fmaf(c2, v2.x, accA.x));
        accA.y = fmaf(c0, v0.y, fmaf(c2, v2.y, accA.y));
        accA.z = fmaf(c0, v0.z, fmaf(c2, v2.z, accA.z));
        accA.w = fmaf(c0, v0.w, fmaf(c2, v2.w, accA.w));
        accB.x = fmaf(c1, v1.x, fmaf(c3, v3.x, accB.x));
        accB.y = fmaf(c1, v1.y, fmaf(c3, v3.y, accB.y));
        accB.z = fmaf(c1, v1.z, fmaf(c3, v3.z, accB.z));
        accB.w = fmaf(c1, v1.w, fmaf(c3, v3.w, accB.w));
    }
    for (; e < end; ++e) {
        int s0 = esrc[e];
        float c0 = dis[s0] * dn;
        float4 v0 = in4[(size_t)s0 * FQ + lane];
        accA.x = fmaf(c0, v0.x, accA.x);
        accA.y = fmaf(c0, v0.y, accA.y);
        accA.z = fmaf(c0, v0.z, accA.z);
        accA.w = fmaf(c0, v0.w, accA.w);
    }
    float4 acc = make_float4(accA.x + accB.x, accA.y + accB.y,
                             accA.z + accB.z, accA.w + accB.w);

    // emit bf16 hi/lo in MFMA A-frag layout
    int f0 = lane * 4;
    int kc = f0 >> 5;
    int lidx = rr | (((f0 & 31) >> 3) << 4);
    int j0 = f0 & 7;
    size_t base = ((size_t)rowblk * KCA + kc) * 512 + (size_t)lidx * 8 + j0;
    float r0, r1, r2, r3, d0;
    ushort4 hi, lo;
    hi.x = f2bf(acc.x, r0); hi.y = f2bf(acc.y, r1);
    hi.z = f2bf(acc.z, r2); hi.w = f2bf(acc.w, r3);
    lo.x = f2bf(r0, d0); lo.y = f2bf(r1, d0);
    lo.z = f2bf(r2, d0); lo.w = f2bf(r3, d0);
    *(ushort4*)(ohi + base) = hi;
    *(ushort4*)(olo + base) = lo;
}

// ---------------- MFMA GEMM + fused bias/BN/ReLU ----------------
// 128 rows x 128 cols per 256-thread block (4 waves x 2 rowblocks).
// A from packed hi/lo frags (global); W-split staged in LDS.
template<int KC>
__global__ __launch_bounds__(256) void k_gemm_m(
        const unsigned short* __restrict__ agh, const unsigned short* __restrict__ agl,
        const unsigned short* __restrict__ wh, const unsigned short* __restrict__ wl,
        const float* __restrict__ bias, const float* __restrict__ gamma,
        const float* __restrict__ beta, const float* __restrict__ mean,
        const float* __restrict__ var, float* __restrict__ out, int n) {
    __shared__ unsigned short lbh[8 * KC * 512];
    __shared__ unsigned short lbl[8 * KC * 512];
    int tid = threadIdx.x;
    for (int i = tid; i < 1024 * KC; i += 256) {
        ((ushort4*)lbh)[i] = ((const ushort4*)wh)[i];
        ((ushort4*)lbl)[i] = ((const ushort4*)wl)[i];
    }
    __syncthreads();

    int wave = tid >> 6, lane = tid & 63;
    int grb0 = blockIdx.x * 8 + wave * 2;

    f32x4 acc[2][8] = {};

    for (int kc = 0; kc < KC; ++kc) {
        short8 a0h = *(const short8*)(agh + ((size_t)grb0 * KC + kc) * 512 + lane * 8);
        short8 a0l = *(const short8*)(agl + ((size_t)grb0 * KC + kc) * 512 + lane * 8);
        short8 a1h = *(const short8*)(agh + ((size_t)(grb0 + 1) * KC + kc) * 512 + lane * 8);
        short8 a1l = *(const short8*)(agl + ((size_t)(grb0 + 1) * KC + kc) * 512 + lane * 8);
        #pragma unroll
        for (int cb = 0; cb < 8; ++cb) {
            short8 bh = *(const short8*)(lbh + (size_t)((cb * KC + kc) * 64 + lane) * 8);
            short8 bl = *(const short8*)(lbl + (size_t)((cb * KC + kc) * 64 + lane) * 8);
            acc[0][cb] = __builtin_amdgcn_mfma_f32_16x16x32_bf16(a0h, bh, acc[0][cb], 0, 0, 0);
            acc[0][cb] = __builtin_amdgcn_mfma_f32_16x16x32_bf16(a0h, bl, acc[0][cb], 0, 0, 0);
            acc[0][cb] = __builtin_amdgcn_mfma_f32_16x16x32_bf16(a0l, bh, acc[0][cb], 0, 0, 0);
            acc[1][cb] = __builtin_amdgcn_mfma_f32_16x16x32_bf16(a1h, bh, acc[1][cb], 0, 0, 0);
            acc[1][cb] = __builtin_amdgcn_mfma_f32_16x16x32_bf16(a1h, bl, acc[1][cb], 0, 0, 0);
            acc[1][cb] = __builtin_amdgcn_mfma_f32_16x16x32_bf16(a1l, bh, acc[1][cb], 0, 0, 0);
        }
    }

    // epilogue: relu((acc + bias - mean) * gamma/sqrt(var+eps) + beta)
    int colbase = lane & 15;
    float scv[8], shv[8];
    #pragma unroll
    for (int cb = 0; cb < 8; ++cb) {
        int c = cb * 16 + colbase;
        float s = gamma[c] * rsqrtf(var[c] + BN_EPS);
        scv[cb] = s;
        shv[cb] = beta[c] + (bias[c] - mean[c]) * s;
    }
    int r0 = (lane >> 4) * 4;
    #pragma unroll
    for (int rb = 0; rb < 2; ++rb) {
        int rowb = (grb0 + rb) * 16 + r0;
        #pragma unroll
        for (int rg = 0; rg < 4; ++rg) {
            int row = rowb + rg;
            if (row < n) {
                #pragma unroll
                for (int cb = 0; cb < 8; ++cb) {
                    float v = fmaf(acc[rb][cb][rg], scv[cb], shv[cb]);
                    out[(size_t)row * HD + cb * 16 + colbase] = fmaxf(v, 0.f);
                }
            }
        }
    }
}

// ---------------- graph segment boundaries (batch is sorted) ----------------
__global__ void k_bounds(const int* __restrict__ batch, int* __restrict__ starts,
                         int n, int G) {
    int g = threadIdx.x;                 // 0..G inclusive
    if (g > G) return;
    int lo = 0, hi = n;
    while (lo < hi) {                    // lower_bound(batch, g)
        int mid = (lo + hi) >> 1;
        if (batch[mid] < g) lo = mid + 1; else hi = mid;
    }
    starts[g] = lo;
}

// ---------------- pooling: per-graph-slice register reduction ----------------
__global__ void k_pool(const float* __restrict__ h, const int* __restrict__ starts,
                       float* __restrict__ gsum, unsigned int* __restrict__ gmax) {
    int g = blockIdx.x;
    int slice = blockIdx.y;
    int t = threadIdx.x;                 // feature 0..127
    int s = starts[g], e = starts[g + 1];
    int cnt = e - s;
    int per = (cnt + PSPLIT - 1) / PSPLIT;
    int beg = s + slice * per;
    int end = min(beg + per, e);
    if (beg >= end) return;
    float sum = 0.f, mx = 0.f;           // post-ReLU values are >= 0
    for (int node = beg; node < end; ++node) {
        float v = h[(size_t)node * HD + t];
        sum += v;
        mx = fmaxf(mx, v);
    }
    atomicAdd(&gsum[g * HD + t], sum);
    atomicMax(&gmax[g * HD + t], __float_as_uint(mx));
}

// ---------------- pooled MLP layer 1: relu([mean||max] @ pool_W + pool_b) ----------------
__global__ void k_mlp1(const float* __restrict__ gsum, const unsigned int* __restrict__ gmax,
                       const int* __restrict__ starts, const float* __restrict__ pool_W,
                       const float* __restrict__ pool_b, float* __restrict__ hid) {
    int g = blockIdx.x, t = threadIdx.x;   // t in [0,128)
    __shared__ float pooled[2 * HD];
    float cntf = fmaxf((float)(starts[g + 1] - starts[g]), 1.f);
    pooled[t] = gsum[g * HD + t] / cntf;
    pooled[HD + t] = __uint_as_float(gmax[g * HD + t]);
    __syncthreads();
    float acc = pool_b[t];
    for (int k = 0; k < 2 * HD; ++k)
        acc += pooled[k] * pool_W[k * HD + t];
    hid[g * HD + t] = fmaxf(acc, 0.f);
}

// ---------------- final head: hid @ out_W + out_b ----------------
__global__ void k_mlp2(const float* __restrict__ hid, const float* __restrict__ out_W,
                       const float* __restrict__ out_b, float* __restrict__ out) {
    int g = blockIdx.x, o = threadIdx.x;   // o in [0,64)
    __shared__ float hv[HD];
    hv[o] = hid[g * HD + o];
    hv[o + 64] = hid[g * HD + o + 64];
    __syncthreads();
    float acc = out_b[o];
    for (int j = 0; j < HD; ++j)
        acc += hv[j] * out_W[j * 64 + o];
    out[g * 64 + o] = acc;
}

extern "C" void kernel_launch(void* const* d_in, const int* in_sizes, int n_in,
                              void* d_out, int out_size, void* d_ws, size_t ws_size,
                              hipStream_t stream) {
    const float* x        = (const float*)d_in[0];
    const int*   eidx     = (const int*)d_in[1];
    const int*   batch    = (const int*)d_in[2];
    const float* W0       = (const float*)d_in[3];
    const float* Wh       = (const float*)d_in[4];
    const float* b        = (const float*)d_in[5];
    const float* bn_gamma = (const float*)d_in[6];
    const float* bn_beta  = (const float*)d_in[7];
    const float* bn_mean  = (const float*)d_in[8];
    const float* bn_var   = (const float*)d_in[9];
    const float* pool_W   = (const float*)d_in[10];
    const float* pool_b   = (const float*)d_in[11];
    const float* out_W    = (const float*)d_in[12];
    const float* out_b    = (const float*)d_in[13];
    float* out = (float*)d_out;

    const int N = in_sizes[2];
    const int E = in_sizes[1] / 2;
    const int L = in_sizes[5] / HD;
    const int G = out_size / (HD / 2);

    const int* src = eidx;
    const int* dst = eidx + E;

    const int NBLK = (N + 127) / 128;          // GEMM blocks (128 rows each)
    const size_t NRB = (size_t)NBLK * 8;       // padded rowblocks

    // workspace layout (16B-aligned chunks first)
    char* p = (char*)d_ws;
    float* h    = (float*)p; p += (size_t)N * HD * 4;            // layer output f32
    unsigned short* agh = (unsigned short*)p; p += NRB * 4 * 512 * 2;  // A hi frags
    unsigned short* agl = (unsigned short*)p; p += NRB * 4 * 512 * 2;  // A lo frags
    unsigned short* whi = (unsigned short*)p; p += (size_t)4 * 16384 * 2;
    unsigned short* wlo = (unsigned short*)p; p += (size_t)4 * 16384 * 2;
    unsigned short* esrc = (unsigned short*)p; p += (((size_t)E * 2 + 15) & ~15ull);
    int*   counts  = (int*)p;   p += (size_t)N * 4;
    float* dis     = (float*)p; p += (size_t)N * 4;
    int*   offs    = (int*)p;   p += (size_t)(N + 1) * 4;
    int*   cursor  = (int*)p;   p += (size_t)N * 4;
    int*   bsums   = (int*)p;   p += 256 * 4;
    float* gsum    = (float*)p; p += (size_t)G * HD * 4;
    unsigned int* gmax = (unsigned int*)p; p += (size_t)G * HD * 4;
    int*   starts  = (int*)p;   p += (size_t)(G + 1) * 4;
    float* hid     = (float*)p; p += (size_t)G * HD * 4;
    (void)ws_size; (void)n_in;

    // zero accumulators
    hipMemsetAsync(counts, 0, (size_t)N * 4, stream);
    hipMemsetAsync(gsum, 0, (size_t)G * HD * 4, stream);
    hipMemsetAsync(gmax, 0, (size_t)G * HD * 4, stream);

    const int NB = (N + 255) / 256;

    k_count<<<1024, 256, 0, stream>>>(dst, counts, E);
    k_scan1<<<NB, 256, 0, stream>>>(counts, offs, bsums, N);
    k_scan2<<<1, 256, 0, stream>>>(bsums, NB);
    k_scan3<<<NB, 256, 0, stream>>>(offs, bsums, cursor, N);
    k_dis<<<(N + 255) / 256, 256, 0, stream>>>(counts, dis, N);
    k_fill<<<1024, 256, 0, stream>>>(src, dst, cursor, esrc, E);
    k_bounds<<<1, 128, 0, stream>>>(batch, starts, N, G);
    k_wsplit<<<256, 256, 0, stream>>>(W0, Wh, whi, wlo);

    // layer 0: aggregate x (24 feats, K padded to 32), MFMA GEMM KC=1
    k_agg<6, 8, 1, true><<<(N + 31) / 32, 256, 0, stream>>>(x, offs, counts, esrc,
                                                            dis, agh, agl, N);
    k_gemm_m<1><<<NBLK, 256, 0, stream>>>(agh, agl, whi, wlo, b, bn_gamma, bn_beta,
                                          bn_mean, bn_var, h, N);

    // layers 1..L-1: aggregate h (128), MFMA GEMM KC=4
    for (int l = 1; l < L; ++l) {
        k_agg<32, 32, 4, false><<<(N + 7) / 8, 256, 0, stream>>>(h, offs, counts, esrc,
                                                                 dis, agh, agl, N);
        k_gemm_m<4><<<NBLK, 256, 0, stream>>>(agh, agl,
                                              whi + (size_t)l * 16384, wlo + (size_t)l * 16384,
                                              b + l * HD, bn_gamma + l * HD, bn_beta + l * HD,
                                              bn_mean + l * HD, bn_var + l * HD, h, N);
    }

    // pooling + head
    dim3 pgrid(G, PSPLIT);
    k_pool<<<pgrid, HD, 0, stream>>>(h, starts, gsum, gmax);
    k_mlp1<<<G, HD, 0, stream>>>(gsum, gmax, starts, pool_W, pool_b, hid);
    k_mlp2<<<G, 64, 0, stream>>>(hid, out_W, out_b, out);
}

// Round 7
// 281.940 us; speedup vs baseline: 4.0159x; 1.2322x over previous
//
#include <hip/hip_runtime.h>
#include <hip/hip_bf16.h>
#include <hip/hip_fp16.h>

#define HD 128          // hidden dim
#define BN_EPS 1e-5f
#define PSPLIT 16       // pooling slices per graph

typedef __attribute__((ext_vector_type(8))) short short8;
typedef __attribute__((ext_vector_type(4))) float f32x4;

// round-to-nearest-even f32 -> bf16 bits; rem = v - bf16(v)
__device__ inline unsigned short f2bf(float v, float& rem) {
    unsigned u = __float_as_uint(v);
    unsigned r = (u + 0x7FFFu + ((u >> 16) & 1u)) >> 16;
    rem = v - __uint_as_float(r << 16);
    return (unsigned short)r;
}

// ---------------- degree count ----------------
__global__ void k_count(const int* __restrict__ dst, int* __restrict__ counts, int E) {
    int i = blockIdx.x * blockDim.x + threadIdx.x;
    for (; i < E; i += gridDim.x * blockDim.x)
        atomicAdd(&counts[dst[i]], 1);
}

// ---------------- exclusive scan (3-kernel) ----------------
__global__ void k_scan1(const int* __restrict__ counts, int* __restrict__ offs,
                        int* __restrict__ bsums, int n) {
    __shared__ int s[256];
    int t = threadIdx.x, i = blockIdx.x * 256 + t;
    int v = (i < n) ? counts[i] : 0;
    s[t] = v; __syncthreads();
    for (int d = 1; d < 256; d <<= 1) {
        int x = (t >= d) ? s[t - d] : 0;
        __syncthreads(); s[t] += x; __syncthreads();
    }
    if (i < n) offs[i] = s[t] - v;
    if (t == 255) bsums[blockIdx.x] = s[255];
}

__global__ void k_scan2(int* __restrict__ bsums, int nb) {
    __shared__ int s[256];
    int t = threadIdx.x;
    int v = (t < nb) ? bsums[t] : 0;
    s[t] = v; __syncthreads();
    for (int d = 1; d < 256; d <<= 1) {
        int x = (t >= d) ? s[t - d] : 0;
        __syncthreads(); s[t] += x; __syncthreads();
    }
    if (t < nb) bsums[t] = s[t] - v;
}

// scan finalize + dis = rsqrt(deg) fused
__global__ void k_scan3(int* __restrict__ offs, const int* __restrict__ bsums,
                        int* __restrict__ cursor, const int* __restrict__ counts,
                        float* __restrict__ dis, int n) {
    int i = blockIdx.x * 256 + threadIdx.x;
    if (i < n) {
        int v = offs[i] + bsums[blockIdx.x];
        offs[i] = v;
        cursor[i] = v;
        dis[i] = rsqrtf((float)(counts[i] + 1));   // +1 self loop
    }
}

// ---------------- CSR fill: u16 src records (coef recomputed later) ----------------
__global__ void k_fill(const int* __restrict__ src, const int* __restrict__ dst,
                       int* __restrict__ cursor, unsigned short* __restrict__ esrc, int E) {
    int i = blockIdx.x * blockDim.x + threadIdx.x;
    for (; i < E; i += gridDim.x * blockDim.x) {
        int s = src[i], d = dst[i];
        int pos = atomicAdd(&cursor[d], 1);
        esrc[pos] = (unsigned short)s;
    }
}

// ---------------- W split to bf16 hi/lo in MFMA B-fragment layout ----------------
// layer 0: K padded to 32, KC=1 layout; layers 1..3: K=128, KC=4 layout.
__global__ void k_wsplit(const float* __restrict__ W0, const float* __restrict__ Wh,
                         unsigned short* __restrict__ whi, unsigned short* __restrict__ wlo) {
    int idx = blockIdx.x * 256 + threadIdx.x;     // 4 * 128 * 128
    int l = idx >> 14, rest = idx & 16383;
    int k = rest >> 7, c = rest & 127;
    float val;
    if (l == 0) {
        if (k >= 32) return;
        val = (k < 24) ? W0[k * HD + c] : 0.f;
    } else {
        val = Wh[(size_t)(l - 1) * HD * HD + (size_t)k * HD + c];
    }
    float rem, rem2;
    unsigned short hi = f2bf(val, rem);
    unsigned short lo = f2bf(rem, rem2);
    int cb = c >> 4, kc = k >> 5;
    int lane = (c & 15) | (((k & 31) >> 3) << 4);
    int j = k & 7;
    size_t addr;
    if (l == 0) addr = (size_t)(cb * 64 + lane) * 8 + j;                  // KC=1
    else        addr = (size_t)l * 16384 + (size_t)((cb * 4 + kc) * 64 + lane) * 8 + j;
    whi[addr] = hi; wlo[addr] = lo;
}

// ---------------- layer-0 aggregation: out = Â x (f32 input, 24 feats) --------
// GRP=8 lanes per node; lane = feature-quad index. Emits bf16 hi/lo A-frags, KC=1.
__global__ void k_agg_x(const float* __restrict__ in, const int* __restrict__ offs,
                        const int* __restrict__ counts, const unsigned short* __restrict__ esrc,
                        const float* __restrict__ dis, unsigned short* __restrict__ ohi,
                        unsigned short* __restrict__ olo, int n) {
    const int FQ = 6, GRP = 8;
    int grp = threadIdx.x / GRP;
    int lane = threadIdx.x % GRP;
    int node = blockIdx.x * (blockDim.x / GRP) + grp;
    if (node >= n) return;
    int rowblk = node >> 4, rr = node & 15;

    if (lane == FQ) {          // zero-fill features 24..31 (K pad)
        size_t base = (size_t)rowblk * 512 + (size_t)(rr + 48) * 8;
        ushort4 z = make_ushort4(0, 0, 0, 0);
        *(ushort4*)(ohi + base) = z; *(ushort4*)(ohi + base + 4) = z;
        *(ushort4*)(olo + base) = z; *(ushort4*)(olo + base + 4) = z;
    }
    if (lane >= FQ) return;

    const float4* in4 = reinterpret_cast<const float4*>(in);
    float dn = dis[node];
    float sl = dn * dn;
    float4 a = in4[(size_t)node * FQ + lane];
    float4 accA = make_float4(sl * a.x, sl * a.y, sl * a.z, sl * a.w);
    float4 accB = make_float4(0.f, 0.f, 0.f, 0.f);

    int e = offs[node], end = e + counts[node];
    for (; e + 3 < end; e += 4) {
        int s0 = esrc[e],     s1 = esrc[e + 1];
        int s2 = esrc[e + 2], s3 = esrc[e + 3];
        float c0 = dis[s0] * dn, c1 = dis[s1] * dn;
        float c2 = dis[s2] * dn, c3 = dis[s3] * dn;
        float4 v0 = in4[(size_t)s0 * FQ + lane];
        float4 v1 = in4[(size_t)s1 * FQ + lane];
        float4 v2 = in4[(size_t)s2 * FQ + lane];
        float4 v3 = in4[(size_t)s3 * FQ + lane];
        accA.x = fmaf(c0, v0.x, fmaf(c2, v2.x, accA.x));
        accA.y = fmaf(c0, v0.y, fmaf(c2, v2.y, accA.y));
        accA.z = fmaf(c0, v0.z, fmaf(c2, v2.z, accA.z));
        accA.w = fmaf(c0, v0.w, fmaf(c2, v2.w, accA.w));
        accB.x = fmaf(c1, v1.x, fmaf(c3, v3.x, accB.x));
        accB.y = fmaf(c1, v1.y, fmaf(c3, v3.y, accB.y));
        accB.z = fmaf(c1, v1.z, fmaf(c3, v3.z, accB.z));
        accB.w = fmaf(c1, v1.w, fmaf(c3, v3.w, accB.w));
    }
    for (; e < end; ++e) {
        int s0 = esrc[e];
        float c0 = dis[s0] * dn;
        float4 v0 = in4[(size_t)s0 * FQ + lane];
        accA.x = fmaf(c0, v0.x, accA.x);
        accA.y = fmaf(c0, v0.y, accA.y);
        accA.z = fmaf(c0, v0.z, accA.z);
        accA.w = fmaf(c0, v0.w, accA.w);
    }
    float4 acc = make_float4(accA.x + accB.x, accA.y + accB.y,
                             accA.z + accB.z, accA.w + accB.w);

    int f0 = lane * 4;
    int lidx = rr | (((f0 & 31) >> 3) << 4);
    int j0 = f0 & 7;
    size_t base = (size_t)rowblk * 512 + (size_t)lidx * 8 + j0;
    float r0, r1, r2, r3, d0;
    ushort4 hi, lo;
    hi.x = f2bf(acc.x, r0); hi.y = f2bf(acc.y, r1);
    hi.z = f2bf(acc.z, r2); hi.w = f2bf(acc.w, r3);
    lo.x = f2bf(r0, d0); lo.y = f2bf(r1, d0);
    lo.z = f2bf(r2, d0); lo.w = f2bf(r3, d0);
    *(ushort4*)(ohi + base) = hi;
    *(ushort4*)(olo + base) = lo;
}

// ---------------- hidden-layer aggregation: out = Â h (fp16 input, 128 feats) --
// 32 lanes per node (4 features each); emits bf16 hi/lo A-frags, KC=4.
__global__ void k_agg_h(const __half* __restrict__ in, const int* __restrict__ offs,
                        const int* __restrict__ counts, const unsigned short* __restrict__ esrc,
                        const float* __restrict__ dis, unsigned short* __restrict__ ohi,
                        unsigned short* __restrict__ olo, int n) {
    int grp = threadIdx.x >> 5;
    int lane = threadIdx.x & 31;
    int node = blockIdx.x * 8 + grp;
    if (node >= n) return;
    int rowblk = node >> 4, rr = node & 15;

    const float2* in8 = reinterpret_cast<const float2*>(in);  // 4 halves per elem
    float dn = dis[node];
    float sl = dn * dn;

    float2 raw = in8[(size_t)node * 32 + lane];
    __half2 p0 = *(__half2*)&raw.x, p1 = *(__half2*)&raw.y;
    float2 f0v = __half22float2(p0), f1v = __half22float2(p1);
    float4 accA = make_float4(sl * f0v.x, sl * f0v.y, sl * f1v.x, sl * f1v.y);
    float4 accB = make_float4(0.f, 0.f, 0.f, 0.f);

    int e = offs[node], end = e + counts[node];
    for (; e + 3 < end; e += 4) {
        int s0 = esrc[e],     s1 = esrc[e + 1];
        int s2 = esrc[e + 2], s3 = esrc[e + 3];
        float c0 = dis[s0] * dn, c1 = dis[s1] * dn;
        float c2 = dis[s2] * dn, c3 = dis[s3] * dn;
        float2 w0 = in8[(size_t)s0 * 32 + lane];
        float2 w1 = in8[(size_t)s1 * 32 + lane];
        float2 w2 = in8[(size_t)s2 * 32 + lane];
        float2 w3 = in8[(size_t)s3 * 32 + lane];
        float2 a0 = __half22float2(*(__half2*)&w0.x), b0 = __half22float2(*(__half2*)&w0.y);
        float2 a1 = __half22float2(*(__half2*)&w1.x), b1 = __half22float2(*(__half2*)&w1.y);
        float2 a2 = __half22float2(*(__half2*)&w2.x), b2 = __half22float2(*(__half2*)&w2.y);
        float2 a3 = __half22float2(*(__half2*)&w3.x), b3 = __half22float2(*(__half2*)&w3.y);
        accA.x = fmaf(c0, a0.x, fmaf(c2, a2.x, accA.x));
        accA.y = fmaf(c0, a0.y, fmaf(c2, a2.y, accA.y));
        accA.z = fmaf(c0, b0.x, fmaf(c2, b2.x, accA.z));
        accA.w = fmaf(c0, b0.y, fmaf(c2, b2.y, accA.w));
        accB.x = fmaf(c1, a1.x, fmaf(c3, a3.x, accB.x));
        accB.y = fmaf(c1, a1.y, fmaf(c3, a3.y, accB.y));
        accB.z = fmaf(c1, b1.x, fmaf(c3, b3.x, accB.z));
        accB.w = fmaf(c1, b1.y, fmaf(c3, b3.y, accB.w));
    }
    for (; e < end; ++e) {
        int s0 = esrc[e];
        float c0 = dis[s0] * dn;
        float2 w0 = in8[(size_t)s0 * 32 + lane];
        float2 a0 = __half22float2(*(__half2*)&w0.x), b0 = __half22float2(*(__half2*)&w0.y);
        accA.x = fmaf(c0, a0.x, accA.x);
        accA.y = fmaf(c0, a0.y, accA.y);
        accA.z = fmaf(c0, b0.x, accA.z);
        accA.w = fmaf(c0, b0.y, accA.w);
    }
    float4 acc = make_float4(accA.x + accB.x, accA.y + accB.y,
                             accA.z + accB.z, accA.w + accB.w);

    // emit bf16 hi/lo in MFMA A-frag layout (KCA=4)
    int f0 = lane * 4;
    int kc = f0 >> 5;
    int lidx = rr | (((f0 & 31) >> 3) << 4);
    int j0 = f0 & 7;
    size_t base = ((size_t)rowblk * 4 + kc) * 512 + (size_t)lidx * 8 + j0;
    float r0, r1, r2, r3, d0;
    ushort4 hi, lo;
    hi.x = f2bf(acc.x, r0); hi.y = f2bf(acc.y, r1);
    hi.z = f2bf(acc.z, r2); hi.w = f2bf(acc.w, r3);
    lo.x = f2bf(r0, d0); lo.y = f2bf(r1, d0);
    lo.z = f2bf(r2, d0); lo.w = f2bf(r3, d0);
    *(ushort4*)(ohi + base) = hi;
    *(ushort4*)(olo + base) = lo;
}

// ---------------- MFMA GEMM + fused bias/BN/ReLU ----------------
// 128 rows x 128 cols per 256-thread block (4 waves x 2 rowblocks).
// OUT_F16: write fp16 (next layer's gather input); else f32 (pooling input).
template<int KC, bool OUT_F16>
__global__ __launch_bounds__(256) void k_gemm_m(
        const unsigned short* __restrict__ agh, const unsigned short* __restrict__ agl,
        const unsigned short* __restrict__ wh, const unsigned short* __restrict__ wl,
        const float* __restrict__ bias, const float* __restrict__ gamma,
        const float* __restrict__ beta, const float* __restrict__ mean,
        const float* __restrict__ var, float* __restrict__ outf,
        __half* __restrict__ outh, int n) {
    __shared__ unsigned short lbh[8 * KC * 512];
    __shared__ unsigned short lbl[8 * KC * 512];
    int tid = threadIdx.x;
    for (int i = tid; i < 1024 * KC; i += 256) {
        ((ushort4*)lbh)[i] = ((const ushort4*)wh)[i];
        ((ushort4*)lbl)[i] = ((const ushort4*)wl)[i];
    }
    __syncthreads();

    int wave = tid >> 6, lane = tid & 63;
    int grb0 = blockIdx.x * 8 + wave * 2;

    f32x4 acc[2][8] = {};

    for (int kc = 0; kc < KC; ++kc) {
        short8 a0h = *(const short8*)(agh + ((size_t)grb0 * KC + kc) * 512 + lane * 8);
        short8 a0l = *(const short8*)(agl + ((size_t)grb0 * KC + kc) * 512 + lane * 8);
        short8 a1h = *(const short8*)(agh + ((size_t)(grb0 + 1) * KC + kc) * 512 + lane * 8);
        short8 a1l = *(const short8*)(agl + ((size_t)(grb0 + 1) * KC + kc) * 512 + lane * 8);
        #pragma unroll
        for (int cb = 0; cb < 8; ++cb) {
            short8 bh = *(const short8*)(lbh + (size_t)((cb * KC + kc) * 64 + lane) * 8);
            short8 bl = *(const short8*)(lbl + (size_t)((cb * KC + kc) * 64 + lane) * 8);
            acc[0][cb] = __builtin_amdgcn_mfma_f32_16x16x32_bf16(a0h, bh, acc[0][cb], 0, 0, 0);
            acc[0][cb] = __builtin_amdgcn_mfma_f32_16x16x32_bf16(a0h, bl, acc[0][cb], 0, 0, 0);
            acc[0][cb] = __builtin_amdgcn_mfma_f32_16x16x32_bf16(a0l, bh, acc[0][cb], 0, 0, 0);
            acc[1][cb] = __builtin_amdgcn_mfma_f32_16x16x32_bf16(a1h, bh, acc[1][cb], 0, 0, 0);
            acc[1][cb] = __builtin_amdgcn_mfma_f32_16x16x32_bf16(a1h, bl, acc[1][cb], 0, 0, 0);
            acc[1][cb] = __builtin_amdgcn_mfma_f32_16x16x32_bf16(a1l, bh, acc[1][cb], 0, 0, 0);
        }
    }

    // epilogue: relu((acc + bias - mean) * gamma/sqrt(var+eps) + beta)
    int colbase = lane & 15;
    float scv[8], shv[8];
    #pragma unroll
    for (int cb = 0; cb < 8; ++cb) {
        int c = cb * 16 + colbase;
        float s = gamma[c] * rsqrtf(var[c] + BN_EPS);
        scv[cb] = s;
        shv[cb] = beta[c] + (bias[c] - mean[c]) * s;
    }
    int r0 = (lane >> 4) * 4;
    #pragma unroll
    for (int rb = 0; rb < 2; ++rb) {
        int rowb = (grb0 + rb) * 16 + r0;
        #pragma unroll
        for (int rg = 0; rg < 4; ++rg) {
            int row = rowb + rg;
            if (row < n) {
                #pragma unroll
                for (int cb = 0; cb < 8; ++cb) {
                    float v = fmaxf(fmaf(acc[rb][cb][rg], scv[cb], shv[cb]), 0.f);
                    if (OUT_F16)
                        outh[(size_t)row * HD + cb * 16 + colbase] = __float2half(v);
                    else
                        outf[(size_t)row * HD + cb * 16 + colbase] = v;
                }
            }
        }
    }
}

// ---------------- graph segment boundaries (batch is sorted) ----------------
__global__ void k_bounds(const int* __restrict__ batch, int* __restrict__ starts,
                         int n, int G) {
    int g = threadIdx.x;                 // 0..G inclusive
    if (g > G) return;
    int lo = 0, hi = n;
    while (lo < hi) {                    // lower_bound(batch, g)
        int mid = (lo + hi) >> 1;
        if (batch[mid] < g) lo = mid + 1; else hi = mid;
    }
    starts[g] = lo;
}

// ---------------- pooling: per-graph-slice register reduction ----------------
__global__ void k_pool(const float* __restrict__ h, const int* __restrict__ starts,
                       float* __restrict__ gsum, unsigned int* __restrict__ gmax) {
    int g = blockIdx.x;
    int slice = blockIdx.y;
    int t = threadIdx.x;                 // feature 0..127
    int s = starts[g], e = starts[g + 1];
    int cnt = e - s;
    int per = (cnt + PSPLIT - 1) / PSPLIT;
    int beg = s + slice * per;
    int end = min(beg + per, e);
    if (beg >= end) return;
    float sum = 0.f, mx = 0.f;           // post-ReLU values are >= 0
    for (int node = beg; node < end; ++node) {
        float v = h[(size_t)node * HD + t];
        sum += v;
        mx = fmaxf(mx, v);
    }
    atomicAdd(&gsum[g * HD + t], sum);
    atomicMax(&gmax[g * HD + t], __float_as_uint(mx));
}

// ---------------- pooled MLP layer 1: relu([mean||max] @ pool_W + pool_b) ----------------
__global__ void k_mlp1(const float* __restrict__ gsum, const unsigned int* __restrict__ gmax,
                       const int* __restrict__ starts, const float* __restrict__ pool_W,
                       const float* __restrict__ pool_b, float* __restrict__ hid) {
    int g = blockIdx.x, t = threadIdx.x;   // t in [0,128)
    __shared__ float pooled[2 * HD];
    float cntf = fmaxf((float)(starts[g + 1] - starts[g]), 1.f);
    pooled[t] = gsum[g * HD + t] / cntf;
    pooled[HD + t] = __uint_as_float(gmax[g * HD + t]);
    __syncthreads();
    float acc = pool_b[t];
    for (int k = 0; k < 2 * HD; ++k)
        acc += pooled[k] * pool_W[k * HD + t];
    hid[g * HD + t] = fmaxf(acc, 0.f);
}

// ---------------- final head: hid @ out_W + out_b ----------------
__global__ void k_mlp2(const float* __restrict__ hid, const float* __restrict__ out_W,
                       const float* __restrict__ out_b, float* __restrict__ out) {
    int g = blockIdx.x, o = threadIdx.x;   // o in [0,64)
    __shared__ float hv[HD];
    hv[o] = hid[g * HD + o];
    hv[o + 64] = hid[g * HD + o + 64];
    __syncthreads();
    float acc = out_b[o];
    for (int j = 0; j < HD; ++j)
        acc += hv[j] * out_W[j * 64 + o];
    out[g * 64 + o] = acc;
}

extern "C" void kernel_launch(void* const* d_in, const int* in_sizes, int n_in,
                              void* d_out, int out_size, void* d_ws, size_t ws_size,
                              hipStream_t stream) {
    const float* x        = (const float*)d_in[0];
    const int*   eidx     = (const int*)d_in[1];
    const int*   batch    = (const int*)d_in[2];
    const float* W0       = (const float*)d_in[3];
    const float* Wh       = (const float*)d_in[4];
    const float* b        = (const float*)d_in[5];
    const float* bn_gamma = (const float*)d_in[6];
    const float* bn_beta  = (const float*)d_in[7];
    const float* bn_mean  = (const float*)d_in[8];
    const float* bn_var   = (const float*)d_in[9];
    const float* pool_W   = (const float*)d_in[10];
    const float* pool_b   = (const float*)d_in[11];
    const float* out_W    = (const float*)d_in[12];
    const float* out_b    = (const float*)d_in[13];
    float* out = (float*)d_out;

    const int N = in_sizes[2];
    const int E = in_sizes[1] / 2;
    const int L = in_sizes[5] / HD;
    const int G = out_size / (HD / 2);

    const int* src = eidx;
    const int* dst = eidx + E;

    const int NBLK = (N + 127) / 128;          // GEMM blocks (128 rows each)
    const size_t NRB = (size_t)NBLK * 8;       // padded rowblocks

    // workspace layout (16B-aligned chunks first)
    char* p = (char*)d_ws;
    float*  h    = (float*)p;  p += (size_t)N * HD * 4;          // final layer f32 (pooling)
    __half* hf   = (__half*)p; p += (size_t)NBLK * 128 * HD * 2; // inter-layer fp16
    unsigned short* agh = (unsigned short*)p; p += NRB * 4 * 512 * 2;  // A hi frags
    unsigned short* agl = (unsigned short*)p; p += NRB * 4 * 512 * 2;  // A lo frags
    unsigned short* whi = (unsigned short*)p; p += (size_t)4 * 16384 * 2;
    unsigned short* wlo = (unsigned short*)p; p += (size_t)4 * 16384 * 2;
    unsigned short* esrc = (unsigned short*)p; p += (((size_t)E * 2 + 15) & ~15ull);
    int*   counts  = (int*)p;   p += (size_t)N * 4;
    float* dis     = (float*)p; p += (size_t)N * 4;
    int*   offs    = (int*)p;   p += (size_t)(N + 1) * 4;
    int*   cursor  = (int*)p;   p += (size_t)N * 4;
    int*   bsums   = (int*)p;   p += 256 * 4;
    float* gsum    = (float*)p; p += (size_t)G * HD * 4;
    unsigned int* gmax = (unsigned int*)p; p += (size_t)G * HD * 4;  // adjacent to gsum
    int*   starts  = (int*)p;   p += (size_t)(G + 1) * 4;
    float* hid     = (float*)p; p += (size_t)G * HD * 4;
    (void)ws_size; (void)n_in;

    // zero accumulators (gsum+gmax adjacent -> single memset)
    hipMemsetAsync(counts, 0, (size_t)N * 4, stream);
    hipMemsetAsync(gsum, 0, (size_t)G * HD * 8, stream);

    const int NB = (N + 255) / 256;

    k_count<<<1024, 256, 0, stream>>>(dst, counts, E);
    k_scan1<<<NB, 256, 0, stream>>>(counts, offs, bsums, N);
    k_scan2<<<1, 256, 0, stream>>>(bsums, NB);
    k_scan3<<<NB, 256, 0, stream>>>(offs, bsums, cursor, counts, dis, N);
    k_fill<<<1024, 256, 0, stream>>>(src, dst, cursor, esrc, E);
    k_bounds<<<1, 128, 0, stream>>>(batch, starts, N, G);
    k_wsplit<<<256, 256, 0, stream>>>(W0, Wh, whi, wlo);

    // layer 0: aggregate x (24 feats, K padded to 32), MFMA GEMM KC=1 -> fp16
    k_agg_x<<<(N + 31) / 32, 256, 0, stream>>>(x, offs, counts, esrc, dis, agh, agl, N);
    k_gemm_m<1, true><<<NBLK, 256, 0, stream>>>(agh, agl, whi, wlo, b, bn_gamma, bn_beta,
                                                bn_mean, bn_var, nullptr, hf, N);

    // layers 1..L-1: aggregate hf (fp16, 128), MFMA GEMM KC=4
    for (int l = 1; l < L; ++l) {
        k_agg_h<<<(N + 7) / 8, 256, 0, stream>>>(hf, offs, counts, esrc, dis, agh, agl, N);
        if (l < L - 1)
            k_gemm_m<4, true><<<NBLK, 256, 0, stream>>>(agh, agl,
                whi + (size_t)l * 16384, wlo + (size_t)l * 16384,
                b + l * HD, bn_gamma + l * HD, bn_beta + l * HD,
                bn_mean + l * HD, bn_var + l * HD, nullptr, hf, N);
        else
            k_gemm_m<4, false><<<NBLK, 256, 0, stream>>>(agh, agl,
                whi + (size_t)l * 16384, wlo + (size_t)l * 16384,
                b + l * HD, bn_gamma + l * HD, bn_beta + l * HD,
                bn_mean + l * HD, bn_var + l * HD, h, nullptr, N);
    }

    // pooling + head
    dim3 pgrid(G, PSPLIT);
    k_pool<<<pgrid, HD, 0, stream>>>(h, starts, gsum, gmax);
    k_mlp1<<<G, HD, 0, stream>>>(gsum, gmax, starts, pool_W, pool_b, hid);
    k_mlp2<<<G, 64, 0, stream>>>(hid, out_W, out_b, out);
}

// Round 8
// 279.822 us; speedup vs baseline: 4.0463x; 1.0076x over previous
//
#include <hip/hip_runtime.h>
#include <hip/hip_bf16.h>
#include <hip/hip_fp16.h>

#define HD 128          // hidden dim
#define BN_EPS 1e-5f
#define PSPLIT 16       // pooling slices per graph

typedef __attribute__((ext_vector_type(8))) short short8;
typedef __attribute__((ext_vector_type(8))) _Float16 half8;
typedef __attribute__((ext_vector_type(4))) float f32x4;

// round-to-nearest-even f32 -> bf16 bits; rem = v - bf16(v)
__device__ inline unsigned short f2bf(float v, float& rem) {
    unsigned u = __float_as_uint(v);
    unsigned r = (u + 0x7FFFu + ((u >> 16) & 1u)) >> 16;
    rem = v - __uint_as_float(r << 16);
    return (unsigned short)r;
}

// ---------------- degree count ----------------
__global__ void k_count(const int* __restrict__ dst, int* __restrict__ counts, int E) {
    int i = blockIdx.x * blockDim.x + threadIdx.x;
    for (; i < E; i += gridDim.x * blockDim.x)
        atomicAdd(&counts[dst[i]], 1);
}

// ---------------- exclusive scan ----------------
__global__ void k_scan1(const int* __restrict__ counts, int* __restrict__ offs,
                        int* __restrict__ bsums, int n) {
    __shared__ int s[256];
    int t = threadIdx.x, i = blockIdx.x * 256 + t;
    int v = (i < n) ? counts[i] : 0;
    s[t] = v; __syncthreads();
    for (int d = 1; d < 256; d <<= 1) {
        int x = (t >= d) ? s[t - d] : 0;
        __syncthreads(); s[t] += x; __syncthreads();
    }
    if (i < n) offs[i] = s[t] - v;
    if (t == 255) bsums[blockIdx.x] = s[255];
}

// scan of block sums + graph segment boundaries (batch is sorted) fused
__global__ void k_scan2(int* __restrict__ bsums, int nb,
                        const int* __restrict__ batch, int* __restrict__ starts,
                        int n, int G) {
    __shared__ int s[256];
    int t = threadIdx.x;
    int v = (t < nb) ? bsums[t] : 0;
    s[t] = v; __syncthreads();
    for (int d = 1; d < 256; d <<= 1) {
        int x = (t >= d) ? s[t - d] : 0;
        __syncthreads(); s[t] += x; __syncthreads();
    }
    if (t < nb) bsums[t] = s[t] - v;
    if (t <= G) {                        // lower_bound(batch, t)
        int lo = 0, hi = n;
        while (lo < hi) {
            int mid = (lo + hi) >> 1;
            if (batch[mid] < t) lo = mid + 1; else hi = mid;
        }
        starts[t] = lo;
    }
}

// scan finalize + dis = rsqrt(deg) fused
__global__ void k_scan3(int* __restrict__ offs, const int* __restrict__ bsums,
                        int* __restrict__ cursor, const int* __restrict__ counts,
                        float* __restrict__ dis, int n) {
    int i = blockIdx.x * 256 + threadIdx.x;
    if (i < n) {
        int v = offs[i] + bsums[blockIdx.x];
        offs[i] = v;
        cursor[i] = v;
        dis[i] = rsqrtf((float)(counts[i] + 1));   // +1 self loop
    }
}

// ---------------- CSR fill: u16 src records (coef recomputed later) ----------------
__global__ void k_fill(const int* __restrict__ src, const int* __restrict__ dst,
                       int* __restrict__ cursor, unsigned short* __restrict__ esrc, int E) {
    int i = blockIdx.x * blockDim.x + threadIdx.x;
    for (; i < E; i += gridDim.x * blockDim.x) {
        int s = src[i], d = dst[i];
        int pos = atomicAdd(&cursor[d], 1);
        esrc[pos] = (unsigned short)s;
    }
}

// ---------------- W split into MFMA B-fragment layout ----------------
// layer 0: bf16 hi/lo, K padded to 32 (KC=1); layers 1..3: fp16 hi/lo (KC=4).
__global__ void k_wsplit(const float* __restrict__ W0, const float* __restrict__ Wh,
                         unsigned short* __restrict__ whi0, unsigned short* __restrict__ wlo0,
                         unsigned short* __restrict__ whf, unsigned short* __restrict__ wlf) {
    int idx = blockIdx.x * 256 + threadIdx.x;     // 4 * 128 * 128
    int l = idx >> 14, rest = idx & 16383;
    int k = rest >> 7, c = rest & 127;
    int cb = c >> 4, kc = k >> 5;
    int lane = (c & 15) | (((k & 31) >> 3) << 4);
    int j = k & 7;
    if (l == 0) {
        if (k >= 32) return;
        float val = (k < 24) ? W0[k * HD + c] : 0.f;
        float rem, rem2;
        unsigned short hi = f2bf(val, rem);
        unsigned short lo = f2bf(rem, rem2);
        size_t addr = (size_t)(cb * 64 + lane) * 8 + j;
        whi0[addr] = hi; wlo0[addr] = lo;
    } else {
        float val = Wh[(size_t)(l - 1) * HD * HD + (size_t)k * HD + c];
        __half h = __float2half(val);
        float rem = val - __half2float(h);
        __half lo = __float2half(rem);
        size_t addr = (size_t)(l - 1) * 16384 + (size_t)((cb * 4 + kc) * 64 + lane) * 8 + j;
        whf[addr] = __half_as_ushort(h);
        wlf[addr] = __half_as_ushort(lo);
    }
}

// ---------------- layer-0 aggregation: out = Â x (f32 input, 24 feats) --------
// emits bf16 hi/lo A-frags, KC=1.
__global__ void k_agg_x(const float* __restrict__ in, const int* __restrict__ offs,
                        const int* __restrict__ counts, const unsigned short* __restrict__ esrc,
                        const float* __restrict__ dis, unsigned short* __restrict__ ohi,
                        unsigned short* __restrict__ olo, int n) {
    const int FQ = 6, GRP = 8;
    int grp = threadIdx.x / GRP;
    int lane = threadIdx.x % GRP;
    int node = blockIdx.x * (blockDim.x / GRP) + grp;
    if (node >= n) return;
    int rowblk = node >> 4, rr = node & 15;

    if (lane == FQ) {          // zero-fill features 24..31 (K pad)
        size_t base = (size_t)rowblk * 512 + (size_t)(rr + 48) * 8;
        ushort4 z = make_ushort4(0, 0, 0, 0);
        *(ushort4*)(ohi + base) = z; *(ushort4*)(ohi + base + 4) = z;
        *(ushort4*)(olo + base) = z; *(ushort4*)(olo + base + 4) = z;
    }
    if (lane >= FQ) return;

    const float4* in4 = reinterpret_cast<const float4*>(in);
    float dn = dis[node];
    float sl = dn * dn;
    float4 a = in4[(size_t)node * FQ + lane];
    float4 accA = make_float4(sl * a.x, sl * a.y, sl * a.z, sl * a.w);
    float4 accB = make_float4(0.f, 0.f, 0.f, 0.f);

    int e = offs[node], end = e + counts[node];
    for (; e + 3 < end; e += 4) {
        int s0 = esrc[e],     s1 = esrc[e + 1];
        int s2 = esrc[e + 2], s3 = esrc[e + 3];
        float c0 = dis[s0] * dn, c1 = dis[s1] * dn;
        float c2 = dis[s2] * dn, c3 = dis[s3] * dn;
        float4 v0 = in4[(size_t)s0 * FQ + lane];
        float4 v1 = in4[(size_t)s1 * FQ + lane];
        float4 v2 = in4[(size_t)s2 * FQ + lane];
        float4 v3 = in4[(size_t)s3 * FQ + lane];
        accA.x = fmaf(c0, v0.x, fmaf(c2, v2.x, accA.x));
        accA.y = fmaf(c0, v0.y, fmaf(c2, v2.y, accA.y));
        accA.z = fmaf(c0, v0.z, fmaf(c2, v2.z, accA.z));
        accA.w = fmaf(c0, v0.w, fmaf(c2, v2.w, accA.w));
        accB.x = fmaf(c1, v1.x, fmaf(c3, v3.x, accB.x));
        accB.y = fmaf(c1, v1.y, fmaf(c3, v3.y, accB.y));
        accB.z = fmaf(c1, v1.z, fmaf(c3, v3.z, accB.z));
        accB.w = fmaf(c1, v1.w, fmaf(c3, v3.w, accB.w));
    }
    for (; e < end; ++e) {
        int s0 = esrc[e];
        float c0 = dis[s0] * dn;
        float4 v0 = in4[(size_t)s0 * FQ + lane];
        accA.x = fmaf(c0, v0.x, accA.x);
        accA.y = fmaf(c0, v0.y, accA.y);
        accA.z = fmaf(c0, v0.z, accA.z);
        accA.w = fmaf(c0, v0.w, accA.w);
    }
    float4 acc = make_float4(accA.x + accB.x, accA.y + accB.y,
                             accA.z + accB.z, accA.w + accB.w);

    int f0 = lane * 4;
    int lidx = rr | (((f0 & 31) >> 3) << 4);
    int j0 = f0 & 7;
    size_t base = (size_t)rowblk * 512 + (size_t)lidx * 8 + j0;
    float r0, r1, r2, r3, d0;
    ushort4 hi, lo;
    hi.x = f2bf(acc.x, r0); hi.y = f2bf(acc.y, r1);
    hi.z = f2bf(acc.z, r2); hi.w = f2bf(acc.w, r3);
    lo.x = f2bf(r0, d0); lo.y = f2bf(r1, d0);
    lo.z = f2bf(r2, d0); lo.w = f2bf(r3, d0);
    *(ushort4*)(ohi + base) = hi;
    *(ushort4*)(olo + base) = lo;
}

// ---------------- hidden-layer aggregation: out = Â h (fp16 in, fp16 A-frags out) --
// 32 lanes per node (4 features each); emits fp16 A-frags, KC=4.
__global__ void k_agg_h(const __half* __restrict__ in, const int* __restrict__ offs,
                        const int* __restrict__ counts, const unsigned short* __restrict__ esrc,
                        const float* __restrict__ dis, unsigned short* __restrict__ af, int n) {
    int grp = threadIdx.x >> 5;
    int lane = threadIdx.x & 31;
    int node = blockIdx.x * 8 + grp;
    if (node >= n) return;
    int rowblk = node >> 4, rr = node & 15;

    const float2* in8 = reinterpret_cast<const float2*>(in);  // 4 halves per elem
    float dn = dis[node];
    float sl = dn * dn;

    float2 raw = in8[(size_t)node * 32 + lane];
    __half2 p0 = *(__half2*)&raw.x, p1 = *(__half2*)&raw.y;
    float2 f0v = __half22float2(p0), f1v = __half22float2(p1);
    float4 accA = make_float4(sl * f0v.x, sl * f0v.y, sl * f1v.x, sl * f1v.y);
    float4 accB = make_float4(0.f, 0.f, 0.f, 0.f);

    int e = offs[node], end = e + counts[node];
    for (; e + 3 < end; e += 4) {
        int s0 = esrc[e],     s1 = esrc[e + 1];
        int s2 = esrc[e + 2], s3 = esrc[e + 3];
        float c0 = dis[s0] * dn, c1 = dis[s1] * dn;
        float c2 = dis[s2] * dn, c3 = dis[s3] * dn;
        float2 w0 = in8[(size_t)s0 * 32 + lane];
        float2 w1 = in8[(size_t)s1 * 32 + lane];
        float2 w2 = in8[(size_t)s2 * 32 + lane];
        float2 w3 = in8[(size_t)s3 * 32 + lane];
        float2 a0 = __half22float2(*(__half2*)&w0.x), b0 = __half22float2(*(__half2*)&w0.y);
        float2 a1 = __half22float2(*(__half2*)&w1.x), b1 = __half22float2(*(__half2*)&w1.y);
        float2 a2 = __half22float2(*(__half2*)&w2.x), b2 = __half22float2(*(__half2*)&w2.y);
        float2 a3 = __half22float2(*(__half2*)&w3.x), b3 = __half22float2(*(__half2*)&w3.y);
        accA.x = fmaf(c0, a0.x, fmaf(c2, a2.x, accA.x));
        accA.y = fmaf(c0, a0.y, fmaf(c2, a2.y, accA.y));
        accA.z = fmaf(c0, b0.x, fmaf(c2, b2.x, accA.z));
        accA.w = fmaf(c0, b0.y, fmaf(c2, b2.y, accA.w));
        accB.x = fmaf(c1, a1.x, fmaf(c3, a3.x, accB.x));
        accB.y = fmaf(c1, a1.y, fmaf(c3, a3.y, accB.y));
        accB.z = fmaf(c1, b1.x, fmaf(c3, b3.x, accB.z));
        accB.w = fmaf(c1, b1.y, fmaf(c3, b3.y, accB.w));
    }
    for (; e < end; ++e) {
        int s0 = esrc[e];
        float c0 = dis[s0] * dn;
        float2 w0 = in8[(size_t)s0 * 32 + lane];
        float2 a0 = __half22float2(*(__half2*)&w0.x), b0 = __half22float2(*(__half2*)&w0.y);
        accA.x = fmaf(c0, a0.x, accA.x);
        accA.y = fmaf(c0, a0.y, accA.y);
        accA.z = fmaf(c0, b0.x, accA.z);
        accA.w = fmaf(c0, b0.y, accA.w);
    }
    float4 acc = make_float4(accA.x + accB.x, accA.y + accB.y,
                             accA.z + accB.z, accA.w + accB.w);

    // emit fp16 A-frag (KCA=4)
    int f0 = lane * 4;
    int kc = f0 >> 5;
    int lidx = rr | (((f0 & 31) >> 3) << 4);
    int j0 = f0 & 7;
    size_t base = ((size_t)rowblk * 4 + kc) * 512 + (size_t)lidx * 8 + j0;
    ushort4 hv;
    hv.x = __half_as_ushort(__float2half(acc.x));
    hv.y = __half_as_ushort(__float2half(acc.y));
    hv.z = __half_as_ushort(__float2half(acc.z));
    hv.w = __half_as_ushort(__float2half(acc.w));
    *(ushort4*)(af + base) = hv;
}

// ---------------- layer-0 MFMA GEMM (bf16 split A & W) + fused BN/ReLU ----------------
__global__ __launch_bounds__(256) void k_gemm_m(
        const unsigned short* __restrict__ agh, const unsigned short* __restrict__ agl,
        const unsigned short* __restrict__ wh, const unsigned short* __restrict__ wl,
        const float* __restrict__ bias, const float* __restrict__ gamma,
        const float* __restrict__ beta, const float* __restrict__ mean,
        const float* __restrict__ var, __half* __restrict__ outh, int n) {
    __shared__ unsigned short lbh[8 * 512];
    __shared__ unsigned short lbl[8 * 512];
    int tid = threadIdx.x;
    for (int i = tid; i < 1024; i += 256) {
        ((ushort4*)lbh)[i] = ((const ushort4*)wh)[i];
        ((ushort4*)lbl)[i] = ((const ushort4*)wl)[i];
    }
    __syncthreads();

    int wave = tid >> 6, lane = tid & 63;
    int grb0 = blockIdx.x * 8 + wave * 2;

    f32x4 acc[2][8] = {};

    short8 a0h = *(const short8*)(agh + (size_t)grb0 * 512 + lane * 8);
    short8 a0l = *(const short8*)(agl + (size_t)grb0 * 512 + lane * 8);
    short8 a1h = *(const short8*)(agh + (size_t)(grb0 + 1) * 512 + lane * 8);
    short8 a1l = *(const short8*)(agl + (size_t)(grb0 + 1) * 512 + lane * 8);
    #pragma unroll
    for (int cb = 0; cb < 8; ++cb) {
        short8 bh = *(const short8*)(lbh + (size_t)(cb * 64 + lane) * 8);
        short8 bl = *(const short8*)(lbl + (size_t)(cb * 64 + lane) * 8);
        acc[0][cb] = __builtin_amdgcn_mfma_f32_16x16x32_bf16(a0h, bh, acc[0][cb], 0, 0, 0);
        acc[0][cb] = __builtin_amdgcn_mfma_f32_16x16x32_bf16(a0h, bl, acc[0][cb], 0, 0, 0);
        acc[0][cb] = __builtin_amdgcn_mfma_f32_16x16x32_bf16(a0l, bh, acc[0][cb], 0, 0, 0);
        acc[1][cb] = __builtin_amdgcn_mfma_f32_16x16x32_bf16(a1h, bh, acc[1][cb], 0, 0, 0);
        acc[1][cb] = __builtin_amdgcn_mfma_f32_16x16x32_bf16(a1h, bl, acc[1][cb], 0, 0, 0);
        acc[1][cb] = __builtin_amdgcn_mfma_f32_16x16x32_bf16(a1l, bh, acc[1][cb], 0, 0, 0);
    }

    int colbase = lane & 15;
    float scv[8], shv[8];
    #pragma unroll
    for (int cb = 0; cb < 8; ++cb) {
        int c = cb * 16 + colbase;
        float s = gamma[c] * rsqrtf(var[c] + BN_EPS);
        scv[cb] = s;
        shv[cb] = beta[c] + (bias[c] - mean[c]) * s;
    }
    int r0 = (lane >> 4) * 4;
    #pragma unroll
    for (int rb = 0; rb < 2; ++rb) {
        int rowb = (grb0 + rb) * 16 + r0;
        #pragma unroll
        for (int rg = 0; rg < 4; ++rg) {
            int row = rowb + rg;
            if (row < n) {
                #pragma unroll
                for (int cb = 0; cb < 8; ++cb) {
                    float v = fmaxf(fmaf(acc[rb][cb][rg], scv[cb], shv[cb]), 0.f);
                    outh[(size_t)row * HD + cb * 16 + colbase] = __float2half(v);
                }
            }
        }
    }
}

// ---------------- hidden-layer MFMA GEMM (fp16 A exact, fp16 W hi/lo) ----------------
// OUT_F16: write fp16 (next gather input); else f32 (pooling input).
template<bool OUT_F16>
__global__ __launch_bounds__(256) void k_gemm_h(
        const unsigned short* __restrict__ af,
        const unsigned short* __restrict__ wh, const unsigned short* __restrict__ wl,
        const float* __restrict__ bias, const float* __restrict__ gamma,
        const float* __restrict__ beta, const float* __restrict__ mean,
        const float* __restrict__ var, float* __restrict__ outf,
        __half* __restrict__ outh, int n) {
    __shared__ unsigned short lbh[16384];   // 32 KB fp16 W hi
    __shared__ unsigned short lbl[16384];   // 32 KB fp16 W lo
    int tid = threadIdx.x;
    for (int i = tid; i < 4096; i += 256) {
        ((ushort4*)lbh)[i] = ((const ushort4*)wh)[i];
        ((ushort4*)lbl)[i] = ((const ushort4*)wl)[i];
    }
    __syncthreads();

    int wave = tid >> 6, lane = tid & 63;
    int grb0 = blockIdx.x * 8 + wave * 2;

    f32x4 acc[2][8] = {};

    #pragma unroll
    for (int kc = 0; kc < 4; ++kc) {
        half8 a0 = *(const half8*)(af + ((size_t)grb0 * 4 + kc) * 512 + lane * 8);
        half8 a1 = *(const half8*)(af + ((size_t)(grb0 + 1) * 4 + kc) * 512 + lane * 8);
        #pragma unroll
        for (int cb = 0; cb < 8; ++cb) {
            half8 bh = *(const half8*)(lbh + (size_t)((cb * 4 + kc) * 64 + lane) * 8);
            half8 bl = *(const half8*)(lbl + (size_t)((cb * 4 + kc) * 64 + lane) * 8);
            acc[0][cb] = __builtin_amdgcn_mfma_f32_16x16x32_f16(a0, bh, acc[0][cb], 0, 0, 0);
            acc[0][cb] = __builtin_amdgcn_mfma_f32_16x16x32_f16(a0, bl, acc[0][cb], 0, 0, 0);
            acc[1][cb] = __builtin_amdgcn_mfma_f32_16x16x32_f16(a1, bh, acc[1][cb], 0, 0, 0);
            acc[1][cb] = __builtin_amdgcn_mfma_f32_16x16x32_f16(a1, bl, acc[1][cb], 0, 0, 0);
        }
    }

    int colbase = lane & 15;
    float scv[8], shv[8];
    #pragma unroll
    for (int cb = 0; cb < 8; ++cb) {
        int c = cb * 16 + colbase;
        float s = gamma[c] * rsqrtf(var[c] + BN_EPS);
        scv[cb] = s;
        shv[cb] = beta[c] + (bias[c] - mean[c]) * s;
    }
    int r0 = (lane >> 4) * 4;
    #pragma unroll
    for (int rb = 0; rb < 2; ++rb) {
        int rowb = (grb0 + rb) * 16 + r0;
        #pragma unroll
        for (int rg = 0; rg < 4; ++rg) {
            int row = rowb + rg;
            if (row < n) {
                #pragma unroll
                for (int cb = 0; cb < 8; ++cb) {
                    float v = fmaxf(fmaf(acc[rb][cb][rg], scv[cb], shv[cb]), 0.f);
                    if (OUT_F16)
                        outh[(size_t)row * HD + cb * 16 + colbase] = __float2half(v);
                    else
                        outf[(size_t)row * HD + cb * 16 + colbase] = v;
                }
            }
        }
    }
}

// ---------------- pooling: per-graph-slice register reduction ----------------
__global__ void k_pool(const float* __restrict__ h, const int* __restrict__ starts,
                       float* __restrict__ gsum, unsigned int* __restrict__ gmax) {
    int g = blockIdx.x;
    int slice = blockIdx.y;
    int t = threadIdx.x;                 // feature 0..127
    int s = starts[g], e = starts[g + 1];
    int cnt = e - s;
    int per = (cnt + PSPLIT - 1) / PSPLIT;
    int beg = s + slice * per;
    int end = min(beg + per, e);
    if (beg >= end) return;
    float sum = 0.f, mx = 0.f;           // post-ReLU values are >= 0
    for (int node = beg; node < end; ++node) {
        float v = h[(size_t)node * HD + t];
        sum += v;
        mx = fmaxf(mx, v);
    }
    atomicAdd(&gsum[g * HD + t], sum);
    atomicMax(&gmax[g * HD + t], __float_as_uint(mx));
}

// ---------------- fused head: relu([mean||max]@pool_W+pool_b) @ out_W + out_b ----
__global__ void k_head(const float* __restrict__ gsum, const unsigned int* __restrict__ gmax,
                       const int* __restrict__ starts, const float* __restrict__ pool_W,
                       const float* __restrict__ pool_b, const float* __restrict__ out_W,
                       const float* __restrict__ out_b, float* __restrict__ out) {
    int g = blockIdx.x, t = threadIdx.x;   // t in [0,128)
    __shared__ float pooled[2 * HD];
    __shared__ float hid_s[HD];
    float cntf = fmaxf((float)(starts[g + 1] - starts[g]), 1.f);
    pooled[t] = gsum[g * HD + t] / cntf;
    pooled[HD + t] = __uint_as_float(gmax[g * HD + t]);
    __syncthreads();
    float acc = pool_b[t];
    for (int k = 0; k < 2 * HD; ++k)
        acc += pooled[k] * pool_W[k * HD + t];
    hid_s[t] = fmaxf(acc, 0.f);
    __syncthreads();
    if (t < 64) {
        float a2 = out_b[t];
        for (int j = 0; j < HD; ++j)
            a2 += hid_s[j] * out_W[j * 64 + t];
        out[g * 64 + t] = a2;
    }
}

extern "C" void kernel_launch(void* const* d_in, const int* in_sizes, int n_in,
                              void* d_out, int out_size, void* d_ws, size_t ws_size,
                              hipStream_t stream) {
    const float* x        = (const float*)d_in[0];
    const int*   eidx     = (const int*)d_in[1];
    const int*   batch    = (const int*)d_in[2];
    const float* W0       = (const float*)d_in[3];
    const float* Wh       = (const float*)d_in[4];
    const float* b        = (const float*)d_in[5];
    const float* bn_gamma = (const float*)d_in[6];
    const float* bn_beta  = (const float*)d_in[7];
    const float* bn_mean  = (const float*)d_in[8];
    const float* bn_var   = (const float*)d_in[9];
    const float* pool_W   = (const float*)d_in[10];
    const float* pool_b   = (const float*)d_in[11];
    const float* out_W    = (const float*)d_in[12];
    const float* out_b    = (const float*)d_in[13];
    float* out = (float*)d_out;

    const int N = in_sizes[2];
    const int E = in_sizes[1] / 2;
    const int L = in_sizes[5] / HD;
    const int G = out_size / (HD / 2);

    const int* src = eidx;
    const int* dst = eidx + E;

    const int NBLK = (N + 127) / 128;          // GEMM blocks (128 rows each)
    const size_t NRB = (size_t)NBLK * 8;       // padded rowblocks

    // workspace layout (16B-aligned chunks first)
    char* p = (char*)d_ws;
    float*  h    = (float*)p;  p += (size_t)N * HD * 4;          // final layer f32 (pooling)
    __half* hf   = (__half*)p; p += (size_t)NBLK * 128 * HD * 2; // inter-layer fp16
    unsigned short* af  = (unsigned short*)p; p += NRB * 4 * 512 * 2;  // fp16 A frags
    unsigned short* agh = (unsigned short*)p; p += NRB * 512 * 2;      // layer0 bf16 hi
    unsigned short* agl = (unsigned short*)p; p += NRB * 512 * 2;      // layer0 bf16 lo
    unsigned short* whi0 = (unsigned short*)p; p += (size_t)16384 * 2;
    unsigned short* wlo0 = (unsigned short*)p; p += (size_t)16384 * 2;
    unsigned short* whf  = (unsigned short*)p; p += (size_t)3 * 16384 * 2;
    unsigned short* wlf  = (unsigned short*)p; p += (size_t)3 * 16384 * 2;
    unsigned short* esrc = (unsigned short*)p; p += (((size_t)E * 2 + 15) & ~15ull);
    int*   counts  = (int*)p;   p += (size_t)N * 4;
    float* dis     = (float*)p; p += (size_t)N * 4;
    int*   offs    = (int*)p;   p += (size_t)(N + 1) * 4;
    int*   cursor  = (int*)p;   p += (size_t)N * 4;
    int*   bsums   = (int*)p;   p += 256 * 4;
    float* gsum    = (float*)p; p += (size_t)G * HD * 4;
    unsigned int* gmax = (unsigned int*)p; p += (size_t)G * HD * 4;  // adjacent to gsum
    int*   starts  = (int*)p;   p += (size_t)(G + 1) * 4;
    (void)ws_size; (void)n_in;

    // zero accumulators (gsum+gmax adjacent -> single memset)
    hipMemsetAsync(counts, 0, (size_t)N * 4, stream);
    hipMemsetAsync(gsum, 0, (size_t)G * HD * 8, stream);

    const int NB = (N + 255) / 256;

    k_count<<<1024, 256, 0, stream>>>(dst, counts, E);
    k_scan1<<<NB, 256, 0, stream>>>(counts, offs, bsums, N);
    k_scan2<<<1, 256, 0, stream>>>(bsums, NB, batch, starts, N, G);
    k_scan3<<<NB, 256, 0, stream>>>(offs, bsums, cursor, counts, dis, N);
    k_fill<<<1024, 256, 0, stream>>>(src, dst, cursor, esrc, E);
    k_wsplit<<<256, 256, 0, stream>>>(W0, Wh, whi0, wlo0, whf, wlf);

    // layer 0: aggregate x (24 feats, K padded to 32), bf16 MFMA GEMM -> fp16
    k_agg_x<<<(N + 31) / 32, 256, 0, stream>>>(x, offs, counts, esrc, dis, agh, agl, N);
    k_gemm_m<<<NBLK, 256, 0, stream>>>(agh, agl, whi0, wlo0, b, bn_gamma, bn_beta,
                                       bn_mean, bn_var, hf, N);

    // layers 1..L-1: aggregate hf (fp16) -> fp16 A-frags, fp16-MFMA GEMM
    for (int l = 1; l < L; ++l) {
        k_agg_h<<<(N + 7) / 8, 256, 0, stream>>>(hf, offs, counts, esrc, dis, af, N);
        const unsigned short* wh_l = whf + (size_t)(l - 1) * 16384;
        const unsigned short* wl_l = wlf + (size_t)(l - 1) * 16384;
        if (l < L - 1)
            k_gemm_h<true><<<NBLK, 256, 0, stream>>>(af, wh_l, wl_l,
                b + l * HD, bn_gamma + l * HD, bn_beta + l * HD,
                bn_mean + l * HD, bn_var + l * HD, nullptr, hf, N);
        else
            k_gemm_h<false><<<NBLK, 256, 0, stream>>>(af, wh_l, wl_l,
                b + l * HD, bn_gamma + l * HD, bn_beta + l * HD,
                bn_mean + l * HD, bn_var + l * HD, h, nullptr, N);
    }

    // pooling + head
    dim3 pgrid(G, PSPLIT);
    k_pool<<<pgrid, HD, 0, stream>>>(h, starts, gsum, gmax);
    k_head<<<G, HD, 0, stream>>>(gsum, gmax, starts, pool_W, pool_b, out_W, out_b, out);
}

// Round 9
// 275.026 us; speedup vs baseline: 4.1168x; 1.0174x over previous
//
#include <hip/hip_runtime.h>
#include <hip/hip_bf16.h>
#include <hip/hip_fp16.h>

#define HD 128          // hidden dim
#define BN_EPS 1e-5f

typedef __attribute__((ext_vector_type(8))) short short8;
typedef __attribute__((ext_vector_type(8))) _Float16 half8;
typedef __attribute__((ext_vector_type(4))) float f32x4;

// round-to-nearest-even f32 -> bf16 bits; rem = v - bf16(v)
__device__ inline unsigned short f2bf(float v, float& rem) {
    unsigned u = __float_as_uint(v);
    unsigned r = (u + 0x7FFFu + ((u >> 16) & 1u)) >> 16;
    rem = v - __uint_as_float(r << 16);
    return (unsigned short)r;
}

// ---------------- degree count + within-destination ordinal ----------------
__global__ void k_count(const int* __restrict__ dst, int* __restrict__ counts,
                        unsigned short* __restrict__ ord, int E) {
    int i = blockIdx.x * blockDim.x + threadIdx.x;
    for (; i < E; i += gridDim.x * blockDim.x) {
        int pos = atomicAdd(&counts[dst[i]], 1);
        ord[i] = (unsigned short)pos;
    }
}

// ---------------- exclusive scan ----------------
__global__ void k_scan1(const int* __restrict__ counts, int* __restrict__ offs,
                        int* __restrict__ bsums, int n) {
    __shared__ int s[256];
    int t = threadIdx.x, i = blockIdx.x * 256 + t;
    int v = (i < n) ? counts[i] : 0;
    s[t] = v; __syncthreads();
    for (int d = 1; d < 256; d <<= 1) {
        int x = (t >= d) ? s[t - d] : 0;
        __syncthreads(); s[t] += x; __syncthreads();
    }
    if (i < n) offs[i] = s[t] - v;
    if (t == 255) bsums[blockIdx.x] = s[255];
}

// scan of block sums + graph segment boundaries (batch is sorted) fused
__global__ void k_scan2(int* __restrict__ bsums, int nb,
                        const int* __restrict__ batch, int* __restrict__ starts,
                        int n, int G) {
    __shared__ int s[256];
    int t = threadIdx.x;
    int v = (t < nb) ? bsums[t] : 0;
    s[t] = v; __syncthreads();
    for (int d = 1; d < 256; d <<= 1) {
        int x = (t >= d) ? s[t - d] : 0;
        __syncthreads(); s[t] += x; __syncthreads();
    }
    if (t < nb) bsums[t] = s[t] - v;
    if (t <= G) {                        // lower_bound(batch, t)
        int lo = 0, hi = n;
        while (lo < hi) {
            int mid = (lo + hi) >> 1;
            if (batch[mid] < t) lo = mid + 1; else hi = mid;
        }
        starts[t] = lo;
    }
}

// scan finalize + dis = rsqrt(deg) fused
__global__ void k_scan3(int* __restrict__ offs, const int* __restrict__ bsums,
                        const int* __restrict__ counts, float* __restrict__ dis, int n) {
    int i = blockIdx.x * 256 + threadIdx.x;
    if (i < n) {
        offs[i] += bsums[blockIdx.x];
        dis[i] = rsqrtf((float)(counts[i] + 1));   // +1 self loop
    }
}

// ---------------- CSR fill: atomic-free via precomputed ordinals ----------------
__global__ void k_fill(const int* __restrict__ src, const int* __restrict__ dst,
                       const unsigned short* __restrict__ ord, const int* __restrict__ offs,
                       unsigned short* __restrict__ esrc, int E) {
    int i = blockIdx.x * blockDim.x + threadIdx.x;
    for (; i < E; i += gridDim.x * blockDim.x) {
        int s = src[i], d = dst[i];
        esrc[offs[d] + ord[i]] = (unsigned short)s;
    }
}

// ---------------- W split into MFMA B-fragment layout ----------------
// layer 0: bf16 hi/lo, K padded to 32 (KC=1); layers 1..3: fp16 hi/lo (KC=4).
__global__ void k_wsplit(const float* __restrict__ W0, const float* __restrict__ Wh,
                         unsigned short* __restrict__ whi0, unsigned short* __restrict__ wlo0,
                         unsigned short* __restrict__ whf, unsigned short* __restrict__ wlf) {
    int idx = blockIdx.x * 256 + threadIdx.x;     // 4 * 128 * 128
    int l = idx >> 14, rest = idx & 16383;
    int k = rest >> 7, c = rest & 127;
    int cb = c >> 4, kc = k >> 5;
    int lane = (c & 15) | (((k & 31) >> 3) << 4);
    int j = k & 7;
    if (l == 0) {
        if (k >= 32) return;
        float val = (k < 24) ? W0[k * HD + c] : 0.f;
        float rem, rem2;
        unsigned short hi = f2bf(val, rem);
        unsigned short lo = f2bf(rem, rem2);
        size_t addr = (size_t)(cb * 64 + lane) * 8 + j;
        whi0[addr] = hi; wlo0[addr] = lo;
    } else {
        float val = Wh[(size_t)(l - 1) * HD * HD + (size_t)k * HD + c];
        __half h = __float2half(val);
        float rem = val - __half2float(h);
        __half lo = __float2half(rem);
        size_t addr = (size_t)(l - 1) * 16384 + (size_t)((cb * 4 + kc) * 64 + lane) * 8 + j;
        whf[addr] = __half_as_ushort(h);
        wlf[addr] = __half_as_ushort(lo);
    }
}

// ---------------- layer-0 aggregation: out = Â x (f32 input, 24 feats) --------
// emits bf16 hi/lo A-frags, KC=1.
__global__ void k_agg_x(const float* __restrict__ in, const int* __restrict__ offs,
                        const int* __restrict__ counts, const unsigned short* __restrict__ esrc,
                        const float* __restrict__ dis, unsigned short* __restrict__ ohi,
                        unsigned short* __restrict__ olo, int n) {
    const int FQ = 6, GRP = 8;
    int grp = threadIdx.x / GRP;
    int lane = threadIdx.x % GRP;
    int node = blockIdx.x * (blockDim.x / GRP) + grp;
    if (node >= n) return;
    int rowblk = node >> 4, rr = node & 15;

    if (lane == FQ) {          // zero-fill features 24..31 (K pad)
        size_t base = (size_t)rowblk * 512 + (size_t)(rr + 48) * 8;
        ushort4 z = make_ushort4(0, 0, 0, 0);
        *(ushort4*)(ohi + base) = z; *(ushort4*)(ohi + base + 4) = z;
        *(ushort4*)(olo + base) = z; *(ushort4*)(olo + base + 4) = z;
    }
    if (lane >= FQ) return;

    const float4* in4 = reinterpret_cast<const float4*>(in);
    float dn = dis[node];
    float sl = dn * dn;
    float4 a = in4[(size_t)node * FQ + lane];
    float4 accA = make_float4(sl * a.x, sl * a.y, sl * a.z, sl * a.w);
    float4 accB = make_float4(0.f, 0.f, 0.f, 0.f);

    int e = offs[node], end = e + counts[node];
    for (; e + 3 < end; e += 4) {
        int s0 = esrc[e],     s1 = esrc[e + 1];
        int s2 = esrc[e + 2], s3 = esrc[e + 3];
        float c0 = dis[s0] * dn, c1 = dis[s1] * dn;
        float c2 = dis[s2] * dn, c3 = dis[s3] * dn;
        float4 v0 = in4[(size_t)s0 * FQ + lane];
        float4 v1 = in4[(size_t)s1 * FQ + lane];
        float4 v2 = in4[(size_t)s2 * FQ + lane];
        float4 v3 = in4[(size_t)s3 * FQ + lane];
        accA.x = fmaf(c0, v0.x, fmaf(c2, v2.x, accA.x));
        accA.y = fmaf(c0, v0.y, fmaf(c2, v2.y, accA.y));
        accA.z = fmaf(c0, v0.z, fmaf(c2, v2.z, accA.z));
        accA.w = fmaf(c0, v0.w, fmaf(c2, v2.w, accA.w));
        accB.x = fmaf(c1, v1.x, fmaf(c3, v3.x, accB.x));
        accB.y = fmaf(c1, v1.y, fmaf(c3, v3.y, accB.y));
        accB.z = fmaf(c1, v1.z, fmaf(c3, v3.z, accB.z));
        accB.w = fmaf(c1, v1.w, fmaf(c3, v3.w, accB.w));
    }
    for (; e < end; ++e) {
        int s0 = esrc[e];
        float c0 = dis[s0] * dn;
        float4 v0 = in4[(size_t)s0 * FQ + lane];
        accA.x = fmaf(c0, v0.x, accA.x);
        accA.y = fmaf(c0, v0.y, accA.y);
        accA.z = fmaf(c0, v0.z, accA.z);
        accA.w = fmaf(c0, v0.w, accA.w);
    }
    float4 acc = make_float4(accA.x + accB.x, accA.y + accB.y,
                             accA.z + accB.z, accA.w + accB.w);

    int f0 = lane * 4;
    int lidx = rr | (((f0 & 31) >> 3) << 4);
    int j0 = f0 & 7;
    size_t base = (size_t)rowblk * 512 + (size_t)lidx * 8 + j0;
    float r0, r1, r2, r3, d0;
    ushort4 hi, lo;
    hi.x = f2bf(acc.x, r0); hi.y = f2bf(acc.y, r1);
    hi.z = f2bf(acc.z, r2); hi.w = f2bf(acc.w, r3);
    lo.x = f2bf(r0, d0); lo.y = f2bf(r1, d0);
    lo.z = f2bf(r2, d0); lo.w = f2bf(r3, d0);
    *(ushort4*)(ohi + base) = hi;
    *(ushort4*)(olo + base) = lo;
}

// ---------------- hidden-layer aggregation: out = Â h (fp16 in, fp16 A-frags out) --
__global__ void k_agg_h(const __half* __restrict__ in, const int* __restrict__ offs,
                        const int* __restrict__ counts, const unsigned short* __restrict__ esrc,
                        const float* __restrict__ dis, unsigned short* __restrict__ af, int n) {
    int grp = threadIdx.x >> 5;
    int lane = threadIdx.x & 31;
    int node = blockIdx.x * 8 + grp;
    if (node >= n) return;
    int rowblk = node >> 4, rr = node & 15;

    const float2* in8 = reinterpret_cast<const float2*>(in);  // 4 halves per elem
    float dn = dis[node];
    float sl = dn * dn;

    float2 raw = in8[(size_t)node * 32 + lane];
    __half2 p0 = *(__half2*)&raw.x, p1 = *(__half2*)&raw.y;
    float2 f0v = __half22float2(p0), f1v = __half22float2(p1);
    float4 accA = make_float4(sl * f0v.x, sl * f0v.y, sl * f1v.x, sl * f1v.y);
    float4 accB = make_float4(0.f, 0.f, 0.f, 0.f);

    int e = offs[node], end = e + counts[node];
    for (; e + 3 < end; e += 4) {
        int s0 = esrc[e],     s1 = esrc[e + 1];
        int s2 = esrc[e + 2], s3 = esrc[e + 3];
        float c0 = dis[s0] * dn, c1 = dis[s1] * dn;
        float c2 = dis[s2] * dn, c3 = dis[s3] * dn;
        float2 w0 = in8[(size_t)s0 * 32 + lane];
        float2 w1 = in8[(size_t)s1 * 32 + lane];
        float2 w2 = in8[(size_t)s2 * 32 + lane];
        float2 w3 = in8[(size_t)s3 * 32 + lane];
        float2 a0 = __half22float2(*(__half2*)&w0.x), b0 = __half22float2(*(__half2*)&w0.y);
        float2 a1 = __half22float2(*(__half2*)&w1.x), b1 = __half22float2(*(__half2*)&w1.y);
        float2 a2 = __half22float2(*(__half2*)&w2.x), b2 = __half22float2(*(__half2*)&w2.y);
        float2 a3 = __half22float2(*(__half2*)&w3.x), b3 = __half22float2(*(__half2*)&w3.y);
        accA.x = fmaf(c0, a0.x, fmaf(c2, a2.x, accA.x));
        accA.y = fmaf(c0, a0.y, fmaf(c2, a2.y, accA.y));
        accA.z = fmaf(c0, b0.x, fmaf(c2, b2.x, accA.z));
        accA.w = fmaf(c0, b0.y, fmaf(c2, b2.y, accA.w));
        accB.x = fmaf(c1, a1.x, fmaf(c3, a3.x, accB.x));
        accB.y = fmaf(c1, a1.y, fmaf(c3, a3.y, accB.y));
        accB.z = fmaf(c1, b1.x, fmaf(c3, b3.x, accB.z));
        accB.w = fmaf(c1, b1.y, fmaf(c3, b3.y, accB.w));
    }
    for (; e < end; ++e) {
        int s0 = esrc[e];
        float c0 = dis[s0] * dn;
        float2 w0 = in8[(size_t)s0 * 32 + lane];
        float2 a0 = __half22float2(*(__half2*)&w0.x), b0 = __half22float2(*(__half2*)&w0.y);
        accA.x = fmaf(c0, a0.x, accA.x);
        accA.y = fmaf(c0, a0.y, accA.y);
        accA.z = fmaf(c0, b0.x, accA.z);
        accA.w = fmaf(c0, b0.y, accA.w);
    }
    float4 acc = make_float4(accA.x + accB.x, accA.y + accB.y,
                             accA.z + accB.z, accA.w + accB.w);

    // emit fp16 A-frag (KCA=4)
    int f0 = lane * 4;
    int kc = f0 >> 5;
    int lidx = rr | (((f0 & 31) >> 3) << 4);
    int j0 = f0 & 7;
    size_t base = ((size_t)rowblk * 4 + kc) * 512 + (size_t)lidx * 8 + j0;
    ushort4 hv;
    hv.x = __half_as_ushort(__float2half(acc.x));
    hv.y = __half_as_ushort(__float2half(acc.y));
    hv.z = __half_as_ushort(__float2half(acc.z));
    hv.w = __half_as_ushort(__float2half(acc.w));
    *(ushort4*)(af + base) = hv;
}

// ---------------- layer-0 MFMA GEMM (bf16 split A & W) + fused BN/ReLU ----------------
__global__ __launch_bounds__(256) void k_gemm_m(
        const unsigned short* __restrict__ agh, const unsigned short* __restrict__ agl,
        const unsigned short* __restrict__ wh, const unsigned short* __restrict__ wl,
        const float* __restrict__ bias, const float* __restrict__ gamma,
        const float* __restrict__ beta, const float* __restrict__ mean,
        const float* __restrict__ var, __half* __restrict__ outh, int n) {
    __shared__ unsigned short lbh[8 * 512];
    __shared__ unsigned short lbl[8 * 512];
    int tid = threadIdx.x;
    for (int i = tid; i < 1024; i += 256) {
        ((ushort4*)lbh)[i] = ((const ushort4*)wh)[i];
        ((ushort4*)lbl)[i] = ((const ushort4*)wl)[i];
    }
    __syncthreads();

    int wave = tid >> 6, lane = tid & 63;
    int grb0 = blockIdx.x * 8 + wave * 2;

    f32x4 acc[2][8] = {};

    short8 a0h = *(const short8*)(agh + (size_t)grb0 * 512 + lane * 8);
    short8 a0l = *(const short8*)(agl + (size_t)grb0 * 512 + lane * 8);
    short8 a1h = *(const short8*)(agh + (size_t)(grb0 + 1) * 512 + lane * 8);
    short8 a1l = *(const short8*)(agl + (size_t)(grb0 + 1) * 512 + lane * 8);
    #pragma unroll
    for (int cb = 0; cb < 8; ++cb) {
        short8 bh = *(const short8*)(lbh + (size_t)(cb * 64 + lane) * 8);
        short8 bl = *(const short8*)(lbl + (size_t)(cb * 64 + lane) * 8);
        acc[0][cb] = __builtin_amdgcn_mfma_f32_16x16x32_bf16(a0h, bh, acc[0][cb], 0, 0, 0);
        acc[0][cb] = __builtin_amdgcn_mfma_f32_16x16x32_bf16(a0h, bl, acc[0][cb], 0, 0, 0);
        acc[0][cb] = __builtin_amdgcn_mfma_f32_16x16x32_bf16(a0l, bh, acc[0][cb], 0, 0, 0);
        acc[1][cb] = __builtin_amdgcn_mfma_f32_16x16x32_bf16(a1h, bh, acc[1][cb], 0, 0, 0);
        acc[1][cb] = __builtin_amdgcn_mfma_f32_16x16x32_bf16(a1h, bl, acc[1][cb], 0, 0, 0);
        acc[1][cb] = __builtin_amdgcn_mfma_f32_16x16x32_bf16(a1l, bh, acc[1][cb], 0, 0, 0);
    }

    int colbase = lane & 15;
    float scv[8], shv[8];
    #pragma unroll
    for (int cb = 0; cb < 8; ++cb) {
        int c = cb * 16 + colbase;
        float s = gamma[c] * rsqrtf(var[c] + BN_EPS);
        scv[cb] = s;
        shv[cb] = beta[c] + (bias[c] - mean[c]) * s;
    }
    int r0 = (lane >> 4) * 4;
    #pragma unroll
    for (int rb = 0; rb < 2; ++rb) {
        int rowb = (grb0 + rb) * 16 + r0;
        #pragma unroll
        for (int rg = 0; rg < 4; ++rg) {
            int row = rowb + rg;
            if (row < n) {
                #pragma unroll
                for (int cb = 0; cb < 8; ++cb) {
                    float v = fmaxf(fmaf(acc[rb][cb][rg], scv[cb], shv[cb]), 0.f);
                    outh[(size_t)row * HD + cb * 16 + colbase] = __float2half(v);
                }
            }
        }
    }
}

// ---------------- hidden-layer MFMA GEMM (fp16 A exact, fp16 W hi/lo) ----------------
// POOL=false: write fp16 h (next gather input). POOL=true: fused mean/max pooling,
// no h output at all (LDS per-graph reduction, rows are batch-sorted).
template<bool POOL>
__global__ __launch_bounds__(256) void k_gemm_h(
        const unsigned short* __restrict__ af,
        const unsigned short* __restrict__ wh, const unsigned short* __restrict__ wl,
        const float* __restrict__ bias, const float* __restrict__ gamma,
        const float* __restrict__ beta, const float* __restrict__ mean,
        const float* __restrict__ var, __half* __restrict__ outh,
        const int* __restrict__ batch, float* __restrict__ gsum,
        unsigned int* __restrict__ gmax, int n) {
    __shared__ unsigned short lbh[16384];   // 32 KB fp16 W hi
    __shared__ unsigned short lbl[16384];   // 32 KB fp16 W lo
    int tid = threadIdx.x;
    for (int i = tid; i < 4096; i += 256) {
        ((ushort4*)lbh)[i] = ((const ushort4*)wh)[i];
        ((ushort4*)lbl)[i] = ((const ushort4*)wl)[i];
    }
    __syncthreads();

    int wave = tid >> 6, lane = tid & 63;
    int grb0 = blockIdx.x * 8 + wave * 2;

    f32x4 acc[2][8] = {};

    #pragma unroll
    for (int kc = 0; kc < 4; ++kc) {
        half8 a0 = *(const half8*)(af + ((size_t)grb0 * 4 + kc) * 512 + lane * 8);
        half8 a1 = *(const half8*)(af + ((size_t)(grb0 + 1) * 4 + kc) * 512 + lane * 8);
        #pragma unroll
        for (int cb = 0; cb < 8; ++cb) {
            half8 bh = *(const half8*)(lbh + (size_t)((cb * 4 + kc) * 64 + lane) * 8);
            half8 bl = *(const half8*)(lbl + (size_t)((cb * 4 + kc) * 64 + lane) * 8);
            acc[0][cb] = __builtin_amdgcn_mfma_f32_16x16x32_f16(a0, bh, acc[0][cb], 0, 0, 0);
            acc[0][cb] = __builtin_amdgcn_mfma_f32_16x16x32_f16(a0, bl, acc[0][cb], 0, 0, 0);
            acc[1][cb] = __builtin_amdgcn_mfma_f32_16x16x32_f16(a1, bh, acc[1][cb], 0, 0, 0);
            acc[1][cb] = __builtin_amdgcn_mfma_f32_16x16x32_f16(a1, bl, acc[1][cb], 0, 0, 0);
        }
    }

    int colbase = lane & 15;
    float scv[8], shv[8];
    #pragma unroll
    for (int cb = 0; cb < 8; ++cb) {
        int c = cb * 16 + colbase;
        float s = gamma[c] * rsqrtf(var[c] + BN_EPS);
        scv[cb] = s;
        shv[cb] = beta[c] + (bias[c] - mean[c]) * s;
    }
    int r0 = (lane >> 4) * 4;

    if (!POOL) {
        #pragma unroll
        for (int rb = 0; rb < 2; ++rb) {
            int rowb = (grb0 + rb) * 16 + r0;
            #pragma unroll
            for (int rg = 0; rg < 4; ++rg) {
                int row = rowb + rg;
                if (row < n) {
                    #pragma unroll
                    for (int cb = 0; cb < 8; ++cb) {
                        float v = fmaxf(fmaf(acc[rb][cb][rg], scv[cb], shv[cb]), 0.f);
                        outh[(size_t)row * HD + cb * 16 + colbase] = __float2half(v);
                    }
                }
            }
        }
    } else {
        // fused mean/max pooling: block covers 128 consecutive rows (sorted batch)
        int row0 = blockIdx.x * 128;
        int row_hi = min(n - 1, row0 + 127);
        int g_lo = batch[row0];
        int g_hi = batch[row_hi];

        int gval[2][4];
        #pragma unroll
        for (int rb = 0; rb < 2; ++rb) {
            int rowb = (grb0 + rb) * 16 + r0;
            #pragma unroll
            for (int rg = 0; rg < 4; ++rg) {
                int row = rowb + rg;
                gval[rb][rg] = (row < n) ? batch[row] : -1;
            }
        }

        __syncthreads();                       // done reading weight LDS
        float* lds_sum = reinterpret_cast<float*>(lbh);            // [4][128]
        unsigned int* lds_max = reinterpret_cast<unsigned int*>(lbh) + 512;

        for (int gbase = g_lo; gbase <= g_hi; gbase += 4) {
            for (int i = tid; i < 512; i += 256) {
                lds_sum[i] = 0.f;
                lds_max[i] = 0u;
            }
            __syncthreads();
            #pragma unroll
            for (int rb = 0; rb < 2; ++rb) {
                #pragma unroll
                for (int rg = 0; rg < 4; ++rg) {
                    int g = gval[rb][rg];
                    if (g >= gbase && g < gbase + 4) {
                        int sbase = (g - gbase) * 128;
                        #pragma unroll
                        for (int cb = 0; cb < 8; ++cb) {
                            float v = fmaxf(fmaf(acc[rb][cb][rg], scv[cb], shv[cb]), 0.f);
                            int col = cb * 16 + colbase;
                            atomicAdd(&lds_sum[sbase + col], v);
                            atomicMax(&lds_max[sbase + col], __float_as_uint(v));
                        }
                    }
                }
            }
            __syncthreads();
            for (int i = tid; i < 512; i += 256) {
                int s = i >> 7, col = i & 127;
                int g = gbase + s;
                if (g <= g_hi) {
                    atomicAdd(&gsum[g * HD + col], lds_sum[i]);
                    atomicMax(&gmax[g * HD + col], lds_max[i]);
                }
            }
            __syncthreads();
        }
    }
}

// ---------------- fused head: relu([mean||max]@pool_W+pool_b) @ out_W + out_b ----
__global__ void k_head(const float* __restrict__ gsum, const unsigned int* __restrict__ gmax,
                       const int* __restrict__ starts, const float* __restrict__ pool_W,
                       const float* __restrict__ pool_b, const float* __restrict__ out_W,
                       const float* __restrict__ out_b, float* __restrict__ out) {
    int g = blockIdx.x, t = threadIdx.x;   // t in [0,128)
    __shared__ float pooled[2 * HD];
    __shared__ float hid_s[HD];
    float cntf = fmaxf((float)(starts[g + 1] - starts[g]), 1.f);
    pooled[t] = gsum[g * HD + t] / cntf;
    pooled[HD + t] = __uint_as_float(gmax[g * HD + t]);
    __syncthreads();
    float acc = pool_b[t];
    for (int k = 0; k < 2 * HD; ++k)
        acc += pooled[k] * pool_W[k * HD + t];
    hid_s[t] = fmaxf(acc, 0.f);
    __syncthreads();
    if (t < 64) {
        float a2 = out_b[t];
        for (int j = 0; j < HD; ++j)
            a2 += hid_s[j] * out_W[j * 64 + t];
        out[g * 64 + t] = a2;
    }
}

extern "C" void kernel_launch(void* const* d_in, const int* in_sizes, int n_in,
                              void* d_out, int out_size, void* d_ws, size_t ws_size,
                              hipStream_t stream) {
    const float* x        = (const float*)d_in[0];
    const int*   eidx     = (const int*)d_in[1];
    const int*   batch    = (const int*)d_in[2];
    const float* W0       = (const float*)d_in[3];
    const float* Wh       = (const float*)d_in[4];
    const float* b        = (const float*)d_in[5];
    const float* bn_gamma = (const float*)d_in[6];
    const float* bn_beta  = (const float*)d_in[7];
    const float* bn_mean  = (const float*)d_in[8];
    const float* bn_var   = (const float*)d_in[9];
    const float* pool_W   = (const float*)d_in[10];
    const float* pool_b   = (const float*)d_in[11];
    const float* out_W    = (const float*)d_in[12];
    const float* out_b    = (const float*)d_in[13];
    float* out = (float*)d_out;

    const int N = in_sizes[2];
    const int E = in_sizes[1] / 2;
    const int L = in_sizes[5] / HD;
    const int G = out_size / (HD / 2);

    const int* src = eidx;
    const int* dst = eidx + E;

    const int NBLK = (N + 127) / 128;          // GEMM blocks (128 rows each)
    const size_t NRB = (size_t)NBLK * 8;       // padded rowblocks

    // workspace layout (16B-aligned chunks first)
    char* p = (char*)d_ws;
    __half* hf   = (__half*)p; p += (size_t)NBLK * 128 * HD * 2; // inter-layer fp16
    unsigned short* af  = (unsigned short*)p; p += NRB * 4 * 512 * 2;  // fp16 A frags
    unsigned short* agh = (unsigned short*)p; p += NRB * 512 * 2;      // layer0 bf16 hi
    unsigned short* agl = (unsigned short*)p; p += NRB * 512 * 2;      // layer0 bf16 lo
    unsigned short* whi0 = (unsigned short*)p; p += (size_t)16384 * 2;
    unsigned short* wlo0 = (unsigned short*)p; p += (size_t)16384 * 2;
    unsigned short* whf  = (unsigned short*)p; p += (size_t)3 * 16384 * 2;
    unsigned short* wlf  = (unsigned short*)p; p += (size_t)3 * 16384 * 2;
    unsigned short* esrc = (unsigned short*)p; p += (((size_t)E * 2 + 15) & ~15ull);
    unsigned short* ord  = (unsigned short*)p; p += (((size_t)E * 2 + 15) & ~15ull);
    int*   counts  = (int*)p;   p += (size_t)N * 4;
    float* dis     = (float*)p; p += (size_t)N * 4;
    int*   offs    = (int*)p;   p += (size_t)(N + 1) * 4;
    int*   bsums   = (int*)p;   p += 256 * 4;
    float* gsum    = (float*)p; p += (size_t)G * HD * 4;
    unsigned int* gmax = (unsigned int*)p; p += (size_t)G * HD * 4;  // adjacent to gsum
    int*   starts  = (int*)p;   p += (size_t)(G + 1) * 4;
    (void)ws_size; (void)n_in;

    // zero accumulators (gsum+gmax adjacent -> single memset)
    hipMemsetAsync(counts, 0, (size_t)N * 4, stream);
    hipMemsetAsync(gsum, 0, (size_t)G * HD * 8, stream);

    const int NB = (N + 255) / 256;

    k_count<<<1024, 256, 0, stream>>>(dst, counts, ord, E);
    k_scan1<<<NB, 256, 0, stream>>>(counts, offs, bsums, N);
    k_scan2<<<1, 256, 0, stream>>>(bsums, NB, batch, starts, N, G);
    k_scan3<<<NB, 256, 0, stream>>>(offs, bsums, counts, dis, N);
    k_fill<<<1024, 256, 0, stream>>>(src, dst, ord, offs, esrc, E);
    k_wsplit<<<256, 256, 0, stream>>>(W0, Wh, whi0, wlo0, whf, wlf);

    // layer 0: aggregate x (24 feats, K padded to 32), bf16 MFMA GEMM -> fp16
    k_agg_x<<<(N + 31) / 32, 256, 0, stream>>>(x, offs, counts, esrc, dis, agh, agl, N);
    k_gemm_m<<<NBLK, 256, 0, stream>>>(agh, agl, whi0, wlo0, b, bn_gamma, bn_beta,
                                       bn_mean, bn_var, hf, N);

    // layers 1..L-1: aggregate hf (fp16) -> fp16 A-frags, fp16-MFMA GEMM
    for (int l = 1; l < L; ++l) {
        k_agg_h<<<(N + 7) / 8, 256, 0, stream>>>(hf, offs, counts, esrc, dis, af, N);
        const unsigned short* wh_l = whf + (size_t)(l - 1) * 16384;
        const unsigned short* wl_l = wlf + (size_t)(l - 1) * 16384;
        if (l < L - 1)
            k_gemm_h<false><<<NBLK, 256, 0, stream>>>(af, wh_l, wl_l,
                b + l * HD, bn_gamma + l * HD, bn_beta + l * HD,
                bn_mean + l * HD, bn_var + l * HD, hf, batch, gsum, gmax, N);
        else
            k_gemm_h<true><<<NBLK, 256, 0, stream>>>(af, wh_l, wl_l,
                b + l * HD, bn_gamma + l * HD, bn_beta + l * HD,
                bn_mean + l * HD, bn_var + l * HD, nullptr, batch, gsum, gmax, N);
    }

    // head
    k_head<<<G, HD, 0, stream>>>(gsum, gmax, starts, pool_W, pool_b, out_W, out_b, out);
}

// Round 10
// 267.828 us; speedup vs baseline: 4.2275x; 1.0269x over previous
//
#include <hip/hip_runtime.h>
#include <hip/hip_bf16.h>
#include <hip/hip_fp16.h>

#define HD 128          // hidden dim
#define BN_EPS 1e-5f

typedef __attribute__((ext_vector_type(8))) short short8;
typedef __attribute__((ext_vector_type(8))) _Float16 half8;
typedef __attribute__((ext_vector_type(4))) float f32x4;

// round-to-nearest-even f32 -> bf16 bits; rem = v - bf16(v)
__device__ inline unsigned short f2bf(float v, float& rem) {
    unsigned u = __float_as_uint(v);
    unsigned r = (u + 0x7FFFu + ((u >> 16) & 1u)) >> 16;
    rem = v - __uint_as_float(r << 16);
    return (unsigned short)r;
}

// ---------------- degree count + within-destination ordinal ----------------
__global__ void k_count(const int* __restrict__ dst, int* __restrict__ counts,
                        unsigned short* __restrict__ ord, int E) {
    int i = blockIdx.x * blockDim.x + threadIdx.x;
    for (; i < E; i += gridDim.x * blockDim.x) {
        int pos = atomicAdd(&counts[dst[i]], 1);
        ord[i] = (unsigned short)pos;
    }
}

// ---------------- exclusive scan ----------------
__global__ void k_scan1(const int* __restrict__ counts, int* __restrict__ offs,
                        int* __restrict__ bsums, int n) {
    __shared__ int s[256];
    int t = threadIdx.x, i = blockIdx.x * 256 + t;
    int v = (i < n) ? counts[i] : 0;
    s[t] = v; __syncthreads();
    for (int d = 1; d < 256; d <<= 1) {
        int x = (t >= d) ? s[t - d] : 0;
        __syncthreads(); s[t] += x; __syncthreads();
    }
    if (i < n) offs[i] = s[t] - v;
    if (t == 255) bsums[blockIdx.x] = s[255];
}

// scan of block sums + graph segment boundaries (batch is sorted) fused
__global__ void k_scan2(int* __restrict__ bsums, int nb,
                        const int* __restrict__ batch, int* __restrict__ starts,
                        int n, int G) {
    __shared__ int s[256];
    int t = threadIdx.x;
    int v = (t < nb) ? bsums[t] : 0;
    s[t] = v; __syncthreads();
    for (int d = 1; d < 256; d <<= 1) {
        int x = (t >= d) ? s[t - d] : 0;
        __syncthreads(); s[t] += x; __syncthreads();
    }
    if (t < nb) bsums[t] = s[t] - v;
    if (t <= G) {                        // lower_bound(batch, t)
        int lo = 0, hi = n;
        while (lo < hi) {
            int mid = (lo + hi) >> 1;
            if (batch[mid] < t) lo = mid + 1; else hi = mid;
        }
        starts[t] = lo;
    }
}

// scan finalize + dis = rsqrt(deg) fused
__global__ void k_scan3(int* __restrict__ offs, const int* __restrict__ bsums,
                        const int* __restrict__ counts, float* __restrict__ dis, int n) {
    int i = blockIdx.x * 256 + threadIdx.x;
    if (i < n) {
        offs[i] += bsums[blockIdx.x];
        dis[i] = rsqrtf((float)(counts[i] + 1));   // +1 self loop
    }
}

// ---------------- CSR fill: atomic-free via precomputed ordinals ----------------
__global__ void k_fill(const int* __restrict__ src, const int* __restrict__ dst,
                       const unsigned short* __restrict__ ord, const int* __restrict__ offs,
                       unsigned short* __restrict__ esrc, int E) {
    int i = blockIdx.x * blockDim.x + threadIdx.x;
    for (; i < E; i += gridDim.x * blockDim.x) {
        int s = src[i], d = dst[i];
        esrc[offs[d] + ord[i]] = (unsigned short)s;
    }
}

// ---------------- W split into MFMA B-fragment layout ----------------
// layer 0: bf16 hi/lo, K padded to 32 (KC=1); layers 1..3: fp16 hi/lo (KC=4).
__global__ void k_wsplit(const float* __restrict__ W0, const float* __restrict__ Wh,
                         unsigned short* __restrict__ whi0, unsigned short* __restrict__ wlo0,
                         unsigned short* __restrict__ whf, unsigned short* __restrict__ wlf) {
    int idx = blockIdx.x * 256 + threadIdx.x;     // 4 * 128 * 128
    int l = idx >> 14, rest = idx & 16383;
    int k = rest >> 7, c = rest & 127;
    int cb = c >> 4, kc = k >> 5;
    int lane = (c & 15) | (((k & 31) >> 3) << 4);
    int j = k & 7;
    if (l == 0) {
        if (k >= 32) return;
        float val = (k < 24) ? W0[k * HD + c] : 0.f;
        float rem, rem2;
        unsigned short hi = f2bf(val, rem);
        unsigned short lo = f2bf(rem, rem2);
        size_t addr = (size_t)(cb * 64 + lane) * 8 + j;
        whi0[addr] = hi; wlo0[addr] = lo;
    } else {
        float val = Wh[(size_t)(l - 1) * HD * HD + (size_t)k * HD + c];
        __half h = __float2half(val);
        float rem = val - __half2float(h);
        __half lo = __float2half(rem);
        size_t addr = (size_t)(l - 1) * 16384 + (size_t)((cb * 4 + kc) * 64 + lane) * 8 + j;
        whf[addr] = __half_as_ushort(h);
        wlf[addr] = __half_as_ushort(lo);
    }
}

// ---------------- layer-0 aggregation: out = Â x (f32 input, 24 feats) --------
// emits bf16 hi/lo A-frags, KC=1.
__global__ void k_agg_x(const float* __restrict__ in, const int* __restrict__ offs,
                        const int* __restrict__ counts, const unsigned short* __restrict__ esrc,
                        const float* __restrict__ dis, unsigned short* __restrict__ ohi,
                        unsigned short* __restrict__ olo, int n) {
    const int FQ = 6, GRP = 8;
    int grp = threadIdx.x / GRP;
    int lane = threadIdx.x % GRP;
    int node = blockIdx.x * (blockDim.x / GRP) + grp;
    if (node >= n) return;
    int rowblk = node >> 4, rr = node & 15;

    if (lane == FQ) {          // zero-fill features 24..31 (K pad)
        size_t base = (size_t)rowblk * 512 + (size_t)(rr + 48) * 8;
        ushort4 z = make_ushort4(0, 0, 0, 0);
        *(ushort4*)(ohi + base) = z; *(ushort4*)(ohi + base + 4) = z;
        *(ushort4*)(olo + base) = z; *(ushort4*)(olo + base + 4) = z;
    }
    if (lane >= FQ) return;

    const float4* in4 = reinterpret_cast<const float4*>(in);
    float dn = dis[node];
    float sl = dn * dn;
    float4 a = in4[(size_t)node * FQ + lane];
    float4 accA = make_float4(sl * a.x, sl * a.y, sl * a.z, sl * a.w);
    float4 accB = make_float4(0.f, 0.f, 0.f, 0.f);

    int e = offs[node], end = e + counts[node];
    for (; e + 3 < end; e += 4) {
        int s0 = esrc[e],     s1 = esrc[e + 1];
        int s2 = esrc[e + 2], s3 = esrc[e + 3];
        float c0 = dis[s0] * dn, c1 = dis[s1] * dn;
        float c2 = dis[s2] * dn, c3 = dis[s3] * dn;
        float4 v0 = in4[(size_t)s0 * FQ + lane];
        float4 v1 = in4[(size_t)s1 * FQ + lane];
        float4 v2 = in4[(size_t)s2 * FQ + lane];
        float4 v3 = in4[(size_t)s3 * FQ + lane];
        accA.x = fmaf(c0, v0.x, fmaf(c2, v2.x, accA.x));
        accA.y = fmaf(c0, v0.y, fmaf(c2, v2.y, accA.y));
        accA.z = fmaf(c0, v0.z, fmaf(c2, v2.z, accA.z));
        accA.w = fmaf(c0, v0.w, fmaf(c2, v2.w, accA.w));
        accB.x = fmaf(c1, v1.x, fmaf(c3, v3.x, accB.x));
        accB.y = fmaf(c1, v1.y, fmaf(c3, v3.y, accB.y));
        accB.z = fmaf(c1, v1.z, fmaf(c3, v3.z, accB.z));
        accB.w = fmaf(c1, v1.w, fmaf(c3, v3.w, accB.w));
    }
    for (; e < end; ++e) {
        int s0 = esrc[e];
        float c0 = dis[s0] * dn;
        float4 v0 = in4[(size_t)s0 * FQ + lane];
        accA.x = fmaf(c0, v0.x, accA.x);
        accA.y = fmaf(c0, v0.y, accA.y);
        accA.z = fmaf(c0, v0.z, accA.z);
        accA.w = fmaf(c0, v0.w, accA.w);
    }
    float4 acc = make_float4(accA.x + accB.x, accA.y + accB.y,
                             accA.z + accB.z, accA.w + accB.w);

    int f0 = lane * 4;
    int lidx = rr | (((f0 & 31) >> 3) << 4);
    int j0 = f0 & 7;
    size_t base = (size_t)rowblk * 512 + (size_t)lidx * 8 + j0;
    float r0, r1, r2, r3, d0;
    ushort4 hi, lo;
    hi.x = f2bf(acc.x, r0); hi.y = f2bf(acc.y, r1);
    hi.z = f2bf(acc.z, r2); hi.w = f2bf(acc.w, r3);
    lo.x = f2bf(r0, d0); lo.y = f2bf(r1, d0);
    lo.z = f2bf(r2, d0); lo.w = f2bf(r3, d0);
    *(ushort4*)(ohi + base) = hi;
    *(ushort4*)(olo + base) = lo;
}

// ---------------- hidden-layer aggregation, XCD-affine feature-sliced ----------
// blockIdx%8 -> XCD (empirical round-robin); XCD pair {2c,2c+1} owns column
// group c (32 features = 64B/edge). Each XCD's h-slice (3.2MB) is L2-resident.
// 8 lanes per node x 4 fp16 features; emits fp16 A-frags for kc = cg.
__global__ void k_agg_h(const __half* __restrict__ in, const int* __restrict__ offs,
                        const int* __restrict__ counts, const unsigned short* __restrict__ esrc,
                        const float* __restrict__ dis, unsigned short* __restrict__ af, int n) {
    int b = blockIdx.x;
    int cg = (b & 7) >> 1;                     // column group 0..3
    int chunk = ((b >> 3) << 1) | (b & 1);     // node chunk within colgroup
    int grp = threadIdx.x >> 3;                // 32 nodes per block
    int lane = threadIdx.x & 7;                // feature-quad within colgroup
    int node = chunk * 32 + grp;
    if (node >= n) return;
    int rowblk = node >> 4, rr = node & 15;
    int fq = cg * 8 + lane;                    // feature-quad within full row

    const float2* in8 = reinterpret_cast<const float2*>(in);  // 4 halves per elem
    float dn = dis[node];
    float sl = dn * dn;

    float2 raw = in8[(size_t)node * 32 + fq];
    float2 f0v = __half22float2(*(__half2*)&raw.x);
    float2 f1v = __half22float2(*(__half2*)&raw.y);
    float4 accA = make_float4(sl * f0v.x, sl * f0v.y, sl * f1v.x, sl * f1v.y);
    float4 accB = make_float4(0.f, 0.f, 0.f, 0.f);

    int e = offs[node], end = e + counts[node];
    for (; e + 3 < end; e += 4) {
        int s0 = esrc[e],     s1 = esrc[e + 1];
        int s2 = esrc[e + 2], s3 = esrc[e + 3];
        float c0 = dis[s0] * dn, c1 = dis[s1] * dn;
        float c2 = dis[s2] * dn, c3 = dis[s3] * dn;
        float2 w0 = in8[(size_t)s0 * 32 + fq];
        float2 w1 = in8[(size_t)s1 * 32 + fq];
        float2 w2 = in8[(size_t)s2 * 32 + fq];
        float2 w3 = in8[(size_t)s3 * 32 + fq];
        float2 a0 = __half22float2(*(__half2*)&w0.x), b0 = __half22float2(*(__half2*)&w0.y);
        float2 a1 = __half22float2(*(__half2*)&w1.x), b1 = __half22float2(*(__half2*)&w1.y);
        float2 a2 = __half22float2(*(__half2*)&w2.x), b2 = __half22float2(*(__half2*)&w2.y);
        float2 a3 = __half22float2(*(__half2*)&w3.x), b3 = __half22float2(*(__half2*)&w3.y);
        accA.x = fmaf(c0, a0.x, fmaf(c2, a2.x, accA.x));
        accA.y = fmaf(c0, a0.y, fmaf(c2, a2.y, accA.y));
        accA.z = fmaf(c0, b0.x, fmaf(c2, b2.x, accA.z));
        accA.w = fmaf(c0, b0.y, fmaf(c2, b2.y, accA.w));
        accB.x = fmaf(c1, a1.x, fmaf(c3, a3.x, accB.x));
        accB.y = fmaf(c1, a1.y, fmaf(c3, a3.y, accB.y));
        accB.z = fmaf(c1, b1.x, fmaf(c3, b3.x, accB.z));
        accB.w = fmaf(c1, b1.y, fmaf(c3, b3.y, accB.w));
    }
    for (; e < end; ++e) {
        int s0 = esrc[e];
        float c0 = dis[s0] * dn;
        float2 w0 = in8[(size_t)s0 * 32 + fq];
        float2 a0 = __half22float2(*(__half2*)&w0.x), b0 = __half22float2(*(__half2*)&w0.y);
        accA.x = fmaf(c0, a0.x, accA.x);
        accA.y = fmaf(c0, a0.y, accA.y);
        accA.z = fmaf(c0, b0.x, accA.z);
        accA.w = fmaf(c0, b0.y, accA.w);
    }
    float4 acc = make_float4(accA.x + accB.x, accA.y + accB.y,
                             accA.z + accB.z, accA.w + accB.w);

    // emit fp16 A-frag (kc = cg)
    int lidx = rr | ((lane >> 1) << 4);
    int j0 = (lane & 1) * 4;
    size_t base = ((size_t)rowblk * 4 + cg) * 512 + (size_t)lidx * 8 + j0;
    ushort4 hv;
    hv.x = __half_as_ushort(__float2half(acc.x));
    hv.y = __half_as_ushort(__float2half(acc.y));
    hv.z = __half_as_ushort(__float2half(acc.z));
    hv.w = __half_as_ushort(__float2half(acc.w));
    *(ushort4*)(af + base) = hv;
}

// ---------------- layer-0 MFMA GEMM (bf16 split A & W) + fused BN/ReLU ----------------
__global__ __launch_bounds__(256) void k_gemm_m(
        const unsigned short* __restrict__ agh, const unsigned short* __restrict__ agl,
        const unsigned short* __restrict__ wh, const unsigned short* __restrict__ wl,
        const float* __restrict__ bias, const float* __restrict__ gamma,
        const float* __restrict__ beta, const float* __restrict__ mean,
        const float* __restrict__ var, __half* __restrict__ outh, int n) {
    __shared__ unsigned short lbh[8 * 512];
    __shared__ unsigned short lbl[8 * 512];
    int tid = threadIdx.x;
    for (int i = tid; i < 1024; i += 256) {
        ((ushort4*)lbh)[i] = ((const ushort4*)wh)[i];
        ((ushort4*)lbl)[i] = ((const ushort4*)wl)[i];
    }
    __syncthreads();

    int wave = tid >> 6, lane = tid & 63;
    int grb0 = blockIdx.x * 8 + wave * 2;

    f32x4 acc[2][8] = {};

    short8 a0h = *(const short8*)(agh + (size_t)grb0 * 512 + lane * 8);
    short8 a0l = *(const short8*)(agl + (size_t)grb0 * 512 + lane * 8);
    short8 a1h = *(const short8*)(agh + (size_t)(grb0 + 1) * 512 + lane * 8);
    short8 a1l = *(const short8*)(agl + (size_t)(grb0 + 1) * 512 + lane * 8);
    #pragma unroll
    for (int cb = 0; cb < 8; ++cb) {
        short8 bh = *(const short8*)(lbh + (size_t)(cb * 64 + lane) * 8);
        short8 bl = *(const short8*)(lbl + (size_t)(cb * 64 + lane) * 8);
        acc[0][cb] = __builtin_amdgcn_mfma_f32_16x16x32_bf16(a0h, bh, acc[0][cb], 0, 0, 0);
        acc[0][cb] = __builtin_amdgcn_mfma_f32_16x16x32_bf16(a0h, bl, acc[0][cb], 0, 0, 0);
        acc[0][cb] = __builtin_amdgcn_mfma_f32_16x16x32_bf16(a0l, bh, acc[0][cb], 0, 0, 0);
        acc[1][cb] = __builtin_amdgcn_mfma_f32_16x16x32_bf16(a1h, bh, acc[1][cb], 0, 0, 0);
        acc[1][cb] = __builtin_amdgcn_mfma_f32_16x16x32_bf16(a1h, bl, acc[1][cb], 0, 0, 0);
        acc[1][cb] = __builtin_amdgcn_mfma_f32_16x16x32_bf16(a1l, bh, acc[1][cb], 0, 0, 0);
    }

    int colbase = lane & 15;
    float scv[8], shv[8];
    #pragma unroll
    for (int cb = 0; cb < 8; ++cb) {
        int c = cb * 16 + colbase;
        float s = gamma[c] * rsqrtf(var[c] + BN_EPS);
        scv[cb] = s;
        shv[cb] = beta[c] + (bias[c] - mean[c]) * s;
    }
    int r0 = (lane >> 4) * 4;
    #pragma unroll
    for (int rb = 0; rb < 2; ++rb) {
        int rowb = (grb0 + rb) * 16 + r0;
        #pragma unroll
        for (int rg = 0; rg < 4; ++rg) {
            int row = rowb + rg;
            if (row < n) {
                #pragma unroll
                for (int cb = 0; cb < 8; ++cb) {
                    float v = fmaxf(fmaf(acc[rb][cb][rg], scv[cb], shv[cb]), 0.f);
                    outh[(size_t)row * HD + cb * 16 + colbase] = __float2half(v);
                }
            }
        }
    }
}

// ---------------- hidden-layer MFMA GEMM (fp16 A exact, fp16 W hi/lo) ----------------
// POOL=false: write fp16 h. POOL=true: fused mean/max pooling via shuffle
// reduction + direct global atomics (no h output, no LDS atomics).
template<bool POOL>
__global__ __launch_bounds__(256) void k_gemm_h(
        const unsigned short* __restrict__ af,
        const unsigned short* __restrict__ wh, const unsigned short* __restrict__ wl,
        const float* __restrict__ bias, const float* __restrict__ gamma,
        const float* __restrict__ beta, const float* __restrict__ mean,
        const float* __restrict__ var, __half* __restrict__ outh,
        const int* __restrict__ batch, float* __restrict__ gsum,
        unsigned int* __restrict__ gmax, int n) {
    __shared__ unsigned short lbh[16384];   // 32 KB fp16 W hi
    __shared__ unsigned short lbl[16384];   // 32 KB fp16 W lo
    int tid = threadIdx.x;
    for (int i = tid; i < 4096; i += 256) {
        ((ushort4*)lbh)[i] = ((const ushort4*)wh)[i];
        ((ushort4*)lbl)[i] = ((const ushort4*)wl)[i];
    }
    __syncthreads();

    int wave = tid >> 6, lane = tid & 63;
    int grb0 = blockIdx.x * 8 + wave * 2;

    f32x4 acc[2][8] = {};

    #pragma unroll
    for (int kc = 0; kc < 4; ++kc) {
        half8 a0 = *(const half8*)(af + ((size_t)grb0 * 4 + kc) * 512 + lane * 8);
        half8 a1 = *(const half8*)(af + ((size_t)(grb0 + 1) * 4 + kc) * 512 + lane * 8);
        #pragma unroll
        for (int cb = 0; cb < 8; ++cb) {
            half8 bh = *(const half8*)(lbh + (size_t)((cb * 4 + kc) * 64 + lane) * 8);
            half8 bl = *(const half8*)(lbl + (size_t)((cb * 4 + kc) * 64 + lane) * 8);
            acc[0][cb] = __builtin_amdgcn_mfma_f32_16x16x32_f16(a0, bh, acc[0][cb], 0, 0, 0);
            acc[0][cb] = __builtin_amdgcn_mfma_f32_16x16x32_f16(a0, bl, acc[0][cb], 0, 0, 0);
            acc[1][cb] = __builtin_amdgcn_mfma_f32_16x16x32_f16(a1, bh, acc[1][cb], 0, 0, 0);
            acc[1][cb] = __builtin_amdgcn_mfma_f32_16x16x32_f16(a1, bl, acc[1][cb], 0, 0, 0);
        }
    }

    int colbase = lane & 15;
    float scv[8], shv[8];
    #pragma unroll
    for (int cb = 0; cb < 8; ++cb) {
        int c = cb * 16 + colbase;
        float s = gamma[c] * rsqrtf(var[c] + BN_EPS);
        scv[cb] = s;
        shv[cb] = beta[c] + (bias[c] - mean[c]) * s;
    }
    int r0 = (lane >> 4) * 4;

    if (!POOL) {
        #pragma unroll
        for (int rb = 0; rb < 2; ++rb) {
            int rowb = (grb0 + rb) * 16 + r0;
            #pragma unroll
            for (int rg = 0; rg < 4; ++rg) {
                int row = rowb + rg;
                if (row < n) {
                    #pragma unroll
                    for (int cb = 0; cb < 8; ++cb) {
                        float v = fmaxf(fmaf(acc[rb][cb][rg], scv[cb], shv[cb]), 0.f);
                        outh[(size_t)row * HD + cb * 16 + colbase] = __float2half(v);
                    }
                }
            }
        }
    } else {
        // fused mean/max pooling: shuffle-reduce rows, one atomic per wave/col
        int row0 = blockIdx.x * 128;
        int row_hi = min(n - 1, row0 + 127);
        int g_lo = batch[row0];
        int g_hi = batch[row_hi];

        int gval[2][4];
        #pragma unroll
        for (int rb = 0; rb < 2; ++rb) {
            int rowb = (grb0 + rb) * 16 + r0;
            #pragma unroll
            for (int rg = 0; rg < 4; ++rg) {
                int row = rowb + rg;
                gval[rb][rg] = (row < n) ? batch[row] : -1;
            }
        }

        for (int g = g_lo; g <= g_hi; ++g) {
            #pragma unroll
            for (int cb = 0; cb < 8; ++cb) {
                float s = 0.f, m = 0.f;
                #pragma unroll
                for (int rb = 0; rb < 2; ++rb) {
                    #pragma unroll
                    for (int rg = 0; rg < 4; ++rg) {
                        if (gval[rb][rg] == g) {
                            float v = fmaxf(fmaf(acc[rb][cb][rg], scv[cb], shv[cb]), 0.f);
                            s += v;
                            m = fmaxf(m, v);
                        }
                    }
                }
                // reduce across the 4 row-groups of the wave (lanes ^16, ^32)
                s += __shfl_xor(s, 16);
                m = fmaxf(m, __shfl_xor(m, 16));
                s += __shfl_xor(s, 32);
                m = fmaxf(m, __shfl_xor(m, 32));
                if (lane < 16 && (s != 0.f || m != 0.f)) {
                    atomicAdd(&gsum[g * HD + cb * 16 + colbase], s);
                    atomicMax(&gmax[g * HD + cb * 16 + colbase], __float_as_uint(m));
                }
            }
        }
    }
}

// ---------------- fused head: relu([mean||max]@pool_W+pool_b) @ out_W + out_b ----
__global__ void k_head(const float* __restrict__ gsum, const unsigned int* __restrict__ gmax,
                       const int* __restrict__ starts, const float* __restrict__ pool_W,
                       const float* __restrict__ pool_b, const float* __restrict__ out_W,
                       const float* __restrict__ out_b, float* __restrict__ out) {
    int g = blockIdx.x, t = threadIdx.x;   // t in [0,128)
    __shared__ float pooled[2 * HD];
    __shared__ float hid_s[HD];
    float cntf = fmaxf((float)(starts[g + 1] - starts[g]), 1.f);
    pooled[t] = gsum[g * HD + t] / cntf;
    pooled[HD + t] = __uint_as_float(gmax[g * HD + t]);
    __syncthreads();
    float acc = pool_b[t];
    for (int k = 0; k < 2 * HD; ++k)
        acc += pooled[k] * pool_W[k * HD + t];
    hid_s[t] = fmaxf(acc, 0.f);
    __syncthreads();
    if (t < 64) {
        float a2 = out_b[t];
        for (int j = 0; j < HD; ++j)
            a2 += hid_s[j] * out_W[j * 64 + t];
        out[g * 64 + t] = a2;
    }
}

extern "C" void kernel_launch(void* const* d_in, const int* in_sizes, int n_in,
                              void* d_out, int out_size, void* d_ws, size_t ws_size,
                              hipStream_t stream) {
    const float* x        = (const float*)d_in[0];
    const int*   eidx     = (const int*)d_in[1];
    const int*   batch    = (const int*)d_in[2];
    const float* W0       = (const float*)d_in[3];
    const float* Wh       = (const float*)d_in[4];
    const float* b        = (const float*)d_in[5];
    const float* bn_gamma = (const float*)d_in[6];
    const float* bn_beta  = (const float*)d_in[7];
    const float* bn_mean  = (const float*)d_in[8];
    const float* bn_var   = (const float*)d_in[9];
    const float* pool_W   = (const float*)d_in[10];
    const float* pool_b   = (const float*)d_in[11];
    const float* out_W    = (const float*)d_in[12];
    const float* out_b    = (const float*)d_in[13];
    float* out = (float*)d_out;

    const int N = in_sizes[2];
    const int E = in_sizes[1] / 2;
    const int L = in_sizes[5] / HD;
    const int G = out_size / (HD / 2);

    const int* src = eidx;
    const int* dst = eidx + E;

    const int NBLK = (N + 127) / 128;          // GEMM blocks (128 rows each)
    const size_t NRB = (size_t)NBLK * 8;       // padded rowblocks

    // workspace layout (16B-aligned chunks first)
    char* p = (char*)d_ws;
    __half* hf   = (__half*)p; p += (size_t)NBLK * 128 * HD * 2; // inter-layer fp16
    unsigned short* af  = (unsigned short*)p; p += NRB * 4 * 512 * 2;  // fp16 A frags
    unsigned short* agh = (unsigned short*)p; p += NRB * 512 * 2;      // layer0 bf16 hi
    unsigned short* agl = (unsigned short*)p; p += NRB * 512 * 2;      // layer0 bf16 lo
    unsigned short* whi0 = (unsigned short*)p; p += (size_t)16384 * 2;
    unsigned short* wlo0 = (unsigned short*)p; p += (size_t)16384 * 2;
    unsigned short* whf  = (unsigned short*)p; p += (size_t)3 * 16384 * 2;
    unsigned short* wlf  = (unsigned short*)p; p += (size_t)3 * 16384 * 2;
    unsigned short* esrc = (unsigned short*)p; p += (((size_t)E * 2 + 15) & ~15ull);
    unsigned short* ord  = (unsigned short*)p; p += (((size_t)E * 2 + 15) & ~15ull);
    int*   counts  = (int*)p;   p += (size_t)N * 4;
    float* dis     = (float*)p; p += (size_t)N * 4;
    int*   offs    = (int*)p;   p += (size_t)(N + 1) * 4;
    int*   bsums   = (int*)p;   p += 256 * 4;
    float* gsum    = (float*)p; p += (size_t)G * HD * 4;
    unsigned int* gmax = (unsigned int*)p; p += (size_t)G * HD * 4;  // adjacent to gsum
    int*   starts  = (int*)p;   p += (size_t)(G + 1) * 4;
    (void)ws_size; (void)n_in;

    // zero accumulators (gsum+gmax adjacent -> single memset)
    hipMemsetAsync(counts, 0, (size_t)N * 4, stream);
    hipMemsetAsync(gsum, 0, (size_t)G * HD * 8, stream);

    const int NB = (N + 255) / 256;

    k_count<<<1024, 256, 0, stream>>>(dst, counts, ord, E);
    k_scan1<<<NB, 256, 0, stream>>>(counts, offs, bsums, N);
    k_scan2<<<1, 256, 0, stream>>>(bsums, NB, batch, starts, N, G);
    k_scan3<<<NB, 256, 0, stream>>>(offs, bsums, counts, dis, N);
    k_fill<<<1024, 256, 0, stream>>>(src, dst, ord, offs, esrc, E);
    k_wsplit<<<256, 256, 0, stream>>>(W0, Wh, whi0, wlo0, whf, wlf);

    // layer 0: aggregate x (24 feats, K padded to 32), bf16 MFMA GEMM -> fp16
    k_agg_x<<<(N + 31) / 32, 256, 0, stream>>>(x, offs, counts, esrc, dis, agh, agl, N);
    k_gemm_m<<<NBLK, 256, 0, stream>>>(agh, agl, whi0, wlo0, b, bn_gamma, bn_beta,
                                       bn_mean, bn_var, hf, N);

    // layers 1..L-1: XCD-affine feature-sliced aggregation, fp16-MFMA GEMM
    const int CHUNKS = (N + 31) / 32;              // 32-node chunks per colgroup
    const int AGG_GRID = 8 * ((CHUNKS + 1) / 2);
    for (int l = 1; l < L; ++l) {
        k_agg_h<<<AGG_GRID, 256, 0, stream>>>(hf, offs, counts, esrc, dis, af, N);
        const unsigned short* wh_l = whf + (size_t)(l - 1) * 16384;
        const unsigned short* wl_l = wlf + (size_t)(l - 1) * 16384;
        if (l < L - 1)
            k_gemm_h<false><<<NBLK, 256, 0, stream>>>(af, wh_l, wl_l,
                b + l * HD, bn_gamma + l * HD, bn_beta + l * HD,
                bn_mean + l * HD, bn_var + l * HD, hf, batch, gsum, gmax, N);
        else
            k_gemm_h<true><<<NBLK, 256, 0, stream>>>(af, wh_l, wl_l,
                b + l * HD, bn_gamma + l * HD, bn_beta + l * HD,
                bn_mean + l * HD, bn_var + l * HD, nullptr, batch, gsum, gmax, N);
    }

    // head
    k_head<<<G, HD, 0, stream>>>(gsum, gmax, starts, pool_W, pool_b, out_W, out_b, out);
}

// Round 11
// 237.764 us; speedup vs baseline: 4.7620x; 1.1264x over previous
//
#include <hip/hip_runtime.h>
#include <hip/hip_bf16.h>
#include <hip/hip_fp16.h>

#define HD 128          // hidden dim
#define BN_EPS 1e-5f

typedef __attribute__((ext_vector_type(8))) short short8;
typedef __attribute__((ext_vector_type(8))) _Float16 half8;
typedef __attribute__((ext_vector_type(4))) float f32x4;

// round-to-nearest-even f32 -> bf16 bits; rem = v - bf16(v)
__device__ inline unsigned short f2bf(float v, float& rem) {
    unsigned u = __float_as_uint(v);
    unsigned r = (u + 0x7FFFu + ((u >> 16) & 1u)) >> 16;
    rem = v - __uint_as_float(r << 16);
    return (unsigned short)r;
}

// ---------------- degree count + within-destination ordinal ----------------
__global__ void k_count(const int* __restrict__ dst, int* __restrict__ counts,
                        unsigned short* __restrict__ ord, int E) {
    int i = blockIdx.x * blockDim.x + threadIdx.x;
    for (; i < E; i += gridDim.x * blockDim.x) {
        int pos = atomicAdd(&counts[dst[i]], 1);
        ord[i] = (unsigned short)pos;
    }
}

// ---------------- exclusive scan ----------------
__global__ void k_scan1(const int* __restrict__ counts, int* __restrict__ offs,
                        int* __restrict__ bsums, int n) {
    __shared__ int s[256];
    int t = threadIdx.x, i = blockIdx.x * 256 + t;
    int v = (i < n) ? counts[i] : 0;
    s[t] = v; __syncthreads();
    for (int d = 1; d < 256; d <<= 1) {
        int x = (t >= d) ? s[t - d] : 0;
        __syncthreads(); s[t] += x; __syncthreads();
    }
    if (i < n) offs[i] = s[t] - v;
    if (t == 255) bsums[blockIdx.x] = s[255];
}

// scan of block sums + graph segment boundaries (batch is sorted) fused
__global__ void k_scan2(int* __restrict__ bsums, int nb,
                        const int* __restrict__ batch, int* __restrict__ starts,
                        int n, int G) {
    __shared__ int s[256];
    int t = threadIdx.x;
    int v = (t < nb) ? bsums[t] : 0;
    s[t] = v; __syncthreads();
    for (int d = 1; d < 256; d <<= 1) {
        int x = (t >= d) ? s[t - d] : 0;
        __syncthreads(); s[t] += x; __syncthreads();
    }
    if (t < nb) bsums[t] = s[t] - v;
    if (t <= G) {                        // lower_bound(batch, t)
        int lo = 0, hi = n;
        while (lo < hi) {
            int mid = (lo + hi) >> 1;
            if (batch[mid] < t) lo = mid + 1; else hi = mid;
        }
        starts[t] = lo;
    }
}

// scan finalize + dis = rsqrt(deg) fused
__global__ void k_scan3(int* __restrict__ offs, const int* __restrict__ bsums,
                        const int* __restrict__ counts, float* __restrict__ dis, int n) {
    int i = blockIdx.x * 256 + threadIdx.x;
    if (i < n) {
        offs[i] += bsums[blockIdx.x];
        dis[i] = rsqrtf((float)(counts[i] + 1));   // +1 self loop
    }
}

// ---------------- CSR fill: atomic-free via precomputed ordinals ----------------
__global__ void k_fill(const int* __restrict__ src, const int* __restrict__ dst,
                       const unsigned short* __restrict__ ord, const int* __restrict__ offs,
                       unsigned short* __restrict__ esrc, int E) {
    int i = blockIdx.x * blockDim.x + threadIdx.x;
    for (; i < E; i += gridDim.x * blockDim.x) {
        int s = src[i], d = dst[i];
        esrc[offs[d] + ord[i]] = (unsigned short)s;
    }
}

// ---------------- W split into MFMA B-fragment layout ----------------
// layer 0: bf16 hi/lo, K padded to 32 (KC=1); layers 1..3: fp16 hi/lo (KC=4).
__global__ void k_wsplit(const float* __restrict__ W0, const float* __restrict__ Wh,
                         unsigned short* __restrict__ whi0, unsigned short* __restrict__ wlo0,
                         unsigned short* __restrict__ whf, unsigned short* __restrict__ wlf) {
    int idx = blockIdx.x * 256 + threadIdx.x;     // 4 * 128 * 128
    int l = idx >> 14, rest = idx & 16383;
    int k = rest >> 7, c = rest & 127;
    int cb = c >> 4, kc = k >> 5;
    int lane = (c & 15) | (((k & 31) >> 3) << 4);
    int j = k & 7;
    if (l == 0) {
        if (k >= 32) return;
        float val = (k < 24) ? W0[k * HD + c] : 0.f;
        float rem, rem2;
        unsigned short hi = f2bf(val, rem);
        unsigned short lo = f2bf(rem, rem2);
        size_t addr = (size_t)(cb * 64 + lane) * 8 + j;
        whi0[addr] = hi; wlo0[addr] = lo;
    } else {
        float val = Wh[(size_t)(l - 1) * HD * HD + (size_t)k * HD + c];
        __half h = __float2half(val);
        float rem = val - __half2float(h);
        __half lo = __float2half(rem);
        size_t addr = (size_t)(l - 1) * 16384 + (size_t)((cb * 4 + kc) * 64 + lane) * 8 + j;
        whf[addr] = __half_as_ushort(h);
        wlf[addr] = __half_as_ushort(lo);
    }
}

// ---------------- layer-0 aggregation: out = Â x (f32 input, 24 feats) --------
// emits bf16 hi/lo A-frags, KC=1.
__global__ void k_agg_x(const float* __restrict__ in, const int* __restrict__ offs,
                        const int* __restrict__ counts, const unsigned short* __restrict__ esrc,
                        const float* __restrict__ dis, unsigned short* __restrict__ ohi,
                        unsigned short* __restrict__ olo, int n) {
    const int FQ = 6, GRP = 8;
    int grp = threadIdx.x / GRP;
    int lane = threadIdx.x % GRP;
    int node = blockIdx.x * (blockDim.x / GRP) + grp;
    if (node >= n) return;
    int rowblk = node >> 4, rr = node & 15;

    if (lane == FQ) {          // zero-fill features 24..31 (K pad)
        size_t base = (size_t)rowblk * 512 + (size_t)(rr + 48) * 8;
        ushort4 z = make_ushort4(0, 0, 0, 0);
        *(ushort4*)(ohi + base) = z; *(ushort4*)(ohi + base + 4) = z;
        *(ushort4*)(olo + base) = z; *(ushort4*)(olo + base + 4) = z;
    }
    if (lane >= FQ) return;

    const float4* in4 = reinterpret_cast<const float4*>(in);
    float dn = dis[node];
    float sl = dn * dn;
    float4 a = in4[(size_t)node * FQ + lane];
    float4 accA = make_float4(sl * a.x, sl * a.y, sl * a.z, sl * a.w);
    float4 accB = make_float4(0.f, 0.f, 0.f, 0.f);

    int e = offs[node], end = e + counts[node];
    for (; e + 3 < end; e += 4) {
        int s0 = esrc[e],     s1 = esrc[e + 1];
        int s2 = esrc[e + 2], s3 = esrc[e + 3];
        float c0 = dis[s0] * dn, c1 = dis[s1] * dn;
        float c2 = dis[s2] * dn, c3 = dis[s3] * dn;
        float4 v0 = in4[(size_t)s0 * FQ + lane];
        float4 v1 = in4[(size_t)s1 * FQ + lane];
        float4 v2 = in4[(size_t)s2 * FQ + lane];
        float4 v3 = in4[(size_t)s3 * FQ + lane];
        accA.x = fmaf(c0, v0.x, fmaf(c2, v2.x, accA.x));
        accA.y = fmaf(c0, v0.y, fmaf(c2, v2.y, accA.y));
        accA.z = fmaf(c0, v0.z, fmaf(c2, v2.z, accA.z));
        accA.w = fmaf(c0, v0.w, fmaf(c2, v2.w, accA.w));
        accB.x = fmaf(c1, v1.x, fmaf(c3, v3.x, accB.x));
        accB.y = fmaf(c1, v1.y, fmaf(c3, v3.y, accB.y));
        accB.z = fmaf(c1, v1.z, fmaf(c3, v3.z, accB.z));
        accB.w = fmaf(c1, v1.w, fmaf(c3, v3.w, accB.w));
    }
    for (; e < end; ++e) {
        int s0 = esrc[e];
        float c0 = dis[s0] * dn;
        float4 v0 = in4[(size_t)s0 * FQ + lane];
        accA.x = fmaf(c0, v0.x, accA.x);
        accA.y = fmaf(c0, v0.y, accA.y);
        accA.z = fmaf(c0, v0.z, accA.z);
        accA.w = fmaf(c0, v0.w, accA.w);
    }
    float4 acc = make_float4(accA.x + accB.x, accA.y + accB.y,
                             accA.z + accB.z, accA.w + accB.w);

    int f0 = lane * 4;
    int lidx = rr | (((f0 & 31) >> 3) << 4);
    int j0 = f0 & 7;
    size_t base = (size_t)rowblk * 512 + (size_t)lidx * 8 + j0;
    float r0, r1, r2, r3, d0;
    ushort4 hi, lo;
    hi.x = f2bf(acc.x, r0); hi.y = f2bf(acc.y, r1);
    hi.z = f2bf(acc.z, r2); hi.w = f2bf(acc.w, r3);
    lo.x = f2bf(r0, d0); lo.y = f2bf(r1, d0);
    lo.z = f2bf(r2, d0); lo.w = f2bf(r3, d0);
    *(ushort4*)(ohi + base) = hi;
    *(ushort4*)(olo + base) = lo;
}

// ---------------- hidden-layer aggregation: out = Â h (fp16 in, fp16 A-frags out) --
// 32 lanes per node (4 features each); emits fp16 A-frags, KC=4.
__global__ void k_agg_h(const __half* __restrict__ in, const int* __restrict__ offs,
                        const int* __restrict__ counts, const unsigned short* __restrict__ esrc,
                        const float* __restrict__ dis, unsigned short* __restrict__ af, int n) {
    int grp = threadIdx.x >> 5;
    int lane = threadIdx.x & 31;
    int node = blockIdx.x * 8 + grp;
    if (node >= n) return;
    int rowblk = node >> 4, rr = node & 15;

    const float2* in8 = reinterpret_cast<const float2*>(in);  // 4 halves per elem
    float dn = dis[node];
    float sl = dn * dn;

    float2 raw = in8[(size_t)node * 32 + lane];
    __half2 p0 = *(__half2*)&raw.x, p1 = *(__half2*)&raw.y;
    float2 f0v = __half22float2(p0), f1v = __half22float2(p1);
    float4 accA = make_float4(sl * f0v.x, sl * f0v.y, sl * f1v.x, sl * f1v.y);
    float4 accB = make_float4(0.f, 0.f, 0.f, 0.f);

    int e = offs[node], end = e + counts[node];
    for (; e + 3 < end; e += 4) {
        int s0 = esrc[e],     s1 = esrc[e + 1];
        int s2 = esrc[e + 2], s3 = esrc[e + 3];
        float c0 = dis[s0] * dn, c1 = dis[s1] * dn;
        float c2 = dis[s2] * dn, c3 = dis[s3] * dn;
        float2 w0 = in8[(size_t)s0 * 32 + lane];
        float2 w1 = in8[(size_t)s1 * 32 + lane];
        float2 w2 = in8[(size_t)s2 * 32 + lane];
        float2 w3 = in8[(size_t)s3 * 32 + lane];
        float2 a0 = __half22float2(*(__half2*)&w0.x), b0 = __half22float2(*(__half2*)&w0.y);
        float2 a1 = __half22float2(*(__half2*)&w1.x), b1 = __half22float2(*(__half2*)&w1.y);
        float2 a2 = __half22float2(*(__half2*)&w2.x), b2 = __half22float2(*(__half2*)&w2.y);
        float2 a3 = __half22float2(*(__half2*)&w3.x), b3 = __half22float2(*(__half2*)&w3.y);
        accA.x = fmaf(c0, a0.x, fmaf(c2, a2.x, accA.x));
        accA.y = fmaf(c0, a0.y, fmaf(c2, a2.y, accA.y));
        accA.z = fmaf(c0, b0.x, fmaf(c2, b2.x, accA.z));
        accA.w = fmaf(c0, b0.y, fmaf(c2, b2.y, accA.w));
        accB.x = fmaf(c1, a1.x, fmaf(c3, a3.x, accB.x));
        accB.y = fmaf(c1, a1.y, fmaf(c3, a3.y, accB.y));
        accB.z = fmaf(c1, b1.x, fmaf(c3, b3.x, accB.z));
        accB.w = fmaf(c1, b1.y, fmaf(c3, b3.y, accB.w));
    }
    for (; e < end; ++e) {
        int s0 = esrc[e];
        float c0 = dis[s0] * dn;
        float2 w0 = in8[(size_t)s0 * 32 + lane];
        float2 a0 = __half22float2(*(__half2*)&w0.x), b0 = __half22float2(*(__half2*)&w0.y);
        accA.x = fmaf(c0, a0.x, accA.x);
        accA.y = fmaf(c0, a0.y, accA.y);
        accA.z = fmaf(c0, b0.x, accA.z);
        accA.w = fmaf(c0, b0.y, accA.w);
    }
    float4 acc = make_float4(accA.x + accB.x, accA.y + accB.y,
                             accA.z + accB.z, accA.w + accB.w);

    // emit fp16 A-frag (KCA=4)
    int f0 = lane * 4;
    int kc = f0 >> 5;
    int lidx = rr | (((f0 & 31) >> 3) << 4);
    int j0 = f0 & 7;
    size_t base = ((size_t)rowblk * 4 + kc) * 512 + (size_t)lidx * 8 + j0;
    ushort4 hv;
    hv.x = __half_as_ushort(__float2half(acc.x));
    hv.y = __half_as_ushort(__float2half(acc.y));
    hv.z = __half_as_ushort(__float2half(acc.z));
    hv.w = __half_as_ushort(__float2half(acc.w));
    *(ushort4*)(af + base) = hv;
}

// ---------------- layer-0 MFMA GEMM (bf16 split A & W) + fused BN/ReLU ----------------
__global__ __launch_bounds__(256) void k_gemm_m(
        const unsigned short* __restrict__ agh, const unsigned short* __restrict__ agl,
        const unsigned short* __restrict__ wh, const unsigned short* __restrict__ wl,
        const float* __restrict__ bias, const float* __restrict__ gamma,
        const float* __restrict__ beta, const float* __restrict__ mean,
        const float* __restrict__ var, __half* __restrict__ outh, int n) {
    __shared__ unsigned short lbh[8 * 512];
    __shared__ unsigned short lbl[8 * 512];
    int tid = threadIdx.x;
    for (int i = tid; i < 1024; i += 256) {
        ((ushort4*)lbh)[i] = ((const ushort4*)wh)[i];
        ((ushort4*)lbl)[i] = ((const ushort4*)wl)[i];
    }
    __syncthreads();

    int wave = tid >> 6, lane = tid & 63;
    int grb0 = blockIdx.x * 8 + wave * 2;

    f32x4 acc[2][8] = {};

    short8 a0h = *(const short8*)(agh + (size_t)grb0 * 512 + lane * 8);
    short8 a0l = *(const short8*)(agl + (size_t)grb0 * 512 + lane * 8);
    short8 a1h = *(const short8*)(agh + (size_t)(grb0 + 1) * 512 + lane * 8);
    short8 a1l = *(const short8*)(agl + (size_t)(grb0 + 1) * 512 + lane * 8);
    #pragma unroll
    for (int cb = 0; cb < 8; ++cb) {
        short8 bh = *(const short8*)(lbh + (size_t)(cb * 64 + lane) * 8);
        short8 bl = *(const short8*)(lbl + (size_t)(cb * 64 + lane) * 8);
        acc[0][cb] = __builtin_amdgcn_mfma_f32_16x16x32_bf16(a0h, bh, acc[0][cb], 0, 0, 0);
        acc[0][cb] = __builtin_amdgcn_mfma_f32_16x16x32_bf16(a0h, bl, acc[0][cb], 0, 0, 0);
        acc[0][cb] = __builtin_amdgcn_mfma_f32_16x16x32_bf16(a0l, bh, acc[0][cb], 0, 0, 0);
        acc[1][cb] = __builtin_amdgcn_mfma_f32_16x16x32_bf16(a1h, bh, acc[1][cb], 0, 0, 0);
        acc[1][cb] = __builtin_amdgcn_mfma_f32_16x16x32_bf16(a1h, bl, acc[1][cb], 0, 0, 0);
        acc[1][cb] = __builtin_amdgcn_mfma_f32_16x16x32_bf16(a1l, bh, acc[1][cb], 0, 0, 0);
    }

    int colbase = lane & 15;
    float scv[8], shv[8];
    #pragma unroll
    for (int cb = 0; cb < 8; ++cb) {
        int c = cb * 16 + colbase;
        float s = gamma[c] * rsqrtf(var[c] + BN_EPS);
        scv[cb] = s;
        shv[cb] = beta[c] + (bias[c] - mean[c]) * s;
    }
    int r0 = (lane >> 4) * 4;
    #pragma unroll
    for (int rb = 0; rb < 2; ++rb) {
        int rowb = (grb0 + rb) * 16 + r0;
        #pragma unroll
        for (int rg = 0; rg < 4; ++rg) {
            int row = rowb + rg;
            if (row < n) {
                #pragma unroll
                for (int cb = 0; cb < 8; ++cb) {
                    float v = fmaxf(fmaf(acc[rb][cb][rg], scv[cb], shv[cb]), 0.f);
                    outh[(size_t)row * HD + cb * 16 + colbase] = __float2half(v);
                }
            }
        }
    }
}

// ---------------- hidden-layer MFMA GEMM (fp16 A exact, fp16 W hi/lo) ----------------
// POOL=false: write fp16 h. POOL=true: fused mean/max pooling via shuffle
// reduction + direct global atomics (no h output, no LDS atomics).
template<bool POOL>
__global__ __launch_bounds__(256) void k_gemm_h(
        const unsigned short* __restrict__ af,
        const unsigned short* __restrict__ wh, const unsigned short* __restrict__ wl,
        const float* __restrict__ bias, const float* __restrict__ gamma,
        const float* __restrict__ beta, const float* __restrict__ mean,
        const float* __restrict__ var, __half* __restrict__ outh,
        const int* __restrict__ batch, float* __restrict__ gsum,
        unsigned int* __restrict__ gmax, int n) {
    __shared__ unsigned short lbh[16384];   // 32 KB fp16 W hi
    __shared__ unsigned short lbl[16384];   // 32 KB fp16 W lo
    int tid = threadIdx.x;
    for (int i = tid; i < 4096; i += 256) {
        ((ushort4*)lbh)[i] = ((const ushort4*)wh)[i];
        ((ushort4*)lbl)[i] = ((const ushort4*)wl)[i];
    }
    __syncthreads();

    int wave = tid >> 6, lane = tid & 63;
    int grb0 = blockIdx.x * 8 + wave * 2;

    f32x4 acc[2][8] = {};

    #pragma unroll
    for (int kc = 0; kc < 4; ++kc) {
        half8 a0 = *(const half8*)(af + ((size_t)grb0 * 4 + kc) * 512 + lane * 8);
        half8 a1 = *(const half8*)(af + ((size_t)(grb0 + 1) * 4 + kc) * 512 + lane * 8);
        #pragma unroll
        for (int cb = 0; cb < 8; ++cb) {
            half8 bh = *(const half8*)(lbh + (size_t)((cb * 4 + kc) * 64 + lane) * 8);
            half8 bl = *(const half8*)(lbl + (size_t)((cb * 4 + kc) * 64 + lane) * 8);
            acc[0][cb] = __builtin_amdgcn_mfma_f32_16x16x32_f16(a0, bh, acc[0][cb], 0, 0, 0);
            acc[0][cb] = __builtin_amdgcn_mfma_f32_16x16x32_f16(a0, bl, acc[0][cb], 0, 0, 0);
            acc[1][cb] = __builtin_amdgcn_mfma_f32_16x16x32_f16(a1, bh, acc[1][cb], 0, 0, 0);
            acc[1][cb] = __builtin_amdgcn_mfma_f32_16x16x32_f16(a1, bl, acc[1][cb], 0, 0, 0);
        }
    }

    int colbase = lane & 15;
    float scv[8], shv[8];
    #pragma unroll
    for (int cb = 0; cb < 8; ++cb) {
        int c = cb * 16 + colbase;
        float s = gamma[c] * rsqrtf(var[c] + BN_EPS);
        scv[cb] = s;
        shv[cb] = beta[c] + (bias[c] - mean[c]) * s;
    }
    int r0 = (lane >> 4) * 4;

    if (!POOL) {
        #pragma unroll
        for (int rb = 0; rb < 2; ++rb) {
            int rowb = (grb0 + rb) * 16 + r0;
            #pragma unroll
            for (int rg = 0; rg < 4; ++rg) {
                int row = rowb + rg;
                if (row < n) {
                    #pragma unroll
                    for (int cb = 0; cb < 8; ++cb) {
                        float v = fmaxf(fmaf(acc[rb][cb][rg], scv[cb], shv[cb]), 0.f);
                        outh[(size_t)row * HD + cb * 16 + colbase] = __float2half(v);
                    }
                }
            }
        }
    } else {
        // fused mean/max pooling: shuffle-reduce rows, one atomic per wave/col
        int row0 = blockIdx.x * 128;
        int row_hi = min(n - 1, row0 + 127);
        int g_lo = batch[row0];
        int g_hi = batch[row_hi];

        int gval[2][4];
        #pragma unroll
        for (int rb = 0; rb < 2; ++rb) {
            int rowb = (grb0 + rb) * 16 + r0;
            #pragma unroll
            for (int rg = 0; rg < 4; ++rg) {
                int row = rowb + rg;
                gval[rb][rg] = (row < n) ? batch[row] : -1;
            }
        }

        for (int g = g_lo; g <= g_hi; ++g) {
            #pragma unroll
            for (int cb = 0; cb < 8; ++cb) {
                float s = 0.f, m = 0.f;
                #pragma unroll
                for (int rb = 0; rb < 2; ++rb) {
                    #pragma unroll
                    for (int rg = 0; rg < 4; ++rg) {
                        if (gval[rb][rg] == g) {
                            float v = fmaxf(fmaf(acc[rb][cb][rg], scv[cb], shv[cb]), 0.f);
                            s += v;
                            m = fmaxf(m, v);
                        }
                    }
                }
                // reduce across the 4 row-groups of the wave (lanes ^16, ^32)
                s += __shfl_xor(s, 16);
                m = fmaxf(m, __shfl_xor(m, 16));
                s += __shfl_xor(s, 32);
                m = fmaxf(m, __shfl_xor(m, 32));
                if (lane < 16 && (s != 0.f || m != 0.f)) {
                    atomicAdd(&gsum[g * HD + cb * 16 + colbase], s);
                    atomicMax(&gmax[g * HD + cb * 16 + colbase], __float_as_uint(m));
                }
            }
        }
    }
}

// ---------------- fused head: relu([mean||max]@pool_W+pool_b) @ out_W + out_b ----
__global__ void k_head(const float* __restrict__ gsum, const unsigned int* __restrict__ gmax,
                       const int* __restrict__ starts, const float* __restrict__ pool_W,
                       const float* __restrict__ pool_b, const float* __restrict__ out_W,
                       const float* __restrict__ out_b, float* __restrict__ out) {
    int g = blockIdx.x, t = threadIdx.x;   // t in [0,128)
    __shared__ float pooled[2 * HD];
    __shared__ float hid_s[HD];
    float cntf = fmaxf((float)(starts[g + 1] - starts[g]), 1.f);
    pooled[t] = gsum[g * HD + t] / cntf;
    pooled[HD + t] = __uint_as_float(gmax[g * HD + t]);
    __syncthreads();
    float acc = pool_b[t];
    for (int k = 0; k < 2 * HD; ++k)
        acc += pooled[k] * pool_W[k * HD + t];
    hid_s[t] = fmaxf(acc, 0.f);
    __syncthreads();
    if (t < 64) {
        float a2 = out_b[t];
        for (int j = 0; j < HD; ++j)
            a2 += hid_s[j] * out_W[j * 64 + t];
        out[g * 64 + t] = a2;
    }
}

extern "C" void kernel_launch(void* const* d_in, const int* in_sizes, int n_in,
                              void* d_out, int out_size, void* d_ws, size_t ws_size,
                              hipStream_t stream) {
    const float* x        = (const float*)d_in[0];
    const int*   eidx     = (const int*)d_in[1];
    const int*   batch    = (const int*)d_in[2];
    const float* W0       = (const float*)d_in[3];
    const float* Wh       = (const float*)d_in[4];
    const float* b        = (const float*)d_in[5];
    const float* bn_gamma = (const float*)d_in[6];
    const float* bn_beta  = (const float*)d_in[7];
    const float* bn_mean  = (const float*)d_in[8];
    const float* bn_var   = (const float*)d_in[9];
    const float* pool_W   = (const float*)d_in[10];
    const float* pool_b   = (const float*)d_in[11];
    const float* out_W    = (const float*)d_in[12];
    const float* out_b    = (const float*)d_in[13];
    float* out = (float*)d_out;

    const int N = in_sizes[2];
    const int E = in_sizes[1] / 2;
    const int L = in_sizes[5] / HD;
    const int G = out_size / (HD / 2);

    const int* src = eidx;
    const int* dst = eidx + E;

    const int NBLK = (N + 127) / 128;          // GEMM blocks (128 rows each)
    const size_t NRB = (size_t)NBLK * 8;       // padded rowblocks

    // workspace layout (16B-aligned chunks first)
    char* p = (char*)d_ws;
    __half* hf   = (__half*)p; p += (size_t)NBLK * 128 * HD * 2; // inter-layer fp16
    unsigned short* af  = (unsigned short*)p; p += NRB * 4 * 512 * 2;  // fp16 A frags
    unsigned short* agh = (unsigned short*)p; p += NRB * 512 * 2;      // layer0 bf16 hi
    unsigned short* agl = (unsigned short*)p; p += NRB * 512 * 2;      // layer0 bf16 lo
    unsigned short* whi0 = (unsigned short*)p; p += (size_t)16384 * 2;
    unsigned short* wlo0 = (unsigned short*)p; p += (size_t)16384 * 2;
    unsigned short* whf  = (unsigned short*)p; p += (size_t)3 * 16384 * 2;
    unsigned short* wlf  = (unsigned short*)p; p += (size_t)3 * 16384 * 2;
    unsigned short* esrc = (unsigned short*)p; p += (((size_t)E * 2 + 15) & ~15ull);
    unsigned short* ord  = (unsigned short*)p; p += (((size_t)E * 2 + 15) & ~15ull);
    int*   counts  = (int*)p;   p += (size_t)N * 4;
    float* dis     = (float*)p; p += (size_t)N * 4;
    int*   offs    = (int*)p;   p += (size_t)(N + 1) * 4;
    int*   bsums   = (int*)p;   p += 256 * 4;
    float* gsum    = (float*)p; p += (size_t)G * HD * 4;
    unsigned int* gmax = (unsigned int*)p; p += (size_t)G * HD * 4;  // adjacent to gsum
    int*   starts  = (int*)p;   p += (size_t)(G + 1) * 4;
    (void)ws_size; (void)n_in;

    // zero accumulators (gsum+gmax adjacent -> single memset)
    hipMemsetAsync(counts, 0, (size_t)N * 4, stream);
    hipMemsetAsync(gsum, 0, (size_t)G * HD * 8, stream);

    const int NB = (N + 255) / 256;

    k_count<<<1024, 256, 0, stream>>>(dst, counts, ord, E);
    k_scan1<<<NB, 256, 0, stream>>>(counts, offs, bsums, N);
    k_scan2<<<1, 256, 0, stream>>>(bsums, NB, batch, starts, N, G);
    k_scan3<<<NB, 256, 0, stream>>>(offs, bsums, counts, dis, N);
    k_fill<<<1024, 256, 0, stream>>>(src, dst, ord, offs, esrc, E);
    k_wsplit<<<256, 256, 0, stream>>>(W0, Wh, whi0, wlo0, whf, wlf);

    // layer 0: aggregate x (24 feats, K padded to 32), bf16 MFMA GEMM -> fp16
    k_agg_x<<<(N + 31) / 32, 256, 0, stream>>>(x, offs, counts, esrc, dis, agh, agl, N);
    k_gemm_m<<<NBLK, 256, 0, stream>>>(agh, agl, whi0, wlo0, b, bn_gamma, bn_beta,
                                       bn_mean, bn_var, hf, N);

    // layers 1..L-1: aggregate hf (fp16, full row) -> fp16 A-frags, fp16-MFMA GEMM
    for (int l = 1; l < L; ++l) {
        k_agg_h<<<(N + 7) / 8, 256, 0, stream>>>(hf, offs, counts, esrc, dis, af, N);
        const unsigned short* wh_l = whf + (size_t)(l - 1) * 16384;
        const unsigned short* wl_l = wlf + (size_t)(l - 1) * 16384;
        if (l < L - 1)
            k_gemm_h<false><<<NBLK, 256, 0, stream>>>(af, wh_l, wl_l,
                b + l * HD, bn_gamma + l * HD, bn_beta + l * HD,
                bn_mean + l * HD, bn_var + l * HD, hf, batch, gsum, gmax, N);
        else
            k_gemm_h<true><<<NBLK, 256, 0, stream>>>(af, wh_l, wl_l,
                b + l * HD, bn_gamma + l * HD, bn_beta + l * HD,
                bn_mean + l * HD, bn_var + l * HD, nullptr, batch, gsum, gmax, N);
    }

    // head
    k_head<<<G, HD, 0, stream>>>(gsum, gmax, starts, pool_W, pool_b, out_W, out_b, out);
}

// Round 12
// 232.615 us; speedup vs baseline: 4.8674x; 1.0221x over previous
//
#include <hip/hip_runtime.h>
#include <hip/hip_bf16.h>
#include <hip/hip_fp16.h>

#define HD 128          // hidden dim
#define BN_EPS 1e-5f

typedef __attribute__((ext_vector_type(8))) short short8;
typedef __attribute__((ext_vector_type(8))) _Float16 half8;
typedef __attribute__((ext_vector_type(4))) float f32x4;

// round-to-nearest-even f32 -> bf16 bits; rem = v - bf16(v)
__device__ inline unsigned short f2bf(float v, float& rem) {
    unsigned u = __float_as_uint(v);
    unsigned r = (u + 0x7FFFu + ((u >> 16) & 1u)) >> 16;
    rem = v - __uint_as_float(r << 16);
    return (unsigned short)r;
}

// ---------------- degree count + within-destination ordinal ----------------
__global__ void k_count(const int* __restrict__ dst, int* __restrict__ counts,
                        unsigned short* __restrict__ ord, int E) {
    int i = blockIdx.x * blockDim.x + threadIdx.x;
    for (; i < E; i += gridDim.x * blockDim.x) {
        int pos = atomicAdd(&counts[dst[i]], 1);
        ord[i] = (unsigned short)pos;
    }
}

// ---------------- exclusive scan ----------------
__global__ void k_scan1(const int* __restrict__ counts, int* __restrict__ offs,
                        int* __restrict__ bsums, int n) {
    __shared__ int s[256];
    int t = threadIdx.x, i = blockIdx.x * 256 + t;
    int v = (i < n) ? counts[i] : 0;
    s[t] = v; __syncthreads();
    for (int d = 1; d < 256; d <<= 1) {
        int x = (t >= d) ? s[t - d] : 0;
        __syncthreads(); s[t] += x; __syncthreads();
    }
    if (i < n) offs[i] = s[t] - v;
    if (t == 255) bsums[blockIdx.x] = s[255];
}

// scan of block sums + graph segment boundaries (batch is sorted) fused
__global__ void k_scan2(int* __restrict__ bsums, int nb,
                        const int* __restrict__ batch, int* __restrict__ starts,
                        int n, int G) {
    __shared__ int s[256];
    int t = threadIdx.x;
    int v = (t < nb) ? bsums[t] : 0;
    s[t] = v; __syncthreads();
    for (int d = 1; d < 256; d <<= 1) {
        int x = (t >= d) ? s[t - d] : 0;
        __syncthreads(); s[t] += x; __syncthreads();
    }
    if (t < nb) bsums[t] = s[t] - v;
    if (t <= G) {                        // lower_bound(batch, t)
        int lo = 0, hi = n;
        while (lo < hi) {
            int mid = (lo + hi) >> 1;
            if (batch[mid] < t) lo = mid + 1; else hi = mid;
        }
        starts[t] = lo;
    }
}

// scan finalize + dis = rsqrt(deg) fused
__global__ void k_scan3(int* __restrict__ offs, const int* __restrict__ bsums,
                        const int* __restrict__ counts, float* __restrict__ dis, int n) {
    int i = blockIdx.x * 256 + threadIdx.x;
    if (i < n) {
        offs[i] += bsums[blockIdx.x];
        dis[i] = rsqrtf((float)(counts[i] + 1));   // +1 self loop
    }
}

// ---------------- CSR fill (atomic-free) + W split, merged ----------------
// blocks [0,1024): fill esrc; blocks [1024,1280): W split into B-frag layout.
#define FILL_BLOCKS 1024
__global__ void k_fill_wsplit(const int* __restrict__ src, const int* __restrict__ dst,
                              const unsigned short* __restrict__ ord,
                              const int* __restrict__ offs,
                              unsigned short* __restrict__ esrc, int E,
                              const float* __restrict__ W0, const float* __restrict__ Wh,
                              unsigned short* __restrict__ whi0, unsigned short* __restrict__ wlo0,
                              unsigned short* __restrict__ whf, unsigned short* __restrict__ wlf) {
    int bid = blockIdx.x;
    if (bid < FILL_BLOCKS) {
        int i = bid * 256 + threadIdx.x;
        for (; i < E; i += FILL_BLOCKS * 256)
            esrc[offs[dst[i]] + ord[i]] = (unsigned short)src[i];
    } else {
        int idx = (bid - FILL_BLOCKS) * 256 + threadIdx.x;   // 4*128*128 total
        int l = idx >> 14, rest = idx & 16383;
        int k = rest >> 7, c = rest & 127;
        int cb = c >> 4, kc = k >> 5;
        int lane = (c & 15) | (((k & 31) >> 3) << 4);
        int j = k & 7;
        if (l == 0) {
            if (k >= 32) return;
            float val = (k < 24) ? W0[k * HD + c] : 0.f;
            float rem, rem2;
            unsigned short hi = f2bf(val, rem);
            unsigned short lo = f2bf(rem, rem2);
            size_t addr = (size_t)(cb * 64 + lane) * 8 + j;
            whi0[addr] = hi; wlo0[addr] = lo;
        } else {
            float val = Wh[(size_t)(l - 1) * HD * HD + (size_t)k * HD + c];
            __half h = __float2half(val);
            float rem = val - __half2float(h);
            __half lo = __float2half(rem);
            size_t addr = (size_t)(l - 1) * 16384 + (size_t)((cb * 4 + kc) * 64 + lane) * 8 + j;
            whf[addr] = __half_as_ushort(h);
            wlf[addr] = __half_as_ushort(lo);
        }
    }
}

// ---------------- layer-0 aggregation: out = Â x (f32 input, 24 feats) --------
// emits bf16 hi/lo A-frags, KC=1.
__global__ void k_agg_x(const float* __restrict__ in, const int* __restrict__ offs,
                        const int* __restrict__ counts, const unsigned short* __restrict__ esrc,
                        const float* __restrict__ dis, unsigned short* __restrict__ ohi,
                        unsigned short* __restrict__ olo, int n) {
    const int FQ = 6, GRP = 8;
    int grp = threadIdx.x / GRP;
    int lane = threadIdx.x % GRP;
    int node = blockIdx.x * (blockDim.x / GRP) + grp;
    if (node >= n) return;
    int rowblk = node >> 4, rr = node & 15;

    if (lane == FQ) {          // zero-fill features 24..31 (K pad)
        size_t base = (size_t)rowblk * 512 + (size_t)(rr + 48) * 8;
        ushort4 z = make_ushort4(0, 0, 0, 0);
        *(ushort4*)(ohi + base) = z; *(ushort4*)(ohi + base + 4) = z;
        *(ushort4*)(olo + base) = z; *(ushort4*)(olo + base + 4) = z;
    }
    if (lane >= FQ) return;

    const float4* in4 = reinterpret_cast<const float4*>(in);
    float dn = dis[node];
    float sl = dn * dn;
    float4 a = in4[(size_t)node * FQ + lane];
    float4 accA = make_float4(sl * a.x, sl * a.y, sl * a.z, sl * a.w);
    float4 accB = make_float4(0.f, 0.f, 0.f, 0.f);

    int e = offs[node], end = e + counts[node];
    for (; e + 3 < end; e += 4) {
        int s0 = esrc[e],     s1 = esrc[e + 1];
        int s2 = esrc[e + 2], s3 = esrc[e + 3];
        float c0 = dis[s0] * dn, c1 = dis[s1] * dn;
        float c2 = dis[s2] * dn, c3 = dis[s3] * dn;
        float4 v0 = in4[(size_t)s0 * FQ + lane];
        float4 v1 = in4[(size_t)s1 * FQ + lane];
        float4 v2 = in4[(size_t)s2 * FQ + lane];
        float4 v3 = in4[(size_t)s3 * FQ + lane];
        accA.x = fmaf(c0, v0.x, fmaf(c2, v2.x, accA.x));
        accA.y = fmaf(c0, v0.y, fmaf(c2, v2.y, accA.y));
        accA.z = fmaf(c0, v0.z, fmaf(c2, v2.z, accA.z));
        accA.w = fmaf(c0, v0.w, fmaf(c2, v2.w, accA.w));
        accB.x = fmaf(c1, v1.x, fmaf(c3, v3.x, accB.x));
        accB.y = fmaf(c1, v1.y, fmaf(c3, v3.y, accB.y));
        accB.z = fmaf(c1, v1.z, fmaf(c3, v3.z, accB.z));
        accB.w = fmaf(c1, v1.w, fmaf(c3, v3.w, accB.w));
    }
    for (; e < end; ++e) {
        int s0 = esrc[e];
        float c0 = dis[s0] * dn;
        float4 v0 = in4[(size_t)s0 * FQ + lane];
        accA.x = fmaf(c0, v0.x, accA.x);
        accA.y = fmaf(c0, v0.y, accA.y);
        accA.z = fmaf(c0, v0.z, accA.z);
        accA.w = fmaf(c0, v0.w, accA.w);
    }
    float4 acc = make_float4(accA.x + accB.x, accA.y + accB.y,
                             accA.z + accB.z, accA.w + accB.w);

    int f0 = lane * 4;
    int lidx = rr | (((f0 & 31) >> 3) << 4);
    int j0 = f0 & 7;
    size_t base = (size_t)rowblk * 512 + (size_t)lidx * 8 + j0;
    float r0, r1, r2, r3, d0;
    ushort4 hi, lo;
    hi.x = f2bf(acc.x, r0); hi.y = f2bf(acc.y, r1);
    hi.z = f2bf(acc.z, r2); hi.w = f2bf(acc.w, r3);
    lo.x = f2bf(r0, d0); lo.y = f2bf(r1, d0);
    lo.z = f2bf(r2, d0); lo.w = f2bf(r3, d0);
    *(ushort4*)(ohi + base) = hi;
    *(ushort4*)(olo + base) = lo;
}

// ---------------- hidden-layer aggregation: out = Â h (fp16 in, fp16 A-frags out) --
// 32 lanes per node (4 features each); emits fp16 A-frags, KC=4.
__global__ void k_agg_h(const __half* __restrict__ in, const int* __restrict__ offs,
                        const int* __restrict__ counts, const unsigned short* __restrict__ esrc,
                        const float* __restrict__ dis, unsigned short* __restrict__ af, int n) {
    int grp = threadIdx.x >> 5;
    int lane = threadIdx.x & 31;
    int node = blockIdx.x * 8 + grp;
    if (node >= n) return;
    int rowblk = node >> 4, rr = node & 15;

    const float2* in8 = reinterpret_cast<const float2*>(in);  // 4 halves per elem
    float dn = dis[node];
    float sl = dn * dn;

    float2 raw = in8[(size_t)node * 32 + lane];
    __half2 p0 = *(__half2*)&raw.x, p1 = *(__half2*)&raw.y;
    float2 f0v = __half22float2(p0), f1v = __half22float2(p1);
    float4 accA = make_float4(sl * f0v.x, sl * f0v.y, sl * f1v.x, sl * f1v.y);
    float4 accB = make_float4(0.f, 0.f, 0.f, 0.f);

    int e = offs[node], end = e + counts[node];
    for (; e + 3 < end; e += 4) {
        int s0 = esrc[e],     s1 = esrc[e + 1];
        int s2 = esrc[e + 2], s3 = esrc[e + 3];
        float c0 = dis[s0] * dn, c1 = dis[s1] * dn;
        float c2 = dis[s2] * dn, c3 = dis[s3] * dn;
        float2 w0 = in8[(size_t)s0 * 32 + lane];
        float2 w1 = in8[(size_t)s1 * 32 + lane];
        float2 w2 = in8[(size_t)s2 * 32 + lane];
        float2 w3 = in8[(size_t)s3 * 32 + lane];
        float2 a0 = __half22float2(*(__half2*)&w0.x), b0 = __half22float2(*(__half2*)&w0.y);
        float2 a1 = __half22float2(*(__half2*)&w1.x), b1 = __half22float2(*(__half2*)&w1.y);
        float2 a2 = __half22float2(*(__half2*)&w2.x), b2 = __half22float2(*(__half2*)&w2.y);
        float2 a3 = __half22float2(*(__half2*)&w3.x), b3 = __half22float2(*(__half2*)&w3.y);
        accA.x = fmaf(c0, a0.x, fmaf(c2, a2.x, accA.x));
        accA.y = fmaf(c0, a0.y, fmaf(c2, a2.y, accA.y));
        accA.z = fmaf(c0, b0.x, fmaf(c2, b2.x, accA.z));
        accA.w = fmaf(c0, b0.y, fmaf(c2, b2.y, accA.w));
        accB.x = fmaf(c1, a1.x, fmaf(c3, a3.x, accB.x));
        accB.y = fmaf(c1, a1.y, fmaf(c3, a3.y, accB.y));
        accB.z = fmaf(c1, b1.x, fmaf(c3, b3.x, accB.z));
        accB.w = fmaf(c1, b1.y, fmaf(c3, b3.y, accB.w));
    }
    for (; e < end; ++e) {
        int s0 = esrc[e];
        float c0 = dis[s0] * dn;
        float2 w0 = in8[(size_t)s0 * 32 + lane];
        float2 a0 = __half22float2(*(__half2*)&w0.x), b0 = __half22float2(*(__half2*)&w0.y);
        accA.x = fmaf(c0, a0.x, accA.x);
        accA.y = fmaf(c0, a0.y, accA.y);
        accA.z = fmaf(c0, b0.x, accA.z);
        accA.w = fmaf(c0, b0.y, accA.w);
    }
    float4 acc = make_float4(accA.x + accB.x, accA.y + accB.y,
                             accA.z + accB.z, accA.w + accB.w);

    // emit fp16 A-frag (KCA=4)
    int f0 = lane * 4;
    int kc = f0 >> 5;
    int lidx = rr | (((f0 & 31) >> 3) << 4);
    int j0 = f0 & 7;
    size_t base = ((size_t)rowblk * 4 + kc) * 512 + (size_t)lidx * 8 + j0;
    ushort4 hv;
    hv.x = __half_as_ushort(__float2half(acc.x));
    hv.y = __half_as_ushort(__float2half(acc.y));
    hv.z = __half_as_ushort(__float2half(acc.z));
    hv.w = __half_as_ushort(__float2half(acc.w));
    *(ushort4*)(af + base) = hv;
}

// ---------------- layer-0 MFMA GEMM (bf16 split A & W) + fused BN/ReLU ----------------
__global__ __launch_bounds__(256) void k_gemm_m(
        const unsigned short* __restrict__ agh, const unsigned short* __restrict__ agl,
        const unsigned short* __restrict__ wh, const unsigned short* __restrict__ wl,
        const float* __restrict__ bias, const float* __restrict__ gamma,
        const float* __restrict__ beta, const float* __restrict__ mean,
        const float* __restrict__ var, __half* __restrict__ outh, int n) {
    __shared__ unsigned short lbh[8 * 512];
    __shared__ unsigned short lbl[8 * 512];
    int tid = threadIdx.x;
    for (int i = tid; i < 1024; i += 256) {
        ((ushort4*)lbh)[i] = ((const ushort4*)wh)[i];
        ((ushort4*)lbl)[i] = ((const ushort4*)wl)[i];
    }
    __syncthreads();

    int wave = tid >> 6, lane = tid & 63;
    int grb0 = blockIdx.x * 8 + wave * 2;

    f32x4 acc[2][8] = {};

    short8 a0h = *(const short8*)(agh + (size_t)grb0 * 512 + lane * 8);
    short8 a0l = *(const short8*)(agl + (size_t)grb0 * 512 + lane * 8);
    short8 a1h = *(const short8*)(agh + (size_t)(grb0 + 1) * 512 + lane * 8);
    short8 a1l = *(const short8*)(agl + (size_t)(grb0 + 1) * 512 + lane * 8);
    #pragma unroll
    for (int cb = 0; cb < 8; ++cb) {
        short8 bh = *(const short8*)(lbh + (size_t)(cb * 64 + lane) * 8);
        short8 bl = *(const short8*)(lbl + (size_t)(cb * 64 + lane) * 8);
        acc[0][cb] = __builtin_amdgcn_mfma_f32_16x16x32_bf16(a0h, bh, acc[0][cb], 0, 0, 0);
        acc[0][cb] = __builtin_amdgcn_mfma_f32_16x16x32_bf16(a0h, bl, acc[0][cb], 0, 0, 0);
        acc[0][cb] = __builtin_amdgcn_mfma_f32_16x16x32_bf16(a0l, bh, acc[0][cb], 0, 0, 0);
        acc[1][cb] = __builtin_amdgcn_mfma_f32_16x16x32_bf16(a1h, bh, acc[1][cb], 0, 0, 0);
        acc[1][cb] = __builtin_amdgcn_mfma_f32_16x16x32_bf16(a1h, bl, acc[1][cb], 0, 0, 0);
        acc[1][cb] = __builtin_amdgcn_mfma_f32_16x16x32_bf16(a1l, bh, acc[1][cb], 0, 0, 0);
    }

    int colbase = lane & 15;
    float scv[8], shv[8];
    #pragma unroll
    for (int cb = 0; cb < 8; ++cb) {
        int c = cb * 16 + colbase;
        float s = gamma[c] * rsqrtf(var[c] + BN_EPS);
        scv[cb] = s;
        shv[cb] = beta[c] + (bias[c] - mean[c]) * s;
    }
    int r0 = (lane >> 4) * 4;
    #pragma unroll
    for (int rb = 0; rb < 2; ++rb) {
        int rowb = (grb0 + rb) * 16 + r0;
        #pragma unroll
        for (int rg = 0; rg < 4; ++rg) {
            int row = rowb + rg;
            if (row < n) {
                #pragma unroll
                for (int cb = 0; cb < 8; ++cb) {
                    float v = fmaxf(fmaf(acc[rb][cb][rg], scv[cb], shv[cb]), 0.f);
                    outh[(size_t)row * HD + cb * 16 + colbase] = __float2half(v);
                }
            }
        }
    }
}

// ---------------- hidden-layer MFMA GEMM: 256 rows/block (4 rowblocks/wave) --------
// POOL=false: write fp16 h. POOL=true: fused mean/max pooling via shuffle
// reduction + direct global atomics (no h output).
template<bool POOL>
__global__ __launch_bounds__(256) void k_gemm_h(
        const unsigned short* __restrict__ af,
        const unsigned short* __restrict__ wh, const unsigned short* __restrict__ wl,
        const float* __restrict__ bias, const float* __restrict__ gamma,
        const float* __restrict__ beta, const float* __restrict__ mean,
        const float* __restrict__ var, __half* __restrict__ outh,
        const int* __restrict__ batch, float* __restrict__ gsum,
        unsigned int* __restrict__ gmax, int n) {
    __shared__ unsigned short lbh[16384];   // 32 KB fp16 W hi
    __shared__ unsigned short lbl[16384];   // 32 KB fp16 W lo
    int tid = threadIdx.x;
    for (int i = tid; i < 4096; i += 256) {
        ((ushort4*)lbh)[i] = ((const ushort4*)wh)[i];
        ((ushort4*)lbl)[i] = ((const ushort4*)wl)[i];
    }
    __syncthreads();

    int wave = tid >> 6, lane = tid & 63;
    int grb0 = blockIdx.x * 16 + wave * 4;

    f32x4 acc[4][8] = {};

    #pragma unroll
    for (int kc = 0; kc < 4; ++kc) {
        half8 a0 = *(const half8*)(af + ((size_t)(grb0 + 0) * 4 + kc) * 512 + lane * 8);
        half8 a1 = *(const half8*)(af + ((size_t)(grb0 + 1) * 4 + kc) * 512 + lane * 8);
        half8 a2 = *(const half8*)(af + ((size_t)(grb0 + 2) * 4 + kc) * 512 + lane * 8);
        half8 a3 = *(const half8*)(af + ((size_t)(grb0 + 3) * 4 + kc) * 512 + lane * 8);
        #pragma unroll
        for (int cb = 0; cb < 8; ++cb) {
            half8 bh = *(const half8*)(lbh + (size_t)((cb * 4 + kc) * 64 + lane) * 8);
            half8 bl = *(const half8*)(lbl + (size_t)((cb * 4 + kc) * 64 + lane) * 8);
            acc[0][cb] = __builtin_amdgcn_mfma_f32_16x16x32_f16(a0, bh, acc[0][cb], 0, 0, 0);
            acc[0][cb] = __builtin_amdgcn_mfma_f32_16x16x32_f16(a0, bl, acc[0][cb], 0, 0, 0);
            acc[1][cb] = __builtin_amdgcn_mfma_f32_16x16x32_f16(a1, bh, acc[1][cb], 0, 0, 0);
            acc[1][cb] = __builtin_amdgcn_mfma_f32_16x16x32_f16(a1, bl, acc[1][cb], 0, 0, 0);
            acc[2][cb] = __builtin_amdgcn_mfma_f32_16x16x32_f16(a2, bh, acc[2][cb], 0, 0, 0);
            acc[2][cb] = __builtin_amdgcn_mfma_f32_16x16x32_f16(a2, bl, acc[2][cb], 0, 0, 0);
            acc[3][cb] = __builtin_amdgcn_mfma_f32_16x16x32_f16(a3, bh, acc[3][cb], 0, 0, 0);
            acc[3][cb] = __builtin_amdgcn_mfma_f32_16x16x32_f16(a3, bl, acc[3][cb], 0, 0, 0);
        }
    }

    int colbase = lane & 15;
    float scv[8], shv[8];
    #pragma unroll
    for (int cb = 0; cb < 8; ++cb) {
        int c = cb * 16 + colbase;
        float s = gamma[c] * rsqrtf(var[c] + BN_EPS);
        scv[cb] = s;
        shv[cb] = beta[c] + (bias[c] - mean[c]) * s;
    }
    int r0 = (lane >> 4) * 4;

    if (!POOL) {
        #pragma unroll
        for (int rb = 0; rb < 4; ++rb) {
            int rowb = (grb0 + rb) * 16 + r0;
            #pragma unroll
            for (int rg = 0; rg < 4; ++rg) {
                int row = rowb + rg;
                if (row < n) {
                    #pragma unroll
                    for (int cb = 0; cb < 8; ++cb) {
                        float v = fmaxf(fmaf(acc[rb][cb][rg], scv[cb], shv[cb]), 0.f);
                        outh[(size_t)row * HD + cb * 16 + colbase] = __float2half(v);
                    }
                }
            }
        }
    } else {
        // fused mean/max pooling: shuffle-reduce rows, one atomic per wave/col
        int row0 = blockIdx.x * 256;
        int row_hi = min(n - 1, row0 + 255);
        int g_lo = batch[min(row0, n - 1)];
        int g_hi = batch[row_hi];

        int gval[4][4];
        #pragma unroll
        for (int rb = 0; rb < 4; ++rb) {
            int rowb = (grb0 + rb) * 16 + r0;
            #pragma unroll
            for (int rg = 0; rg < 4; ++rg) {
                int row = rowb + rg;
                gval[rb][rg] = (row < n) ? batch[row] : -1;
            }
        }

        for (int g = g_lo; g <= g_hi; ++g) {
            #pragma unroll
            for (int cb = 0; cb < 8; ++cb) {
                float s = 0.f, m = 0.f;
                #pragma unroll
                for (int rb = 0; rb < 4; ++rb) {
                    #pragma unroll
                    for (int rg = 0; rg < 4; ++rg) {
                        if (gval[rb][rg] == g) {
                            float v = fmaxf(fmaf(acc[rb][cb][rg], scv[cb], shv[cb]), 0.f);
                            s += v;
                            m = fmaxf(m, v);
                        }
                    }
                }
                // reduce across the 4 row-groups of the wave (lanes ^16, ^32)
                s += __shfl_xor(s, 16);
                m = fmaxf(m, __shfl_xor(m, 16));
                s += __shfl_xor(s, 32);
                m = fmaxf(m, __shfl_xor(m, 32));
                if (lane < 16 && (s != 0.f || m != 0.f)) {
                    atomicAdd(&gsum[g * HD + cb * 16 + colbase], s);
                    atomicMax(&gmax[g * HD + cb * 16 + colbase], __float_as_uint(m));
                }
            }
        }
    }
}

// ---------------- fused head: relu([mean||max]@pool_W+pool_b) @ out_W + out_b ----
__global__ void k_head(const float* __restrict__ gsum, const unsigned int* __restrict__ gmax,
                       const int* __restrict__ starts, const float* __restrict__ pool_W,
                       const float* __restrict__ pool_b, const float* __restrict__ out_W,
                       const float* __restrict__ out_b, float* __restrict__ out) {
    int g = blockIdx.x, t = threadIdx.x;   // t in [0,128)
    __shared__ float pooled[2 * HD];
    __shared__ float hid_s[HD];
    float cntf = fmaxf((float)(starts[g + 1] - starts[g]), 1.f);
    pooled[t] = gsum[g * HD + t] / cntf;
    pooled[HD + t] = __uint_as_float(gmax[g * HD + t]);
    __syncthreads();
    float acc = pool_b[t];
    for (int k = 0; k < 2 * HD; ++k)
        acc += pooled[k] * pool_W[k * HD + t];
    hid_s[t] = fmaxf(acc, 0.f);
    __syncthreads();
    if (t < 64) {
        float a2 = out_b[t];
        for (int j = 0; j < HD; ++j)
            a2 += hid_s[j] * out_W[j * 64 + t];
        out[g * 64 + t] = a2;
    }
}

extern "C" void kernel_launch(void* const* d_in, const int* in_sizes, int n_in,
                              void* d_out, int out_size, void* d_ws, size_t ws_size,
                              hipStream_t stream) {
    const float* x        = (const float*)d_in[0];
    const int*   eidx     = (const int*)d_in[1];
    const int*   batch    = (const int*)d_in[2];
    const float* W0       = (const float*)d_in[3];
    const float* Wh       = (const float*)d_in[4];
    const float* b        = (const float*)d_in[5];
    const float* bn_gamma = (const float*)d_in[6];
    const float* bn_beta  = (const float*)d_in[7];
    const float* bn_mean  = (const float*)d_in[8];
    const float* bn_var   = (const float*)d_in[9];
    const float* pool_W   = (const float*)d_in[10];
    const float* pool_b   = (const float*)d_in[11];
    const float* out_W    = (const float*)d_in[12];
    const float* out_b    = (const float*)d_in[13];
    float* out = (float*)d_out;

    const int N = in_sizes[2];
    const int E = in_sizes[1] / 2;
    const int L = in_sizes[5] / HD;
    const int G = out_size / (HD / 2);

    const int* src = eidx;
    const int* dst = eidx + E;

    const int NBLK  = (N + 127) / 128;          // layer-0 GEMM blocks (128 rows)
    const int NBLK2 = (N + 255) / 256;          // hidden GEMM blocks (256 rows)
    const size_t NRB  = (size_t)NBLK * 8;       // layer-0 padded rowblocks
    const size_t NRB2 = (size_t)NBLK2 * 16;     // hidden padded rowblocks

    // workspace layout (16B-aligned chunks first)
    char* p = (char*)d_ws;
    __half* hf   = (__half*)p; p += NRB2 * 16 * HD * 2;                // inter-layer fp16
    unsigned short* af  = (unsigned short*)p; p += NRB2 * 4 * 512 * 2; // fp16 A frags
    unsigned short* agh = (unsigned short*)p; p += NRB * 512 * 2;      // layer0 bf16 hi
    unsigned short* agl = (unsigned short*)p; p += NRB * 512 * 2;      // layer0 bf16 lo
    unsigned short* whi0 = (unsigned short*)p; p += (size_t)16384 * 2;
    unsigned short* wlo0 = (unsigned short*)p; p += (size_t)16384 * 2;
    unsigned short* whf  = (unsigned short*)p; p += (size_t)3 * 16384 * 2;
    unsigned short* wlf  = (unsigned short*)p; p += (size_t)3 * 16384 * 2;
    unsigned short* esrc = (unsigned short*)p; p += (((size_t)E * 2 + 15) & ~15ull);
    unsigned short* ord  = (unsigned short*)p; p += (((size_t)E * 2 + 15) & ~15ull);
    // contiguous zero-init region: counts | gsum | gmax
    int*   counts  = (int*)p;   p += (size_t)N * 4;
    float* gsum    = (float*)p; p += (size_t)G * HD * 4;
    unsigned int* gmax = (unsigned int*)p; p += (size_t)G * HD * 4;
    float* dis     = (float*)p; p += (size_t)N * 4;
    int*   offs    = (int*)p;   p += (size_t)(N + 1) * 4;
    int*   bsums   = (int*)p;   p += 256 * 4;
    int*   starts  = (int*)p;   p += (size_t)(G + 1) * 4;
    (void)ws_size; (void)n_in;

    // single memset over counts+gsum+gmax (contiguous)
    hipMemsetAsync(counts, 0, (size_t)N * 4 + (size_t)G * HD * 8, stream);

    const int NB = (N + 255) / 256;

    k_count<<<1024, 256, 0, stream>>>(dst, counts, ord, E);
    k_scan1<<<NB, 256, 0, stream>>>(counts, offs, bsums, N);
    k_scan2<<<1, 256, 0, stream>>>(bsums, NB, batch, starts, N, G);
    k_scan3<<<NB, 256, 0, stream>>>(offs, bsums, counts, dis, N);
    k_fill_wsplit<<<FILL_BLOCKS + 256, 256, 0, stream>>>(src, dst, ord, offs, esrc, E,
                                                         W0, Wh, whi0, wlo0, whf, wlf);

    // layer 0: aggregate x (24 feats, K padded to 32), bf16 MFMA GEMM -> fp16
    k_agg_x<<<(N + 31) / 32, 256, 0, stream>>>(x, offs, counts, esrc, dis, agh, agl, N);
    k_gemm_m<<<NBLK, 256, 0, stream>>>(agh, agl, whi0, wlo0, b, bn_gamma, bn_beta,
                                       bn_mean, bn_var, hf, N);

    // layers 1..L-1: aggregate hf (fp16, full row) -> fp16 A-frags, fp16-MFMA GEMM
    for (int l = 1; l < L; ++l) {
        k_agg_h<<<(N + 7) / 8, 256, 0, stream>>>(hf, offs, counts, esrc, dis, af, N);
        const unsigned short* wh_l = whf + (size_t)(l - 1) * 16384;
        const unsigned short* wl_l = wlf + (size_t)(l - 1) * 16384;
        if (l < L - 1)
            k_gemm_h<false><<<NBLK2, 256, 0, stream>>>(af, wh_l, wl_l,
                b + l * HD, bn_gamma + l * HD, bn_beta + l * HD,
                bn_mean + l * HD, bn_var + l * HD, hf, batch, gsum, gmax, N);
        else
            k_gemm_h<true><<<NBLK2, 256, 0, stream>>>(af, wh_l, wl_l,
                b + l * HD, bn_gamma + l * HD, bn_beta + l * HD,
                bn_mean + l * HD, bn_var + l * HD, nullptr, batch, gsum, gmax, N);
    }

    // head
    k_head<<<G, HD, 0, stream>>>(gsum, gmax, starts, pool_W, pool_b, out_W, out_b, out);
}